// Round 1
// baseline (2160.380 us; speedup 1.0000x reference)
//
#include <hip/hip_runtime.h>
#include <math.h>

#define BB 4
#define CC 128
#define HH 48
#define WW 48
#define NSP (HH*WW)          // 2304
#define DCC 256
#define BCN (BB*CC*NSP)      // 1179648
#define BNTOT (BB*NSP)       // 9216

__device__ __forceinline__ float sigmf(float v) { return 1.0f / (1.0f + expf(-v)); }

// ---------------- RoPE ----------------
__global__ __launch_bounds__(256) void rope_kernel(const float* __restrict__ x,
                                                   float* __restrict__ o) {
  int idx = blockIdx.x * 256 + threadIdx.x;
  if (idx >= BCN) return;
  int n = idx % NSP;
  int c = (idx / NSP) % CC;
  int b = idx / (NSP * CC);
  int h = n / WW, w = n % WW;
  int i = c >> 1;
  float theta = expf(-9.2103403719761836f * ((float)i) / 64.0f);  // 1/10000^(i/64)
  float pos = (float)(h + w) * theta;
  float cs = cosf(pos), sn = sinf(pos);
  size_t base = ((size_t)b * CC + (i << 1)) * NSP + n;
  float re = x[base], im = x[base + NSP];
  o[idx] = (c & 1) ? (re * sn + im * cs) : (re * cs - im * sn);
}

// ---------------- conv1x1 (GEMM over positions), ACT: 0 none, 1 relu, 2 sigmoid, 3 relu^2
template <int ACT>
__global__ __launch_bounds__(256) void conv1x1_kernel(
    const float* __restrict__ in, const float* __restrict__ w,
    const float* __restrict__ bias, const float* __restrict__ addsrc,
    float* __restrict__ out, int Cin, int O) {
  int t = blockIdx.x * 256 + threadIdx.x;  // over B*NSP (exact)
  int b = t / NSP, n = t % NSP;
  int o0 = blockIdx.y * 8;
  float acc[8];
#pragma unroll
  for (int j = 0; j < 8; ++j) acc[j] = bias[o0 + j];
  const float* xin = in + (size_t)b * Cin * NSP + n;
  const float* wp = w + (size_t)o0 * Cin;
  for (int c = 0; c < Cin; ++c) {
    float xv = xin[(size_t)c * NSP];
#pragma unroll
    for (int j = 0; j < 8; ++j) acc[j] += wp[(size_t)j * Cin + c] * xv;
  }
#pragma unroll
  for (int j = 0; j < 8; ++j) {
    float v = acc[j];
    if (ACT == 1) v = fmaxf(v, 0.0f);
    else if (ACT == 2) v = sigmf(v);
    else if (ACT == 3) { v = fmaxf(v, 0.0f); v = v * v; }
    size_t oi = ((size_t)b * O + o0 + j) * NSP + n;
    if (addsrc) v += addsrc[oi];
    out[oi] = v;
  }
}

// ---------------- conv3x3, O=32, 4 outputs/thread ----------------
__global__ __launch_bounds__(256) void conv3x3_kernel(
    const float* __restrict__ in, int bstride_in, int Cin,
    const float* __restrict__ wt, const float* __restrict__ bias,
    float* __restrict__ out, int bstride_out) {
  int t = blockIdx.x * 256 + threadIdx.x;
  int b = t / NSP, n = t % NSP;
  int h = n / WW, w = n % WW;
  int o0 = blockIdx.y * 4;
  float acc[4];
#pragma unroll
  for (int j = 0; j < 4; ++j) acc[j] = bias[o0 + j];
  const float* xb = in + (size_t)b * bstride_in;
  for (int c = 0; c < Cin; ++c) {
    const float* xc = xb + (size_t)c * NSP;
    const float* wc = wt + ((size_t)o0 * Cin + c) * 9;
#pragma unroll
    for (int dh = 0; dh < 3; ++dh) {
      int hh = h + dh - 1;
      if (hh < 0 || hh >= HH) continue;
#pragma unroll
      for (int dw = 0; dw < 3; ++dw) {
        int ww2 = w + dw - 1;
        if (ww2 < 0 || ww2 >= WW) continue;
        float xv = xc[hh * WW + ww2];
        int ki = dh * 3 + dw;
#pragma unroll
        for (int j = 0; j < 4; ++j) acc[j] += wc[(size_t)j * Cin * 9 + ki] * xv;
      }
    }
  }
#pragma unroll
  for (int j = 0; j < 4; ++j)
    out[(size_t)b * bstride_out + (size_t)(o0 + j) * NSP + n] = acc[j];
}

// ---------------- batchnorm stats (mean/var per channel over B,H,W) ----------------
__global__ __launch_bounds__(256) void bn_stats_kernel(const float* __restrict__ in, int bstride,
                                                       float* __restrict__ mean,
                                                       float* __restrict__ var) {
  int c = blockIdx.x;
  float s = 0.0f, s2 = 0.0f;
  for (int i = threadIdx.x; i < BB * NSP; i += 256) {
    int b = i / NSP, n = i % NSP;
    float v = in[(size_t)b * bstride + (size_t)c * NSP + n];
    s += v;
    s2 += v * v;
  }
  __shared__ float rs[4], rs2[4];
#pragma unroll
  for (int off = 32; off > 0; off >>= 1) {
    s += __shfl_down(s, off);
    s2 += __shfl_down(s2, off);
  }
  int wid = threadIdx.x >> 6;
  if ((threadIdx.x & 63) == 0) { rs[wid] = s; rs2[wid] = s2; }
  __syncthreads();
  if (threadIdx.x == 0) {
    float S = rs[0] + rs[1] + rs[2] + rs[3];
    float S2 = rs2[0] + rs2[1] + rs2[2] + rs2[3];
    float m = S / (float)(BB * NSP);
    mean[c] = m;
    var[c] = S2 / (float)(BB * NSP) - m * m;
  }
}

__global__ __launch_bounds__(256) void bn_relu_kernel(
    const float* __restrict__ in, int bstride_in, int cin,
    const float* __restrict__ mean, const float* __restrict__ var,
    const float* __restrict__ g, const float* __restrict__ bb,
    float* __restrict__ h) {
  int idx = blockIdx.x * 256 + threadIdx.x;
  int tot = BB * cin * NSP;
  if (idx >= tot) return;
  int n = idx % NSP;
  int c = (idx / NSP) % cin;
  int b = idx / (NSP * cin);
  float v = in[(size_t)b * bstride_in + (size_t)c * NSP + n];
  float y = (v - mean[c]) * rsqrtf(var[c] + 1e-5f) * g[c] + bb[c];
  h[idx] = fmaxf(y, 0.0f);
}

// ---------------- small elementwise kernels ----------------
__global__ __launch_bounds__(256) void copyx_kernel(const float* __restrict__ x,
                                                    float* __restrict__ feats) {
  int idx = blockIdx.x * 256 + threadIdx.x;
  if (idx >= BCN) return;
  int n = idx % NSP;
  int c = (idx / NSP) % CC;
  int b = idx / (NSP * CC);
  feats[((size_t)b * DCC + c) * NSP + n] = x[idx];
}

__global__ __launch_bounds__(256) void mul_kernel(const float* __restrict__ a,
                                                  const float* __restrict__ b,
                                                  float* __restrict__ o, int ntot) {
  int idx = blockIdx.x * 256 + threadIdx.x;
  if (idx < ntot) o[idx] = a[idx] * b[idx];
}

__global__ __launch_bounds__(256) void add_kernel(const float* __restrict__ a,
                                                  const float* __restrict__ b,
                                                  float* __restrict__ o, int ntot) {
  int idx = blockIdx.x * 256 + threadIdx.x;
  if (idx < ntot) o[idx] = a[idx] + b[idx];
}

// rec = sigmoid_r * ((k*v + eu*k*v) / (k + eu*k))
__global__ __launch_bounds__(256) void recwkv_kernel(
    const float* __restrict__ r, const float* __restrict__ k,
    const float* __restrict__ kv, const float* __restrict__ v,
    const float* __restrict__ u, float* __restrict__ rec) {
  int idx = blockIdx.x * 256 + threadIdx.x;
  if (idx >= BCN) return;
  int c = (idx / NSP) % CC;
  float eu = expf(u[c]);
  float kk = k[idx], vv = v[idx], nv = kv[idx];
  float t = eu * kk;
  float num = nv + t * vv;
  float den = kk + t;
  rec[idx] = r[idx] * (num / den);
}

__global__ __launch_bounds__(256) void tau_kernel(const float* __restrict__ z2,
                                                  float* __restrict__ tau) {
  int bc = blockIdx.x;  // b*DCC + c
  float s = 0.0f;
  for (int n = threadIdx.x; n < NSP; n += 256) s += z2[(size_t)bc * NSP + n];
  __shared__ float rs[4];
#pragma unroll
  for (int off = 32; off > 0; off >>= 1) s += __shfl_down(s, off);
  int wid = threadIdx.x >> 6;
  if ((threadIdx.x & 63) == 0) rs[wid] = s;
  __syncthreads();
  if (threadIdx.x == 0) tau[bc] = (rs[0] + rs[1] + rs[2] + rs[3]) / (float)NSP;
}

__global__ __launch_bounds__(256) void sf_kernel(const float* __restrict__ feats,
                                                 const float* __restrict__ tau,
                                                 float* __restrict__ sf) {
  int idx = blockIdx.x * 256 + threadIdx.x;
  int tot = BB * DCC * NSP;
  if (idx >= tot) return;
  int c = (idx / NSP) % DCC;
  int b = idx / (NSP * DCC);
  float df = feats[idx];
  float sp = sigmf((df - 1.0f) * 5.0f);
  float e = expf(-1.0f / (tau[b * DCC + c] + 1e-6f));
  sf[idx] = sp * (df * e) + (1.0f - sp) * df;
}

// (B,Cc,N) -> (B,N,Cc)
__global__ __launch_bounds__(256) void transpose_kernel(const float* __restrict__ in,
                                                        float* __restrict__ out, int Cc) {
  int idx = blockIdx.x * 256 + threadIdx.x;
  int tot = BB * Cc * NSP;
  if (idx >= tot) return;
  int c = idx % Cc;
  int n = (idx / Cc) % NSP;
  int b = idx / (Cc * NSP);
  out[idx] = in[((size_t)b * Cc + c) * NSP + n];
}

// ---------------- attention: scores in LDS, block of 4 rows ----------------
__device__ __forceinline__ float block_reduce_max(float v, float* red) {
#pragma unroll
  for (int off = 32; off > 0; off >>= 1) v = fmaxf(v, __shfl_down(v, off));
  int wid = threadIdx.x >> 6;
  if ((threadIdx.x & 63) == 0) red[wid] = v;
  __syncthreads();
  v = fmaxf(fmaxf(red[0], red[1]), fmaxf(red[2], red[3]));
  __syncthreads();
  return v;
}
__device__ __forceinline__ float block_reduce_sum(float v, float* red) {
#pragma unroll
  for (int off = 32; off > 0; off >>= 1) v += __shfl_down(v, off);
  int wid = threadIdx.x >> 6;
  if ((threadIdx.x & 63) == 0) red[wid] = v;
  __syncthreads();
  v = red[0] + red[1] + red[2] + red[3];
  __syncthreads();
  return v;
}

// scores[n][m] = sum_c Qt[n][c] * Kmat[c][m] (Qt pre-scaled); out[c][n] = softmax_m . Vt[m][c]
template <int CD>
__global__ __launch_bounds__(256) void attention_kernel(
    const float* __restrict__ Kmat,  // (B, CD, N)
    const float* __restrict__ Qt,    // (B, N, CD)
    const float* __restrict__ Vt,    // (B, N, CD)
    float* __restrict__ outm,        // (B, CD, N)
    float scale) {
  constexpr int ROWS = 4;
  constexpr int MPT = NSP / 256;  // 9
  __shared__ float sc[ROWS][NSP];
  __shared__ float qs[ROWS][CD];
  __shared__ float red[4];
  __shared__ float rowinv[ROWS];
  __shared__ float red2[256 * ROWS];
  int tid = threadIdx.x;
  int b = blockIdx.y;
  int n0 = blockIdx.x * ROWS;

  for (int i = tid; i < ROWS * CD; i += 256) {
    int r = i / CD, c = i % CD;
    qs[r][c] = Qt[((size_t)b * NSP + n0 + r) * CD + c] * scale;
  }
  __syncthreads();

  float acc[ROWS][MPT];
#pragma unroll
  for (int r = 0; r < ROWS; ++r)
#pragma unroll
    for (int j = 0; j < MPT; ++j) acc[r][j] = 0.0f;

  const float* Kb = Kmat + (size_t)b * CD * NSP;
  for (int c = 0; c < CD; ++c) {
    const float* Kc = Kb + (size_t)c * NSP;
    float q0 = qs[0][c], q1 = qs[1][c], q2 = qs[2][c], q3 = qs[3][c];
#pragma unroll
    for (int j = 0; j < MPT; ++j) {
      float kv = Kc[tid + 256 * j];
      acc[0][j] += q0 * kv;
      acc[1][j] += q1 * kv;
      acc[2][j] += q2 * kv;
      acc[3][j] += q3 * kv;
    }
  }

#pragma unroll
  for (int r = 0; r < ROWS; ++r) {
    float mx = -3.4e38f;
#pragma unroll
    for (int j = 0; j < MPT; ++j) mx = fmaxf(mx, acc[r][j]);
    mx = block_reduce_max(mx, red);
    float s = 0.0f;
#pragma unroll
    for (int j = 0; j < MPT; ++j) {
      float e = expf(acc[r][j] - mx);
      sc[r][tid + 256 * j] = e;
      s += e;
    }
    s = block_reduce_sum(s, red);
    if (tid == 0) rowinv[r] = 1.0f / s;
  }
  __syncthreads();

  constexpr int G = 256 / CD;
  constexpr int MSPAN = NSP / G;
  int c = tid & (CD - 1);
  int g = tid / CD;
  float oacc[ROWS] = {0.0f, 0.0f, 0.0f, 0.0f};
  const float* Vb = Vt + (size_t)b * NSP * CD;
  for (int m = g * MSPAN; m < (g + 1) * MSPAN; ++m) {
    float vv = Vb[(size_t)m * CD + c];
#pragma unroll
    for (int r = 0; r < ROWS; ++r) oacc[r] += sc[r][m] * vv;
  }
#pragma unroll
  for (int r = 0; r < ROWS; ++r) red2[tid * ROWS + r] = oacc[r];
  __syncthreads();
  for (int i = tid; i < ROWS * CD; i += 256) {
    int r = i / CD, cc = i % CD;
    float s = 0.0f;
    for (int g2 = 0; g2 < G; ++g2) s += red2[(g2 * CD + cc) * ROWS + r];
    outm[((size_t)b * CD + cc) * NSP + n0 + r] = s * rowinv[r];
  }
}

// ---------------- host ----------------
extern "C" void kernel_launch(void* const* d_in, const int* in_sizes, int n_in,
                              void* d_out, int out_size, void* d_ws, size_t ws_size,
                              hipStream_t stream) {
  const float* x = (const float*)d_in[0];
  const float* r_w = (const float*)d_in[1];
  const float* r_b = (const float*)d_in[2];
  const float* k_w = (const float*)d_in[3];
  const float* k_b = (const float*)d_in[4];
  const float* v_w = (const float*)d_in[5];
  const float* v_b = (const float*)d_in[6];
  // d_in[7..10]: wc1/wc2 — dead code (multiplied by zeros in reference)
  const float* u = (const float*)d_in[11];
  const float* sn1_w = (const float*)d_in[12];
  const float* sn1_b = (const float*)d_in[13];
  const float* sn2_w = (const float*)d_in[14];
  const float* sn2_b = (const float*)d_in[15];
  const float* lb_w = (const float*)d_in[16];
  const float* lb_b = (const float*)d_in[17];
  const float* ld_w = (const float*)d_in[18];
  const float* ld_b = (const float*)d_in[19];
  const float* ps_w = (const float*)d_in[20];
  const float* ps_b = (const float*)d_in[21];
  const float* pq_w = (const float*)d_in[22];
  const float* pq_b = (const float*)d_in[23];
  const float* fc1_w = (const float*)d_in[24];
  const float* fc1_b = (const float*)d_in[25];
  const float* fc2_w = (const float*)d_in[26];
  const float* fc2_b = (const float*)d_in[27];
  const float* db_g[4] = {(const float*)d_in[28], (const float*)d_in[32],
                          (const float*)d_in[36], (const float*)d_in[40]};
  const float* db_b[4] = {(const float*)d_in[29], (const float*)d_in[33],
                          (const float*)d_in[37], (const float*)d_in[41]};
  const float* db_w[4] = {(const float*)d_in[30], (const float*)d_in[34],
                          (const float*)d_in[38], (const float*)d_in[42]};
  const float* db_cb[4] = {(const float*)d_in[31], (const float*)d_in[35],
                           (const float*)d_in[39], (const float*)d_in[43]};

  float* outp = (float*)d_out;        // out  (B,C,H,W)
  float* knum = outp + BCN;           // new_num = k*v
  float* kden = outp + 2 * (size_t)BCN;  // new_den = k

  float* ws = (float*)d_ws;
  const size_t F_FEATS = 0;           // (B,256,N)  2359296
  const size_t F_HBUF = 2359296;      // h / z2 / sf 2359296
  const size_t F_A2 = 4718592;        // xrope / z1 / Q / att2
  const size_t F_A3 = 5898240;        // v / K2
  const size_t F_A4 = 7077888;        // r / V2 / x1
  const size_t F_A5 = 8257536;        // rec / combined
  const size_t F_BF = 9437184;        // (B,32,N)
  const size_t F_DF = 9732096;
  const size_t F_BFT = 10027008;
  const size_t F_DFT = 10321920;
  const size_t F_ATT1 = 10616832;
  const size_t F_QT = 10911744;
  const size_t F_V2T = 12091392;
  const size_t F_STATS = 13271040;    // mean[256], var[256], tau[1024]
  float* mean = ws + F_STATS;
  float* var = ws + F_STATS + 256;
  float* tau = ws + F_STATS + 512;

  dim3 blk(256);
  int ewBCN = (BCN + 255) / 256;  // 4608
  const int GX = BNTOT / 256;     // 36

  // --- recurrent path ---
  rope_kernel<<<ewBCN, blk, 0, stream>>>(x, ws + F_A2);
  conv1x1_kernel<0><<<dim3(GX, 16), blk, 0, stream>>>(ws + F_A2, k_w, k_b, nullptr, kden, 128, 128);
  conv1x1_kernel<0><<<dim3(GX, 16), blk, 0, stream>>>(ws + F_A2, v_w, v_b, nullptr, ws + F_A3, 128, 128);
  mul_kernel<<<ewBCN, blk, 0, stream>>>(kden, ws + F_A3, knum, BCN);
  conv1x1_kernel<2><<<dim3(GX, 16), blk, 0, stream>>>(x, r_w, r_b, nullptr, ws + F_A4, 128, 128);
  recwkv_kernel<<<ewBCN, blk, 0, stream>>>(ws + F_A4, kden, knum, ws + F_A3, u, ws + F_A5);

  // --- dense block ---
  copyx_kernel<<<ewBCN, blk, 0, stream>>>(x, ws + F_FEATS);
  int cins[4] = {128, 160, 192, 224};
  for (int i = 0; i < 4; ++i) {
    int cin = cins[i];
    bn_stats_kernel<<<cin, blk, 0, stream>>>(ws + F_FEATS, DCC * NSP, mean, var);
    bn_relu_kernel<<<(BB * cin * NSP + 255) / 256, blk, 0, stream>>>(
        ws + F_FEATS, DCC * NSP, cin, mean, var, db_g[i], db_b[i], ws + F_HBUF);
    conv3x3_kernel<<<dim3(GX, 8), blk, 0, stream>>>(
        ws + F_HBUF, cin * NSP, cin, db_w[i], db_cb[i],
        ws + F_FEATS + (size_t)(128 + 32 * i) * NSP, DCC * NSP);
  }

  // --- spike path ---
  conv1x1_kernel<1><<<dim3(GX, 8), blk, 0, stream>>>(ws + F_FEATS, sn1_w, sn1_b, nullptr, ws + F_A2, 256, 64);
  conv1x1_kernel<2><<<dim3(GX, 32), blk, 0, stream>>>(ws + F_A2, sn2_w, sn2_b, nullptr, ws + F_HBUF, 64, 256);
  tau_kernel<<<BB * DCC, blk, 0, stream>>>(ws + F_HBUF, tau);
  sf_kernel<<<(BB * DCC * NSP + 255) / 256, blk, 0, stream>>>(ws + F_FEATS, tau, ws + F_HBUF);
  conv1x1_kernel<0><<<dim3(GX, 4), blk, 0, stream>>>(ws + F_HBUF, lb_w, lb_b, nullptr, ws + F_BF, 256, 32);
  conv1x1_kernel<0><<<dim3(GX, 4), blk, 0, stream>>>(ws + F_HBUF, ld_w, ld_b, nullptr, ws + F_DF, 256, 32);
  transpose_kernel<<<(BB * 32 * NSP + 255) / 256, blk, 0, stream>>>(ws + F_BF, ws + F_BFT, 32);
  transpose_kernel<<<(BB * 32 * NSP + 255) / 256, blk, 0, stream>>>(ws + F_DF, ws + F_DFT, 32);
  attention_kernel<32><<<dim3(NSP / 4, BB), blk, 0, stream>>>(
      ws + F_BF, ws + F_BFT, ws + F_DFT, ws + F_ATT1, 1.0f);
  // combined = rec + conv1x1(att1, ps)
  conv1x1_kernel<0><<<dim3(GX, 16), blk, 0, stream>>>(ws + F_ATT1, ps_w, ps_b, ws + F_A5, ws + F_A5, 32, 128);

  // --- final attention ---
  conv1x1_kernel<0><<<dim3(GX, 16), blk, 0, stream>>>(ws + F_A5, pq_w, pq_b, nullptr, ws + F_A2, 128, 128);
  conv1x1_kernel<0><<<dim3(GX, 16), blk, 0, stream>>>(ws + F_A5, k_w, k_b, nullptr, ws + F_A3, 128, 128);
  conv1x1_kernel<0><<<dim3(GX, 16), blk, 0, stream>>>(ws + F_A5, v_w, v_b, nullptr, ws + F_A4, 128, 128);
  transpose_kernel<<<ewBCN, blk, 0, stream>>>(ws + F_A2, ws + F_QT, 128);
  transpose_kernel<<<ewBCN, blk, 0, stream>>>(ws + F_A4, ws + F_V2T, 128);
  attention_kernel<128><<<dim3(NSP / 4, BB), blk, 0, stream>>>(
      ws + F_A3, ws + F_QT, ws + F_V2T, ws + F_A2, 0.08838834764831845f);

  // --- FFN tail ---
  add_kernel<<<ewBCN, blk, 0, stream>>>(x, ws + F_A2, ws + F_A4, BCN);  // x1
  conv1x1_kernel<3><<<dim3(GX, 64), blk, 0, stream>>>(ws + F_A4, fc1_w, fc1_b, nullptr, ws + F_FEATS, 128, 512);
  conv1x1_kernel<0><<<dim3(GX, 16), blk, 0, stream>>>(ws + F_FEATS, fc2_w, fc2_b, ws + F_A4, outp, 512, 128);
}

// Round 3
// 1711.929 us; speedup vs baseline: 1.2620x; 1.2620x over previous
//
#include <hip/hip_runtime.h>
#include <math.h>

#define BB 4
#define CC 128
#define HH 48
#define WW 48
#define NSP (HH*WW)          // 2304
#define DCC 256
#define BCN (BB*CC*NSP)      // 1179648
#define BNTOT (BB*NSP)       // 9216

__device__ __forceinline__ float sigmf(float v) { return 1.0f / (1.0f + expf(-v)); }

// ---------------- RoPE ----------------
__global__ __launch_bounds__(256) void rope_kernel(const float* __restrict__ x,
                                                   float* __restrict__ o) {
  int idx = blockIdx.x * 256 + threadIdx.x;
  if (idx >= BCN) return;
  int n = idx % NSP;
  int c = (idx / NSP) % CC;
  int b = idx / (NSP * CC);
  int h = n / WW, w = n % WW;
  int i = c >> 1;
  float theta = expf(-9.2103403719761836f * ((float)i) / 64.0f);  // 1/10000^(i/64)
  float pos = (float)(h + w) * theta;
  float cs = cosf(pos), sn = sinf(pos);
  size_t base = ((size_t)b * CC + (i << 1)) * NSP + n;
  float re = x[base], im = x[base + NSP];
  o[idx] = (c & 1) ? (re * sn + im * cs) : (re * cs - im * sn);
}

// ---------------- conv1x1 (GEMM over positions), ACT: 0 none, 1 relu, 2 sigmoid, 3 relu^2
template <int ACT>
__global__ __launch_bounds__(256) void conv1x1_kernel(
    const float* __restrict__ in, const float* __restrict__ w,
    const float* __restrict__ bias, const float* __restrict__ addsrc,
    float* __restrict__ out, int Cin, int O) {
  int t = blockIdx.x * 256 + threadIdx.x;  // over B*NSP (exact)
  int b = t / NSP, n = t % NSP;
  int o0 = blockIdx.y * 8;
  float acc[8];
#pragma unroll
  for (int j = 0; j < 8; ++j) acc[j] = bias[o0 + j];
  const float* xin = in + (size_t)b * Cin * NSP + n;
  const float* wp = w + (size_t)o0 * Cin;
  for (int c = 0; c < Cin; ++c) {
    float xv = xin[(size_t)c * NSP];
#pragma unroll
    for (int j = 0; j < 8; ++j) acc[j] += wp[(size_t)j * Cin + c] * xv;
  }
#pragma unroll
  for (int j = 0; j < 8; ++j) {
    float v = acc[j];
    if (ACT == 1) v = fmaxf(v, 0.0f);
    else if (ACT == 2) v = sigmf(v);
    else if (ACT == 3) { v = fmaxf(v, 0.0f); v = v * v; }
    size_t oi = ((size_t)b * O + o0 + j) * NSP + n;
    if (addsrc) v += addsrc[oi];
    out[oi] = v;
  }
}

// ---------------- fused BN+ReLU+conv3x3, branchless, 4 outputs/thread ----------------
__global__ __launch_bounds__(256) void conv3x3_bn_kernel(
    const float* __restrict__ feats, int Cin,
    const float* __restrict__ mean, const float* __restrict__ var,
    const float* __restrict__ g, const float* __restrict__ bb,
    const float* __restrict__ wt, const float* __restrict__ cb,
    float* __restrict__ out) {  // out = feats + outc0*NSP, batch stride DCC*NSP
  int t = blockIdx.x * 256 + threadIdx.x;
  int b = t / NSP, n = t % NSP;
  int h = n / WW, w = n % WW;
  int o0 = blockIdx.y * 4;
  float acc0 = cb[o0], acc1 = cb[o0 + 1], acc2 = cb[o0 + 2], acc3 = cb[o0 + 3];
  const float* xb = feats + (size_t)b * (DCC * NSP);
  const float* w0 = wt + (size_t)(o0)*Cin * 9;
  const float* w1 = wt + (size_t)(o0 + 1) * Cin * 9;
  const float* w2 = wt + (size_t)(o0 + 2) * Cin * 9;
  const float* w3 = wt + (size_t)(o0 + 3) * Cin * 9;

  // thread-invariant tap validity + clamped addresses (hoisted out of c-loop)
  bool vh0 = h > 0, vh2 = h < HH - 1, vw0 = w > 0, vw2 = w < WW - 1;
  bool vm[9] = {vh0 && vw0, vh0, vh0 && vw2, vw0, true, vw2, vh2 && vw0, vh2, vh2 && vw2};
  const int offs[9] = {-WW - 1, -WW, -WW + 1, -1, 0, 1, WW - 1, WW, WW + 1};
  int adr[9];
#pragma unroll
  for (int k = 0; k < 9; ++k) adr[k] = vm[k] ? (n + offs[k]) : 0;

#pragma unroll 2
  for (int c = 0; c < Cin; ++c) {
    float sc_ = rsqrtf(var[c] + 1e-5f) * g[c];
    float sh_ = bb[c] - mean[c] * sc_;
    const float* xc = xb + (size_t)c * NSP;
    float hv[9];
#pragma unroll
    for (int k = 0; k < 9; ++k) {
      float xv = xc[adr[k]];
      float y = fmaxf(xv * sc_ + sh_, 0.0f);
      hv[k] = vm[k] ? y : 0.0f;
    }
    const float* wc0 = w0 + c * 9;
    const float* wc1 = w1 + c * 9;
    const float* wc2 = w2 + c * 9;
    const float* wc3 = w3 + c * 9;
#pragma unroll
    for (int k = 0; k < 9; ++k) {
      acc0 += wc0[k] * hv[k];
      acc1 += wc1[k] * hv[k];
      acc2 += wc2[k] * hv[k];
      acc3 += wc3[k] * hv[k];
    }
  }
  size_t ob = (size_t)b * (DCC * NSP) + (size_t)o0 * NSP + n;
  out[ob] = acc0;
  out[ob + NSP] = acc1;
  out[ob + 2 * NSP] = acc2;
  out[ob + 3 * NSP] = acc3;
}

// ---------------- batchnorm stats (per channel over B,H,W), channel offset ----------------
__global__ __launch_bounds__(256) void bn_stats_kernel(const float* __restrict__ feats, int coff,
                                                       float* __restrict__ mean,
                                                       float* __restrict__ var) {
  int c = coff + blockIdx.x;
  float s = 0.0f, s2 = 0.0f;
  for (int i = threadIdx.x; i < BB * NSP; i += 256) {
    int b = i / NSP, n = i % NSP;
    float v = feats[((size_t)b * DCC + c) * NSP + n];
    s += v;
    s2 += v * v;
  }
  __shared__ float rs[4], rs2[4];
#pragma unroll
  for (int off = 32; off > 0; off >>= 1) {
    s += __shfl_down(s, off);
    s2 += __shfl_down(s2, off);
  }
  int wid = threadIdx.x >> 6;
  if ((threadIdx.x & 63) == 0) { rs[wid] = s; rs2[wid] = s2; }
  __syncthreads();
  if (threadIdx.x == 0) {
    float S = rs[0] + rs[1] + rs[2] + rs[3];
    float S2 = rs2[0] + rs2[1] + rs2[2] + rs2[3];
    float m = S / (float)(BB * NSP);
    mean[c] = m;
    var[c] = S2 / (float)(BB * NSP) - m * m;
  }
}

// ---------------- small elementwise kernels ----------------
__global__ __launch_bounds__(256) void copyx_kernel(const float* __restrict__ x,
                                                    float* __restrict__ feats) {
  int idx = blockIdx.x * 256 + threadIdx.x;
  if (idx >= BCN) return;
  int n = idx % NSP;
  int c = (idx / NSP) % CC;
  int b = idx / (NSP * CC);
  feats[((size_t)b * DCC + c) * NSP + n] = x[idx];
}

__global__ __launch_bounds__(256) void add_kernel(const float* __restrict__ a,
                                                  const float* __restrict__ b,
                                                  float* __restrict__ o, int ntot) {
  int idx = blockIdx.x * 256 + threadIdx.x;
  if (idx < ntot) o[idx] = a[idx] + b[idx];
}

// knum = k*v; rec = sigmoid_r * ((k*v + eu*k*v) / (k + eu*k))
__global__ __launch_bounds__(256) void recwkv_kernel(
    const float* __restrict__ r, const float* __restrict__ k,
    const float* __restrict__ v, const float* __restrict__ u,
    float* __restrict__ knum, float* __restrict__ rec) {
  int idx = blockIdx.x * 256 + threadIdx.x;
  if (idx >= BCN) return;
  int c = (idx / NSP) % CC;
  float eu = expf(u[c]);
  float kk = k[idx], vv = v[idx];
  float nv = kk * vv;
  knum[idx] = nv;
  float t = eu * kk;
  rec[idx] = r[idx] * ((nv + t * vv) / (kk + t));
}

__global__ __launch_bounds__(256) void tau_kernel(const float* __restrict__ z2,
                                                  float* __restrict__ tau) {
  int bc = blockIdx.x;  // b*DCC + c
  float s = 0.0f;
  for (int n = threadIdx.x; n < NSP; n += 256) s += z2[(size_t)bc * NSP + n];
  __shared__ float rs[4];
#pragma unroll
  for (int off = 32; off > 0; off >>= 1) s += __shfl_down(s, off);
  int wid = threadIdx.x >> 6;
  if ((threadIdx.x & 63) == 0) rs[wid] = s;
  __syncthreads();
  if (threadIdx.x == 0) tau[bc] = (rs[0] + rs[1] + rs[2] + rs[3]) / (float)NSP;
}

__global__ __launch_bounds__(256) void sf_kernel(const float* __restrict__ feats,
                                                 const float* __restrict__ tau,
                                                 float* __restrict__ sf) {
  int idx = blockIdx.x * 256 + threadIdx.x;
  int tot = BB * DCC * NSP;
  if (idx >= tot) return;
  int c = (idx / NSP) % DCC;
  int b = idx / (NSP * DCC);
  float df = feats[idx];
  float sp = sigmf((df - 1.0f) * 5.0f);
  float e = expf(-1.0f / (tau[b * DCC + c] + 1e-6f));
  sf[idx] = sp * (df * e) + (1.0f - sp) * df;
}

// (B,Cc,N) -> (B,N,Cc)
__global__ __launch_bounds__(256) void transpose_kernel(const float* __restrict__ in,
                                                        float* __restrict__ out, int Cc) {
  int idx = blockIdx.x * 256 + threadIdx.x;
  int tot = BB * Cc * NSP;
  if (idx >= tot) return;
  int c = idx % Cc;
  int n = (idx / Cc) % NSP;
  int b = idx / (Cc * NSP);
  out[idx] = in[((size_t)b * Cc + c) * NSP + n];
}

// ---------------- attention: scores in LDS, block of 4 rows ----------------
__device__ __forceinline__ float block_reduce_max(float v, float* red) {
#pragma unroll
  for (int off = 32; off > 0; off >>= 1) v = fmaxf(v, __shfl_down(v, off));
  int wid = threadIdx.x >> 6;
  if ((threadIdx.x & 63) == 0) red[wid] = v;
  __syncthreads();
  v = fmaxf(fmaxf(red[0], red[1]), fmaxf(red[2], red[3]));
  __syncthreads();
  return v;
}
__device__ __forceinline__ float block_reduce_sum(float v, float* red) {
#pragma unroll
  for (int off = 32; off > 0; off >>= 1) v += __shfl_down(v, off);
  int wid = threadIdx.x >> 6;
  if ((threadIdx.x & 63) == 0) red[wid] = v;
  __syncthreads();
  v = red[0] + red[1] + red[2] + red[3];
  __syncthreads();
  return v;
}

// scores[n][m] = sum_c Q[n][c] * Kmat[c][m] (Q pre-scaled); out[c][n] = softmax_m . Vt[m][c]
// Qm is read DIRECTLY in (B,CD,N) layout (no transpose kernel).
template <int CD>
__global__ __launch_bounds__(256) void attention_kernel(
    const float* __restrict__ Kmat,  // (B, CD, N)
    const float* __restrict__ Qm,    // (B, CD, N)
    const float* __restrict__ Vt,    // (B, N, CD)
    float* __restrict__ outm,        // (B, CD, N)
    float scale) {
  constexpr int ROWS = 4;
  constexpr int MPT = NSP / 256;  // 9
  __shared__ float sc[ROWS][NSP];
  __shared__ float qs[ROWS][CD];
  __shared__ float red[4];
  __shared__ float rowinv[ROWS];
  __shared__ float red2[256 * ROWS];
  int tid = threadIdx.x;
  int b = blockIdx.y;
  int n0 = blockIdx.x * ROWS;

  for (int i = tid; i < ROWS * CD; i += 256) {
    int r = i & (ROWS - 1), c = i >> 2;  // r-major: 4 consecutive lanes hit 4 consecutive n
    qs[r][c] = Qm[((size_t)b * CD + c) * NSP + n0 + r] * scale;
  }
  __syncthreads();

  float acc[ROWS][MPT];
#pragma unroll
  for (int r = 0; r < ROWS; ++r)
#pragma unroll
    for (int j = 0; j < MPT; ++j) acc[r][j] = 0.0f;

  const float* Kb = Kmat + (size_t)b * CD * NSP;
  for (int c = 0; c < CD; ++c) {
    const float* Kc = Kb + (size_t)c * NSP;
    float q0 = qs[0][c], q1 = qs[1][c], q2 = qs[2][c], q3 = qs[3][c];
#pragma unroll
    for (int j = 0; j < MPT; ++j) {
      float kv = Kc[tid + 256 * j];
      acc[0][j] += q0 * kv;
      acc[1][j] += q1 * kv;
      acc[2][j] += q2 * kv;
      acc[3][j] += q3 * kv;
    }
  }

#pragma unroll
  for (int r = 0; r < ROWS; ++r) {
    float mx = -3.4e38f;
#pragma unroll
    for (int j = 0; j < MPT; ++j) mx = fmaxf(mx, acc[r][j]);
    mx = block_reduce_max(mx, red);
    float s = 0.0f;
#pragma unroll
    for (int j = 0; j < MPT; ++j) {
      float e = expf(acc[r][j] - mx);
      sc[r][tid + 256 * j] = e;
      s += e;
    }
    s = block_reduce_sum(s, red);
    if (tid == 0) rowinv[r] = 1.0f / s;
  }
  __syncthreads();

  constexpr int G = 256 / CD;
  constexpr int MSPAN = NSP / G;
  int c = tid & (CD - 1);
  int g = tid / CD;
  float oacc[ROWS] = {0.0f, 0.0f, 0.0f, 0.0f};
  const float* Vb = Vt + (size_t)b * NSP * CD;
  for (int m = g * MSPAN; m < (g + 1) * MSPAN; ++m) {
    float vv = Vb[(size_t)m * CD + c];
#pragma unroll
    for (int r = 0; r < ROWS; ++r) oacc[r] += sc[r][m] * vv;
  }
#pragma unroll
  for (int r = 0; r < ROWS; ++r) red2[tid * ROWS + r] = oacc[r];
  __syncthreads();
  for (int i = tid; i < ROWS * CD; i += 256) {
    int r = i / CD, cc = i % CD;
    float s = 0.0f;
    for (int g2 = 0; g2 < G; ++g2) s += red2[(g2 * CD + cc) * ROWS + r];
    outm[((size_t)b * CD + cc) * NSP + n0 + r] = s * rowinv[r];
  }
}

// ---------------- host ----------------
extern "C" void kernel_launch(void* const* d_in, const int* in_sizes, int n_in,
                              void* d_out, int out_size, void* d_ws, size_t ws_size,
                              hipStream_t stream) {
  const float* x = (const float*)d_in[0];
  const float* r_w = (const float*)d_in[1];
  const float* r_b = (const float*)d_in[2];
  const float* k_w = (const float*)d_in[3];
  const float* k_b = (const float*)d_in[4];
  const float* v_w = (const float*)d_in[5];
  const float* v_b = (const float*)d_in[6];
  // d_in[7..10]: wc1/wc2 — dead code (multiplied by zeros in reference)
  const float* u = (const float*)d_in[11];
  const float* sn1_w = (const float*)d_in[12];
  const float* sn1_b = (const float*)d_in[13];
  const float* sn2_w = (const float*)d_in[14];
  const float* sn2_b = (const float*)d_in[15];
  const float* lb_w = (const float*)d_in[16];
  const float* lb_b = (const float*)d_in[17];
  const float* ld_w = (const float*)d_in[18];
  const float* ld_b = (const float*)d_in[19];
  const float* ps_w = (const float*)d_in[20];
  const float* ps_b = (const float*)d_in[21];
  const float* pq_w = (const float*)d_in[22];
  const float* pq_b = (const float*)d_in[23];
  const float* fc1_w = (const float*)d_in[24];
  const float* fc1_b = (const float*)d_in[25];
  const float* fc2_w = (const float*)d_in[26];
  const float* fc2_b = (const float*)d_in[27];
  const float* db_g[4] = {(const float*)d_in[28], (const float*)d_in[32],
                          (const float*)d_in[36], (const float*)d_in[40]};
  const float* db_b[4] = {(const float*)d_in[29], (const float*)d_in[33],
                          (const float*)d_in[37], (const float*)d_in[41]};
  const float* db_w[4] = {(const float*)d_in[30], (const float*)d_in[34],
                          (const float*)d_in[38], (const float*)d_in[42]};
  const float* db_cb[4] = {(const float*)d_in[31], (const float*)d_in[35],
                           (const float*)d_in[39], (const float*)d_in[43]};

  float* outp = (float*)d_out;           // out  (B,C,H,W)
  float* knum = outp + BCN;              // new_num = k*v
  float* kden = outp + 2 * (size_t)BCN;  // new_den = k

  float* ws = (float*)d_ws;
  const size_t F_FEATS = 0;           // (B,256,N)  2359296
  const size_t F_HBUF = 2359296;      // z2 / sf
  const size_t F_A2 = 4718592;        // xrope / z1 / Q
  const size_t F_A3 = 5898240;        // v / K2
  const size_t F_A4 = 7077888;        // r / V2 / x1
  const size_t F_A5 = 8257536;        // rec / combined
  const size_t F_BF = 9437184;        // (B,32,N)
  const size_t F_DF = 9732096;
  const size_t F_DFT = 10321920;
  const size_t F_ATT1 = 10616832;
  const size_t F_ATT2 = 10911744;     // att2 (B,128,N)
  const size_t F_V2T = 12091392;
  const size_t F_STATS = 13271040;    // mean[256], var[256], tau[1024]
  float* mean = ws + F_STATS;
  float* var = ws + F_STATS + 256;
  float* tau = ws + F_STATS + 512;

  dim3 blk(256);
  int ewBCN = (BCN + 255) / 256;  // 4608
  const int GX = BNTOT / 256;     // 36

  // --- recurrent path ---
  rope_kernel<<<ewBCN, blk, 0, stream>>>(x, ws + F_A2);
  conv1x1_kernel<0><<<dim3(GX, 16), blk, 0, stream>>>(ws + F_A2, k_w, k_b, nullptr, kden, 128, 128);
  conv1x1_kernel<0><<<dim3(GX, 16), blk, 0, stream>>>(ws + F_A2, v_w, v_b, nullptr, ws + F_A3, 128, 128);
  conv1x1_kernel<2><<<dim3(GX, 16), blk, 0, stream>>>(x, r_w, r_b, nullptr, ws + F_A4, 128, 128);
  recwkv_kernel<<<ewBCN, blk, 0, stream>>>(ws + F_A4, kden, ws + F_A3, u, knum, ws + F_A5);

  // --- dense block (fused BN+ReLU+conv3x3, incremental stats) ---
  copyx_kernel<<<ewBCN, blk, 0, stream>>>(x, ws + F_FEATS);
  bn_stats_kernel<<<128, blk, 0, stream>>>(ws + F_FEATS, 0, mean, var);
  int cins[4] = {128, 160, 192, 224};
  for (int i = 0; i < 4; ++i) {
    int cin = cins[i];
    conv3x3_bn_kernel<<<dim3(GX, 8), blk, 0, stream>>>(
        ws + F_FEATS, cin, mean, var, db_g[i], db_b[i], db_w[i], db_cb[i],
        ws + F_FEATS + (size_t)cin * NSP);
    if (i < 3)
      bn_stats_kernel<<<32, blk, 0, stream>>>(ws + F_FEATS, cin, mean, var);  // stats for the channels JUST written
  }

  // --- spike path ---
  conv1x1_kernel<1><<<dim3(GX, 8), blk, 0, stream>>>(ws + F_FEATS, sn1_w, sn1_b, nullptr, ws + F_A2, 256, 64);
  conv1x1_kernel<2><<<dim3(GX, 32), blk, 0, stream>>>(ws + F_A2, sn2_w, sn2_b, nullptr, ws + F_HBUF, 64, 256);
  tau_kernel<<<BB * DCC, blk, 0, stream>>>(ws + F_HBUF, tau);
  sf_kernel<<<(BB * DCC * NSP + 255) / 256, blk, 0, stream>>>(ws + F_FEATS, tau, ws + F_HBUF);
  conv1x1_kernel<0><<<dim3(GX, 4), blk, 0, stream>>>(ws + F_HBUF, lb_w, lb_b, nullptr, ws + F_BF, 256, 32);
  conv1x1_kernel<0><<<dim3(GX, 4), blk, 0, stream>>>(ws + F_HBUF, ld_w, ld_b, nullptr, ws + F_DF, 256, 32);
  transpose_kernel<<<(BB * 32 * NSP + 255) / 256, blk, 0, stream>>>(ws + F_DF, ws + F_DFT, 32);
  attention_kernel<32><<<dim3(NSP / 4, BB), blk, 0, stream>>>(
      ws + F_BF, ws + F_BF, ws + F_DFT, ws + F_ATT1, 1.0f);
  // combined = rec + conv1x1(att1, ps)
  conv1x1_kernel<0><<<dim3(GX, 16), blk, 0, stream>>>(ws + F_ATT1, ps_w, ps_b, ws + F_A5, ws + F_A5, 32, 128);

  // --- final attention ---
  conv1x1_kernel<0><<<dim3(GX, 16), blk, 0, stream>>>(ws + F_A5, pq_w, pq_b, nullptr, ws + F_A2, 128, 128);
  conv1x1_kernel<0><<<dim3(GX, 16), blk, 0, stream>>>(ws + F_A5, k_w, k_b, nullptr, ws + F_A3, 128, 128);
  conv1x1_kernel<0><<<dim3(GX, 16), blk, 0, stream>>>(ws + F_A5, v_w, v_b, nullptr, ws + F_A4, 128, 128);
  transpose_kernel<<<ewBCN, blk, 0, stream>>>(ws + F_A4, ws + F_V2T, 128);
  attention_kernel<128><<<dim3(NSP / 4, BB), blk, 0, stream>>>(
      ws + F_A3, ws + F_A2, ws + F_V2T, ws + F_ATT2, 0.08838834764831845f);

  // --- FFN tail ---
  add_kernel<<<ewBCN, blk, 0, stream>>>(x, ws + F_ATT2, ws + F_A4, BCN);  // x1
  conv1x1_kernel<3><<<dim3(GX, 64), blk, 0, stream>>>(ws + F_A4, fc1_w, fc1_b, nullptr, ws + F_FEATS, 128, 512);
  conv1x1_kernel<0><<<dim3(GX, 16), blk, 0, stream>>>(ws + F_FEATS, fc2_w, fc2_b, ws + F_A4, outp, 512, 128);
}

// Round 4
// 1511.637 us; speedup vs baseline: 1.4292x; 1.1325x over previous
//
#include <hip/hip_runtime.h>
#include <math.h>

#define BB 4
#define CC 128
#define HH 48
#define WW 48
#define NSP (HH*WW)          // 2304
#define DCC 256
#define BCN (BB*CC*NSP)      // 1179648
#define BNTOT (BB*NSP)       // 9216

typedef float f32x4 __attribute__((ext_vector_type(4)));
typedef __bf16 bf16x8 __attribute__((ext_vector_type(8)));

__device__ __forceinline__ float sigmf(float v) { return 1.0f / (1.0f + expf(-v)); }

// ---------------- RoPE ----------------
__global__ __launch_bounds__(256) void rope_kernel(const float* __restrict__ x,
                                                   float* __restrict__ o) {
  int idx = blockIdx.x * 256 + threadIdx.x;
  if (idx >= BCN) return;
  int n = idx % NSP;
  int c = (idx / NSP) % CC;
  int b = idx / (NSP * CC);
  int h = n / WW, w = n % WW;
  int i = c >> 1;
  float theta = expf(-9.2103403719761836f * ((float)i) / 64.0f);  // 1/10000^(i/64)
  float pos = (float)(h + w) * theta;
  float cs = cosf(pos), sn = sinf(pos);
  size_t base = ((size_t)b * CC + (i << 1)) * NSP + n;
  float re = x[base], im = x[base + NSP];
  o[idx] = (c & 1) ? (re * sn + im * cs) : (re * cs - im * sn);
}

// ---------------- conv1x1 (GEMM over positions), ACT: 0 none, 1 relu, 2 sigmoid, 3 relu^2
template <int ACT>
__global__ __launch_bounds__(256) void conv1x1_kernel(
    const float* __restrict__ in, const float* __restrict__ w,
    const float* __restrict__ bias, const float* __restrict__ addsrc,
    float* __restrict__ out, int Cin, int O) {
  int t = blockIdx.x * 256 + threadIdx.x;  // over B*NSP (exact)
  int b = t / NSP, n = t % NSP;
  int o0 = blockIdx.y * 8;
  float acc[8];
#pragma unroll
  for (int j = 0; j < 8; ++j) acc[j] = bias[o0 + j];
  const float* xin = in + (size_t)b * Cin * NSP + n;
  const float* wp = w + (size_t)o0 * Cin;
  for (int c = 0; c < Cin; ++c) {
    float xv = xin[(size_t)c * NSP];
#pragma unroll
    for (int j = 0; j < 8; ++j) acc[j] += wp[(size_t)j * Cin + c] * xv;
  }
#pragma unroll
  for (int j = 0; j < 8; ++j) {
    float v = acc[j];
    if (ACT == 1) v = fmaxf(v, 0.0f);
    else if (ACT == 2) v = sigmf(v);
    else if (ACT == 3) { v = fmaxf(v, 0.0f); v = v * v; }
    size_t oi = ((size_t)b * O + o0 + j) * NSP + n;
    if (addsrc) v += addsrc[oi];
    out[oi] = v;
  }
}

// ---------------- fused BN+ReLU+conv3x3, branchless, 4 outputs/thread ----------------
__global__ __launch_bounds__(256) void conv3x3_bn_kernel(
    const float* __restrict__ feats, int Cin,
    const float* __restrict__ mean, const float* __restrict__ var,
    const float* __restrict__ g, const float* __restrict__ bb,
    const float* __restrict__ wt, const float* __restrict__ cb,
    float* __restrict__ out) {  // out = feats + outc0*NSP, batch stride DCC*NSP
  int t = blockIdx.x * 256 + threadIdx.x;
  int b = t / NSP, n = t % NSP;
  int h = n / WW, w = n % WW;
  int o0 = blockIdx.y * 4;
  float acc0 = cb[o0], acc1 = cb[o0 + 1], acc2 = cb[o0 + 2], acc3 = cb[o0 + 3];
  const float* xb = feats + (size_t)b * (DCC * NSP);
  const float* w0 = wt + (size_t)(o0)*Cin * 9;
  const float* w1 = wt + (size_t)(o0 + 1) * Cin * 9;
  const float* w2 = wt + (size_t)(o0 + 2) * Cin * 9;
  const float* w3 = wt + (size_t)(o0 + 3) * Cin * 9;

  bool vh0 = h > 0, vh2 = h < HH - 1, vw0 = w > 0, vw2 = w < WW - 1;
  bool vm[9] = {vh0 && vw0, vh0, vh0 && vw2, vw0, true, vw2, vh2 && vw0, vh2, vh2 && vw2};
  const int offs[9] = {-WW - 1, -WW, -WW + 1, -1, 0, 1, WW - 1, WW, WW + 1};
  int adr[9];
#pragma unroll
  for (int k = 0; k < 9; ++k) adr[k] = vm[k] ? (n + offs[k]) : 0;

#pragma unroll 2
  for (int c = 0; c < Cin; ++c) {
    float sc_ = rsqrtf(var[c] + 1e-5f) * g[c];
    float sh_ = bb[c] - mean[c] * sc_;
    const float* xc = xb + (size_t)c * NSP;
    float hv[9];
#pragma unroll
    for (int k = 0; k < 9; ++k) {
      float xv = xc[adr[k]];
      float y = fmaxf(xv * sc_ + sh_, 0.0f);
      hv[k] = vm[k] ? y : 0.0f;
    }
    const float* wc0 = w0 + c * 9;
    const float* wc1 = w1 + c * 9;
    const float* wc2 = w2 + c * 9;
    const float* wc3 = w3 + c * 9;
#pragma unroll
    for (int k = 0; k < 9; ++k) {
      acc0 += wc0[k] * hv[k];
      acc1 += wc1[k] * hv[k];
      acc2 += wc2[k] * hv[k];
      acc3 += wc3[k] * hv[k];
    }
  }
  size_t ob = (size_t)b * (DCC * NSP) + (size_t)o0 * NSP + n;
  out[ob] = acc0;
  out[ob + NSP] = acc1;
  out[ob + 2 * NSP] = acc2;
  out[ob + 3 * NSP] = acc3;
}

// ---------------- batchnorm stats (per channel over B,H,W), channel offset ----------------
__global__ __launch_bounds__(256) void bn_stats_kernel(const float* __restrict__ feats, int coff,
                                                       float* __restrict__ mean,
                                                       float* __restrict__ var) {
  int c = coff + blockIdx.x;
  float s = 0.0f, s2 = 0.0f;
  for (int i = threadIdx.x; i < BB * NSP; i += 256) {
    int b = i / NSP, n = i % NSP;
    float v = feats[((size_t)b * DCC + c) * NSP + n];
    s += v;
    s2 += v * v;
  }
  __shared__ float rs[4], rs2[4];
#pragma unroll
  for (int off = 32; off > 0; off >>= 1) {
    s += __shfl_down(s, off);
    s2 += __shfl_down(s2, off);
  }
  int wid = threadIdx.x >> 6;
  if ((threadIdx.x & 63) == 0) { rs[wid] = s; rs2[wid] = s2; }
  __syncthreads();
  if (threadIdx.x == 0) {
    float S = rs[0] + rs[1] + rs[2] + rs[3];
    float S2 = rs2[0] + rs2[1] + rs2[2] + rs2[3];
    float m = S / (float)(BB * NSP);
    mean[c] = m;
    var[c] = S2 / (float)(BB * NSP) - m * m;
  }
}

// ---------------- small elementwise kernels ----------------
__global__ __launch_bounds__(256) void copyx_kernel(const float* __restrict__ x,
                                                    float* __restrict__ feats) {
  int idx = blockIdx.x * 256 + threadIdx.x;
  if (idx >= BCN) return;
  int n = idx % NSP;
  int c = (idx / NSP) % CC;
  int b = idx / (NSP * CC);
  feats[((size_t)b * DCC + c) * NSP + n] = x[idx];
}

__global__ __launch_bounds__(256) void add_kernel(const float* __restrict__ a,
                                                  const float* __restrict__ b,
                                                  float* __restrict__ o, int ntot) {
  int idx = blockIdx.x * 256 + threadIdx.x;
  if (idx < ntot) o[idx] = a[idx] + b[idx];
}

// knum = k*v; rec = sigmoid_r * ((k*v + eu*k*v) / (k + eu*k))
__global__ __launch_bounds__(256) void recwkv_kernel(
    const float* __restrict__ r, const float* __restrict__ k,
    const float* __restrict__ v, const float* __restrict__ u,
    float* __restrict__ knum, float* __restrict__ rec) {
  int idx = blockIdx.x * 256 + threadIdx.x;
  if (idx >= BCN) return;
  int c = (idx / NSP) % CC;
  float eu = expf(u[c]);
  float kk = k[idx], vv = v[idx];
  float nv = kk * vv;
  knum[idx] = nv;
  float t = eu * kk;
  rec[idx] = r[idx] * ((nv + t * vv) / (kk + t));
}

__global__ __launch_bounds__(256) void tau_kernel(const float* __restrict__ z2,
                                                  float* __restrict__ tau) {
  int bc = blockIdx.x;  // b*DCC + c
  float s = 0.0f;
  for (int n = threadIdx.x; n < NSP; n += 256) s += z2[(size_t)bc * NSP + n];
  __shared__ float rs[4];
#pragma unroll
  for (int off = 32; off > 0; off >>= 1) s += __shfl_down(s, off);
  int wid = threadIdx.x >> 6;
  if ((threadIdx.x & 63) == 0) rs[wid] = s;
  __syncthreads();
  if (threadIdx.x == 0) tau[bc] = (rs[0] + rs[1] + rs[2] + rs[3]) / (float)NSP;
}

__global__ __launch_bounds__(256) void sf_kernel(const float* __restrict__ feats,
                                                 const float* __restrict__ tau,
                                                 float* __restrict__ sf) {
  int idx = blockIdx.x * 256 + threadIdx.x;
  int tot = BB * DCC * NSP;
  if (idx >= tot) return;
  int c = (idx / NSP) % DCC;
  int b = idx / (NSP * DCC);
  float df = feats[idx];
  float sp = sigmf((df - 1.0f) * 5.0f);
  float e = expf(-1.0f / (tau[b * DCC + c] + 1e-6f));
  sf[idx] = sp * (df * e) + (1.0f - sp) * df;
}

// (B,C,N) f32 -> (B,N,C) bf16, with scale
__global__ __launch_bounds__(256) void trans_bf16_kernel(const float* __restrict__ in,
                                                         __bf16* __restrict__ out, int C,
                                                         float scale) {
  int idx = blockIdx.x * 256 + threadIdx.x;
  int tot = BB * NSP * C;
  if (idx >= tot) return;
  int c = idx % C;
  int n = (idx / C) % NSP;
  int b = idx / (C * NSP);
  out[idx] = (__bf16)(in[((size_t)b * C + c) * NSP + n] * scale);
}

// elementwise f32 -> bf16
__global__ __launch_bounds__(256) void cvt_bf16_kernel(const float* __restrict__ in,
                                                       __bf16* __restrict__ out, int tot) {
  int idx = blockIdx.x * 256 + threadIdx.x;
  if (idx < tot) out[idx] = (__bf16)in[idx];
}

// ---------------- MFMA flash attention (no max-sub: |scores| << 88) ----------------
// Qt, Kt: (B, N, CD) bf16 (Qt pre-scaled); Vb: (B, CD, N) bf16; out: (B, CD, N) f32.
// 1 wave per block, 16 Q-rows per block, K-tiles of 32 keys.
template <int CD>
__global__ __launch_bounds__(64) void attn_mfma_kernel(
    const __bf16* __restrict__ Qt, const __bf16* __restrict__ Kt,
    const __bf16* __restrict__ Vb, float* __restrict__ outm) {
  constexpr int NC = CD / 16;  // output col-tiles (8 or 2)
  constexpr int KC = CD / 32;  // k-chunks for QK (4 or 1)
  __shared__ float pt[16][36];  // P transpose buffer (rows padded: 2-way conflicts only)
  int lane = threadIdx.x;
  int m15 = lane & 15;
  int quad = lane >> 4;
  int b = blockIdx.y;
  int n0 = blockIdx.x * 16;

  // Loop-invariant A-frags (Q): lane holds Q^T[n0+m15][kc*32 + quad*8 + j]
  bf16x8 qf[KC];
  const __bf16* qrow = Qt + ((size_t)b * NSP + n0 + m15) * CD + quad * 8;
#pragma unroll
  for (int kc = 0; kc < KC; ++kc) qf[kc] = *(const bf16x8*)(qrow + kc * 32);

  f32x4 of[NC];
#pragma unroll
  for (int i = 0; i < NC; ++i) of[i] = (f32x4){0.f, 0.f, 0.f, 0.f};
  float l0 = 0.f, l1 = 0.f, l2 = 0.f, l3 = 0.f;

  const __bf16* Kb = Kt + (size_t)b * NSP * CD;
  const __bf16* Vbb = Vb + (size_t)b * CD * NSP;

  for (int m0 = 0; m0 < NSP; m0 += 32) {
    // S-tiles: two 16-key col tiles
    f32x4 s[2];
#pragma unroll
    for (int t = 0; t < 2; ++t) {
      f32x4 acc = (f32x4){0.f, 0.f, 0.f, 0.f};
      const __bf16* krow = Kb + (size_t)(m0 + t * 16 + m15) * CD + quad * 8;
#pragma unroll
      for (int kc = 0; kc < KC; ++kc) {
        bf16x8 kf = *(const bf16x8*)(krow + kc * 32);
        acc = __builtin_amdgcn_mfma_f32_16x16x32_bf16(qf[kc], kf, acc, 0, 0, 0);
      }
      s[t] = acc;
    }
    // P = exp(S); accumulate row-sums; C-layout -> LDS (row = quad*4+reg, col = key)
#pragma unroll
    for (int t = 0; t < 2; ++t) {
      float e0 = expf(s[t].x), e1 = expf(s[t].y), e2 = expf(s[t].z), e3 = expf(s[t].w);
      l0 += e0; l1 += e1; l2 += e2; l3 += e3;
      pt[quad * 4 + 0][t * 16 + m15] = e0;
      pt[quad * 4 + 1][t * 16 + m15] = e1;
      pt[quad * 4 + 2][t * 16 + m15] = e2;
      pt[quad * 4 + 3][t * 16 + m15] = e3;
    }
    __syncthreads();
    // read P in A-layout: P[m15][quad*8 + j]
    const float* prow = &pt[m15][quad * 8];
    f32x4 pa = *(const f32x4*)(prow);
    f32x4 pb = *(const f32x4*)(prow + 4);
    bf16x8 pf;
    pf[0] = (__bf16)pa.x; pf[1] = (__bf16)pa.y; pf[2] = (__bf16)pa.z; pf[3] = (__bf16)pa.w;
    pf[4] = (__bf16)pb.x; pf[5] = (__bf16)pb.y; pf[6] = (__bf16)pb.z; pf[7] = (__bf16)pb.w;
    __syncthreads();
    // O += P * V  (B-frag: V[ct*16+m15][m0 + quad*8 + j], contiguous 16B)
#pragma unroll
    for (int ct = 0; ct < NC; ++ct) {
      bf16x8 vf = *(const bf16x8*)(Vbb + (size_t)(ct * 16 + m15) * NSP + m0 + quad * 8);
      of[ct] = __builtin_amdgcn_mfma_f32_16x16x32_bf16(pf, vf, of[ct], 0, 0, 0);
    }
  }

  // row-sum reduce across the 16 lanes of each quad group
#pragma unroll
  for (int off = 1; off < 16; off <<= 1) {
    l0 += __shfl_xor(l0, off);
    l1 += __shfl_xor(l1, off);
    l2 += __shfl_xor(l2, off);
    l3 += __shfl_xor(l3, off);
  }
  float i0 = 1.0f / l0, i1 = 1.0f / l1, i2 = 1.0f / l2, i3 = 1.0f / l3;

#pragma unroll
  for (int ct = 0; ct < NC; ++ct) {
    f32x4 o = of[ct];
    o.x *= i0; o.y *= i1; o.z *= i2; o.w *= i3;
    float* dst = outm + ((size_t)b * CD + ct * 16 + m15) * NSP + n0 + quad * 4;
    *(f32x4*)dst = o;  // rows quad*4+reg are consecutive n -> dwordx4
  }
}

// ---------------- host ----------------
extern "C" void kernel_launch(void* const* d_in, const int* in_sizes, int n_in,
                              void* d_out, int out_size, void* d_ws, size_t ws_size,
                              hipStream_t stream) {
  const float* x = (const float*)d_in[0];
  const float* r_w = (const float*)d_in[1];
  const float* r_b = (const float*)d_in[2];
  const float* k_w = (const float*)d_in[3];
  const float* k_b = (const float*)d_in[4];
  const float* v_w = (const float*)d_in[5];
  const float* v_b = (const float*)d_in[6];
  // d_in[7..10]: wc1/wc2 — dead code (multiplied by zeros in reference)
  const float* u = (const float*)d_in[11];
  const float* sn1_w = (const float*)d_in[12];
  const float* sn1_b = (const float*)d_in[13];
  const float* sn2_w = (const float*)d_in[14];
  const float* sn2_b = (const float*)d_in[15];
  const float* lb_w = (const float*)d_in[16];
  const float* lb_b = (const float*)d_in[17];
  const float* ld_w = (const float*)d_in[18];
  const float* ld_b = (const float*)d_in[19];
  const float* ps_w = (const float*)d_in[20];
  const float* ps_b = (const float*)d_in[21];
  const float* pq_w = (const float*)d_in[22];
  const float* pq_b = (const float*)d_in[23];
  const float* fc1_w = (const float*)d_in[24];
  const float* fc1_b = (const float*)d_in[25];
  const float* fc2_w = (const float*)d_in[26];
  const float* fc2_b = (const float*)d_in[27];
  const float* db_g[4] = {(const float*)d_in[28], (const float*)d_in[32],
                          (const float*)d_in[36], (const float*)d_in[40]};
  const float* db_b[4] = {(const float*)d_in[29], (const float*)d_in[33],
                          (const float*)d_in[37], (const float*)d_in[41]};
  const float* db_w[4] = {(const float*)d_in[30], (const float*)d_in[34],
                          (const float*)d_in[38], (const float*)d_in[42]};
  const float* db_cb[4] = {(const float*)d_in[31], (const float*)d_in[35],
                           (const float*)d_in[39], (const float*)d_in[43]};

  float* outp = (float*)d_out;           // out  (B,C,H,W)
  float* knum = outp + BCN;              // new_num = k*v
  float* kden = outp + 2 * (size_t)BCN;  // new_den = k

  float* ws = (float*)d_ws;
  const size_t F_FEATS = 0;           // (B,256,N)  2359296
  const size_t F_HBUF = 2359296;      // z2 / sf
  const size_t F_A2 = 4718592;        // xrope / z1 / Q
  const size_t F_A3 = 5898240;        // v / K2
  const size_t F_A4 = 7077888;        // r / V2 / x1
  const size_t F_A5 = 8257536;        // rec / combined
  const size_t F_BF = 9437184;        // Bf f32 (B,32,N); later V2b bf16 (spans F_BF..F_BF+589824)
  const size_t F_DF = 9732096;        // Df f32 (B,32,N)
  const size_t F_BFT = 10321920;      // Bft bf16 (B,N,32): 147456 float-slots
  const size_t F_DFB = 10469376;      // Dfb bf16 (B,32,N): 147456 float-slots (ends at F_ATT1)
  const size_t F_ATT1 = 10616832;
  const size_t F_ATT2 = 10911744;     // att2 f32 (B,128,N)
  const size_t F_QT = 12091392;       // Qt bf16 (B,N,128): 589824 slots
  const size_t F_K2T = 12681216;      // K2t bf16 (B,N,128): 589824 slots (ends at 13271040)
  const size_t F_STATS = 13271040;    // mean[256], var[256], tau[1024]
  float* mean = ws + F_STATS;
  float* var = ws + F_STATS + 256;
  float* tau = ws + F_STATS + 512;

  dim3 blk(256);
  int ewBCN = (BCN + 255) / 256;  // 4608
  const int GX = BNTOT / 256;     // 36

  // --- recurrent path ---
  rope_kernel<<<ewBCN, blk, 0, stream>>>(x, ws + F_A2);
  conv1x1_kernel<0><<<dim3(GX, 16), blk, 0, stream>>>(ws + F_A2, k_w, k_b, nullptr, kden, 128, 128);
  conv1x1_kernel<0><<<dim3(GX, 16), blk, 0, stream>>>(ws + F_A2, v_w, v_b, nullptr, ws + F_A3, 128, 128);
  conv1x1_kernel<2><<<dim3(GX, 16), blk, 0, stream>>>(x, r_w, r_b, nullptr, ws + F_A4, 128, 128);
  recwkv_kernel<<<ewBCN, blk, 0, stream>>>(ws + F_A4, kden, ws + F_A3, u, knum, ws + F_A5);

  // --- dense block (fused BN+ReLU+conv3x3, incremental stats) ---
  copyx_kernel<<<ewBCN, blk, 0, stream>>>(x, ws + F_FEATS);
  bn_stats_kernel<<<128, blk, 0, stream>>>(ws + F_FEATS, 0, mean, var);
  int cins[4] = {128, 160, 192, 224};
  for (int i = 0; i < 4; ++i) {
    int cin = cins[i];
    conv3x3_bn_kernel<<<dim3(GX, 8), blk, 0, stream>>>(
        ws + F_FEATS, cin, mean, var, db_g[i], db_b[i], db_w[i], db_cb[i],
        ws + F_FEATS + (size_t)cin * NSP);
    if (i < 3)
      bn_stats_kernel<<<32, blk, 0, stream>>>(ws + F_FEATS, cin, mean, var);
  }

  // --- spike path ---
  conv1x1_kernel<1><<<dim3(GX, 8), blk, 0, stream>>>(ws + F_FEATS, sn1_w, sn1_b, nullptr, ws + F_A2, 256, 64);
  conv1x1_kernel<2><<<dim3(GX, 32), blk, 0, stream>>>(ws + F_A2, sn2_w, sn2_b, nullptr, ws + F_HBUF, 64, 256);
  tau_kernel<<<BB * DCC, blk, 0, stream>>>(ws + F_HBUF, tau);
  sf_kernel<<<(BB * DCC * NSP + 255) / 256, blk, 0, stream>>>(ws + F_FEATS, tau, ws + F_HBUF);
  conv1x1_kernel<0><<<dim3(GX, 4), blk, 0, stream>>>(ws + F_HBUF, lb_w, lb_b, nullptr, ws + F_BF, 256, 32);
  conv1x1_kernel<0><<<dim3(GX, 4), blk, 0, stream>>>(ws + F_HBUF, ld_w, ld_b, nullptr, ws + F_DF, 256, 32);
  // bf16 attention #1 (Bf is both Q and K; Df is V; scale = 1)
  __bf16* Bft = (__bf16*)(ws + F_BFT);
  __bf16* Dfb = (__bf16*)(ws + F_DFB);
  trans_bf16_kernel<<<(BB * NSP * 32 + 255) / 256, blk, 0, stream>>>(ws + F_BF, Bft, 32, 1.0f);
  cvt_bf16_kernel<<<(BB * 32 * NSP + 255) / 256, blk, 0, stream>>>(ws + F_DF, Dfb, BB * 32 * NSP);
  attn_mfma_kernel<32><<<dim3(NSP / 16, BB), dim3(64), 0, stream>>>(Bft, Bft, Dfb, ws + F_ATT1);
  // combined = rec + conv1x1(att1, ps)
  conv1x1_kernel<0><<<dim3(GX, 16), blk, 0, stream>>>(ws + F_ATT1, ps_w, ps_b, ws + F_A5, ws + F_A5, 32, 128);

  // --- final attention (bf16 MFMA) ---
  conv1x1_kernel<0><<<dim3(GX, 16), blk, 0, stream>>>(ws + F_A5, pq_w, pq_b, nullptr, ws + F_A2, 128, 128);
  conv1x1_kernel<0><<<dim3(GX, 16), blk, 0, stream>>>(ws + F_A5, k_w, k_b, nullptr, ws + F_A3, 128, 128);
  conv1x1_kernel<0><<<dim3(GX, 16), blk, 0, stream>>>(ws + F_A5, v_w, v_b, nullptr, ws + F_A4, 128, 128);
  __bf16* Qt = (__bf16*)(ws + F_QT);
  __bf16* K2t = (__bf16*)(ws + F_K2T);
  __bf16* V2b = (__bf16*)(ws + F_BF);  // overlays dead Bf/Df f32
  trans_bf16_kernel<<<ewBCN, blk, 0, stream>>>(ws + F_A2, Qt, 128, 0.08838834764831845f);
  trans_bf16_kernel<<<ewBCN, blk, 0, stream>>>(ws + F_A3, K2t, 128, 1.0f);
  cvt_bf16_kernel<<<ewBCN, blk, 0, stream>>>(ws + F_A4, V2b, BCN);
  attn_mfma_kernel<128><<<dim3(NSP / 16, BB), dim3(64), 0, stream>>>(Qt, K2t, V2b, ws + F_ATT2);

  // --- FFN tail ---
  add_kernel<<<ewBCN, blk, 0, stream>>>(x, ws + F_ATT2, ws + F_A4, BCN);  // x1
  conv1x1_kernel<3><<<dim3(GX, 64), blk, 0, stream>>>(ws + F_A4, fc1_w, fc1_b, nullptr, ws + F_FEATS, 128, 512);
  conv1x1_kernel<0><<<dim3(GX, 16), blk, 0, stream>>>(ws + F_FEATS, fc2_w, fc2_b, ws + F_A4, outp, 512, 128);
}

// Round 5
// 1073.186 us; speedup vs baseline: 2.0131x; 1.4086x over previous
//
#include <hip/hip_runtime.h>
#include <math.h>

#define BB 4
#define CC 128
#define HH 48
#define WW 48
#define NSP (HH*WW)          // 2304
#define DCC 256
#define BCN (BB*CC*NSP)      // 1179648
#define BNTOT (BB*NSP)       // 9216

typedef float f32x4 __attribute__((ext_vector_type(4)));
typedef __bf16 bf16x8 __attribute__((ext_vector_type(8)));

__device__ __forceinline__ float sigmf(float v) { return 1.0f / (1.0f + expf(-v)); }

// ---------------- RoPE ----------------
__global__ __launch_bounds__(256) void rope_kernel(const float* __restrict__ x,
                                                   float* __restrict__ o) {
  int idx = blockIdx.x * 256 + threadIdx.x;
  if (idx >= BCN) return;
  int n = idx % NSP;
  int c = (idx / NSP) % CC;
  int b = idx / (NSP * CC);
  int h = n / WW, w = n % WW;
  int i = c >> 1;
  float theta = expf(-9.2103403719761836f * ((float)i) / 64.0f);  // 1/10000^(i/64)
  float pos = (float)(h + w) * theta;
  float cs = cosf(pos), sn = sinf(pos);
  size_t base = ((size_t)b * CC + (i << 1)) * NSP + n;
  float re = x[base], im = x[base + NSP];
  o[idx] = (c & 1) ? (re * sn + im * cs) : (re * cs - im * sn);
}

// ---------------- conv1x1 (GEMM over positions), ACT: 0 none, 1 relu, 2 sigmoid, 3 relu^2
template <int ACT>
__global__ __launch_bounds__(256) void conv1x1_kernel(
    const float* __restrict__ in, const float* __restrict__ w,
    const float* __restrict__ bias, const float* __restrict__ addsrc,
    float* __restrict__ out, int Cin, int O) {
  int t = blockIdx.x * 256 + threadIdx.x;  // over B*NSP (exact)
  int b = t / NSP, n = t % NSP;
  int o0 = blockIdx.y * 8;
  float acc[8];
#pragma unroll
  for (int j = 0; j < 8; ++j) acc[j] = bias[o0 + j];
  const float* xin = in + (size_t)b * Cin * NSP + n;
  const float* wp = w + (size_t)o0 * Cin;
  for (int c = 0; c < Cin; ++c) {
    float xv = xin[(size_t)c * NSP];
#pragma unroll
    for (int j = 0; j < 8; ++j) acc[j] += wp[(size_t)j * Cin + c] * xv;
  }
#pragma unroll
  for (int j = 0; j < 8; ++j) {
    float v = acc[j];
    if (ACT == 1) v = fmaxf(v, 0.0f);
    else if (ACT == 2) v = sigmf(v);
    else if (ACT == 3) { v = fmaxf(v, 0.0f); v = v * v; }
    size_t oi = ((size_t)b * O + o0 + j) * NSP + n;
    if (addsrc) v += addsrc[oi];
    out[oi] = v;
  }
}

// ---------------- batchnorm stats (per channel over B,H,W), channel offset ----------------
__global__ __launch_bounds__(256) void bn_stats_kernel(const float* __restrict__ feats, int coff,
                                                       float* __restrict__ mean,
                                                       float* __restrict__ var) {
  int c = coff + blockIdx.x;
  float s = 0.0f, s2 = 0.0f;
  for (int i = threadIdx.x; i < BB * NSP; i += 256) {
    int b = i / NSP, n = i % NSP;
    float v = feats[((size_t)b * DCC + c) * NSP + n];
    s += v;
    s2 += v * v;
  }
  __shared__ float rs[4], rs2[4];
#pragma unroll
  for (int off = 32; off > 0; off >>= 1) {
    s += __shfl_down(s, off);
    s2 += __shfl_down(s2, off);
  }
  int wid = threadIdx.x >> 6;
  if ((threadIdx.x & 63) == 0) { rs[wid] = s; rs2[wid] = s2; }
  __syncthreads();
  if (threadIdx.x == 0) {
    float S = rs[0] + rs[1] + rs[2] + rs[3];
    float S2 = rs2[0] + rs2[1] + rs2[2] + rs2[3];
    float m = S / (float)(BB * NSP);
    mean[c] = m;
    var[c] = S2 / (float)(BB * NSP) - m * m;
  }
}

// ---------------- dense-block prepasses ----------------
// BN+ReLU all Cin channels -> ht (B, NSP, DCC-stride) bf16 (per-layer affine params)
__global__ __launch_bounds__(256) void bnrelu_t_kernel(
    const float* __restrict__ feats, const float* __restrict__ mean,
    const float* __restrict__ var, const float* __restrict__ g,
    const float* __restrict__ bb, __bf16* __restrict__ ht, int Cin) {
  int idx = blockIdx.x * 256 + threadIdx.x;
  int tot = BB * NSP * Cin;
  if (idx >= tot) return;
  int c = idx % Cin;
  int n = (idx / Cin) % NSP;
  int b = idx / (Cin * NSP);
  float v = feats[((size_t)b * DCC + c) * NSP + n];
  float sc_ = rsqrtf(var[c] + 1e-5f) * g[c];
  float sh_ = bb[c] - mean[c] * sc_;
  ht[((size_t)b * NSP + n) * DCC + c] = (__bf16)fmaxf(v * sc_ + sh_, 0.0f);
}

// db_w (32, Cin, 3, 3) f32 -> wb[tap][o][c] bf16
__global__ __launch_bounds__(256) void packw_kernel(const float* __restrict__ w,
                                                    __bf16* __restrict__ wb, int Cin) {
  int idx = blockIdx.x * 256 + threadIdx.x;
  if (idx >= 9 * 32 * Cin) return;
  int c = idx % Cin;
  int o = (idx / Cin) % 32;
  int tap = idx / (Cin * 32);
  wb[idx] = (__bf16)w[((size_t)o * Cin + c) * 9 + tap];
}

// ---------------- conv3x3 as 9 shifted MFMA GEMMs ----------------
// ht: (B, NSP, DCC) bf16 BN-ReLU'd input; wb: [9][32][Cin] bf16; out ch [cout0,cout0+32)
template <int Cin>
__global__ __launch_bounds__(64) void conv3x3_mfma_kernel(
    const __bf16* __restrict__ ht, const __bf16* __restrict__ wb,
    const float* __restrict__ cb, float* __restrict__ feats, int cout0) {
  int lane = threadIdx.x;
  int m15 = lane & 15, quad = lane >> 4;
  int b = blockIdx.y;
  int n0 = blockIdx.x * 16;
  int n = n0 + m15;
  int h = n / WW, w = n % WW;
  f32x4 of0 = (f32x4){0.f, 0.f, 0.f, 0.f};
  f32x4 of1 = (f32x4){0.f, 0.f, 0.f, 0.f};
  const __bf16* htb = ht + (size_t)b * NSP * DCC;
  const bf16x8 zf = {};
#pragma unroll
  for (int tap = 0; tap < 9; ++tap) {
    const int dh = tap / 3 - 1, dw = tap % 3 - 1;
    bool valid = ((unsigned)(h + dh) < HH) && ((unsigned)(w + dw) < WW);
    int pa = valid ? (n + dh * WW + dw) : 0;
    const __bf16* hrow = htb + (size_t)pa * DCC + quad * 8;
    const __bf16* wt = wb + tap * 32 * Cin + quad * 8;
#pragma unroll
    for (int kc = 0; kc < Cin; kc += 32) {
      bf16x8 bfr = *(const bf16x8*)(hrow + kc);
      if (!valid) bfr = zf;
      bf16x8 a0 = *(const bf16x8*)(wt + m15 * Cin + kc);
      bf16x8 a1 = *(const bf16x8*)(wt + (16 + m15) * Cin + kc);
      of0 = __builtin_amdgcn_mfma_f32_16x16x32_bf16(a0, bfr, of0, 0, 0, 0);
      of1 = __builtin_amdgcn_mfma_f32_16x16x32_bf16(a1, bfr, of1, 0, 0, 0);
    }
  }
  // D: row (quad*4+reg) = out-ch, col (m15) = position
#pragma unroll
  for (int reg = 0; reg < 4; ++reg) {
    int o = quad * 4 + reg;
    feats[((size_t)b * DCC + cout0 + o) * NSP + n] = of0[reg] + cb[o];
    feats[((size_t)b * DCC + cout0 + 16 + o) * NSP + n] = of1[reg] + cb[16 + o];
  }
}

// ---------------- small elementwise kernels ----------------
__global__ __launch_bounds__(256) void copyx_kernel(const float* __restrict__ x,
                                                    float* __restrict__ feats) {
  int idx = blockIdx.x * 256 + threadIdx.x;
  if (idx >= BCN) return;
  int n = idx % NSP;
  int c = (idx / NSP) % CC;
  int b = idx / (NSP * CC);
  feats[((size_t)b * DCC + c) * NSP + n] = x[idx];
}

__global__ __launch_bounds__(256) void add_kernel(const float* __restrict__ a,
                                                  const float* __restrict__ b,
                                                  float* __restrict__ o, int ntot) {
  int idx = blockIdx.x * 256 + threadIdx.x;
  if (idx < ntot) o[idx] = a[idx] + b[idx];
}

// knum = k*v; rec = sigmoid_r * ((k*v + eu*k*v) / (k + eu*k))
__global__ __launch_bounds__(256) void recwkv_kernel(
    const float* __restrict__ r, const float* __restrict__ k,
    const float* __restrict__ v, const float* __restrict__ u,
    float* __restrict__ knum, float* __restrict__ rec) {
  int idx = blockIdx.x * 256 + threadIdx.x;
  if (idx >= BCN) return;
  int c = (idx / NSP) % CC;
  float eu = expf(u[c]);
  float kk = k[idx], vv = v[idx];
  float nv = kk * vv;
  knum[idx] = nv;
  float t = eu * kk;
  rec[idx] = r[idx] * ((nv + t * vv) / (kk + t));
}

__global__ __launch_bounds__(256) void tau_kernel(const float* __restrict__ z2,
                                                  float* __restrict__ tau) {
  int bc = blockIdx.x;  // b*DCC + c
  float s = 0.0f;
  for (int n = threadIdx.x; n < NSP; n += 256) s += z2[(size_t)bc * NSP + n];
  __shared__ float rs[4];
#pragma unroll
  for (int off = 32; off > 0; off >>= 1) s += __shfl_down(s, off);
  int wid = threadIdx.x >> 6;
  if ((threadIdx.x & 63) == 0) rs[wid] = s;
  __syncthreads();
  if (threadIdx.x == 0) tau[bc] = (rs[0] + rs[1] + rs[2] + rs[3]) / (float)NSP;
}

__global__ __launch_bounds__(256) void sf_kernel(const float* __restrict__ feats,
                                                 const float* __restrict__ tau,
                                                 float* __restrict__ sf) {
  int idx = blockIdx.x * 256 + threadIdx.x;
  int tot = BB * DCC * NSP;
  if (idx >= tot) return;
  int c = (idx / NSP) % DCC;
  int b = idx / (NSP * DCC);
  float df = feats[idx];
  float sp = sigmf((df - 1.0f) * 5.0f);
  float e = expf(-1.0f / (tau[b * DCC + c] + 1e-6f));
  sf[idx] = sp * (df * e) + (1.0f - sp) * df;
}

// (B,C,N) f32 -> (B,N,C) bf16, with scale
__global__ __launch_bounds__(256) void trans_bf16_kernel(const float* __restrict__ in,
                                                         __bf16* __restrict__ out, int C,
                                                         float scale) {
  int idx = blockIdx.x * 256 + threadIdx.x;
  int tot = BB * NSP * C;
  if (idx >= tot) return;
  int c = idx % C;
  int n = (idx / C) % NSP;
  int b = idx / (C * NSP);
  out[idx] = (__bf16)(in[((size_t)b * C + c) * NSP + n] * scale);
}

// elementwise f32 -> bf16
__global__ __launch_bounds__(256) void cvt_bf16_kernel(const float* __restrict__ in,
                                                       __bf16* __restrict__ out, int tot) {
  int idx = blockIdx.x * 256 + threadIdx.x;
  if (idx < tot) out[idx] = (__bf16)in[idx];
}

// ---------------- MFMA flash attention (no max-sub: |scores| << 88) ----------------
template <int CD>
__global__ __launch_bounds__(64) void attn_mfma_kernel(
    const __bf16* __restrict__ Qt, const __bf16* __restrict__ Kt,
    const __bf16* __restrict__ Vb, float* __restrict__ outm) {
  constexpr int NC = CD / 16;
  constexpr int KC = CD / 32;
  __shared__ float pt[16][36];
  int lane = threadIdx.x;
  int m15 = lane & 15;
  int quad = lane >> 4;
  int b = blockIdx.y;
  int n0 = blockIdx.x * 16;

  bf16x8 qf[KC];
  const __bf16* qrow = Qt + ((size_t)b * NSP + n0 + m15) * CD + quad * 8;
#pragma unroll
  for (int kc = 0; kc < KC; ++kc) qf[kc] = *(const bf16x8*)(qrow + kc * 32);

  f32x4 of[NC];
#pragma unroll
  for (int i = 0; i < NC; ++i) of[i] = (f32x4){0.f, 0.f, 0.f, 0.f};
  float l0 = 0.f, l1 = 0.f, l2 = 0.f, l3 = 0.f;

  const __bf16* Kb = Kt + (size_t)b * NSP * CD;
  const __bf16* Vbb = Vb + (size_t)b * CD * NSP;

  for (int m0 = 0; m0 < NSP; m0 += 32) {
    f32x4 s[2];
#pragma unroll
    for (int t = 0; t < 2; ++t) {
      f32x4 acc = (f32x4){0.f, 0.f, 0.f, 0.f};
      const __bf16* krow = Kb + (size_t)(m0 + t * 16 + m15) * CD + quad * 8;
#pragma unroll
      for (int kc = 0; kc < KC; ++kc) {
        bf16x8 kf = *(const bf16x8*)(krow + kc * 32);
        acc = __builtin_amdgcn_mfma_f32_16x16x32_bf16(qf[kc], kf, acc, 0, 0, 0);
      }
      s[t] = acc;
    }
#pragma unroll
    for (int t = 0; t < 2; ++t) {
      float e0 = expf(s[t].x), e1 = expf(s[t].y), e2 = expf(s[t].z), e3 = expf(s[t].w);
      l0 += e0; l1 += e1; l2 += e2; l3 += e3;
      pt[quad * 4 + 0][t * 16 + m15] = e0;
      pt[quad * 4 + 1][t * 16 + m15] = e1;
      pt[quad * 4 + 2][t * 16 + m15] = e2;
      pt[quad * 4 + 3][t * 16 + m15] = e3;
    }
    __syncthreads();
    const float* prow = &pt[m15][quad * 8];
    f32x4 pa = *(const f32x4*)(prow);
    f32x4 pb = *(const f32x4*)(prow + 4);
    bf16x8 pf;
    pf[0] = (__bf16)pa.x; pf[1] = (__bf16)pa.y; pf[2] = (__bf16)pa.z; pf[3] = (__bf16)pa.w;
    pf[4] = (__bf16)pb.x; pf[5] = (__bf16)pb.y; pf[6] = (__bf16)pb.z; pf[7] = (__bf16)pb.w;
    __syncthreads();
#pragma unroll
    for (int ct = 0; ct < NC; ++ct) {
      bf16x8 vf = *(const bf16x8*)(Vbb + (size_t)(ct * 16 + m15) * NSP + m0 + quad * 8);
      of[ct] = __builtin_amdgcn_mfma_f32_16x16x32_bf16(pf, vf, of[ct], 0, 0, 0);
    }
  }

#pragma unroll
  for (int off = 1; off < 16; off <<= 1) {
    l0 += __shfl_xor(l0, off);
    l1 += __shfl_xor(l1, off);
    l2 += __shfl_xor(l2, off);
    l3 += __shfl_xor(l3, off);
  }
  float i0 = 1.0f / l0, i1 = 1.0f / l1, i2 = 1.0f / l2, i3 = 1.0f / l3;

#pragma unroll
  for (int ct = 0; ct < NC; ++ct) {
    f32x4 o = of[ct];
    o.x *= i0; o.y *= i1; o.z *= i2; o.w *= i3;
    float* dst = outm + ((size_t)b * CD + ct * 16 + m15) * NSP + n0 + quad * 4;
    *(f32x4*)dst = o;
  }
}

// ---------------- host ----------------
extern "C" void kernel_launch(void* const* d_in, const int* in_sizes, int n_in,
                              void* d_out, int out_size, void* d_ws, size_t ws_size,
                              hipStream_t stream) {
  const float* x = (const float*)d_in[0];
  const float* r_w = (const float*)d_in[1];
  const float* r_b = (const float*)d_in[2];
  const float* k_w = (const float*)d_in[3];
  const float* k_b = (const float*)d_in[4];
  const float* v_w = (const float*)d_in[5];
  const float* v_b = (const float*)d_in[6];
  // d_in[7..10]: wc1/wc2 — dead code (multiplied by zeros in reference)
  const float* u = (const float*)d_in[11];
  const float* sn1_w = (const float*)d_in[12];
  const float* sn1_b = (const float*)d_in[13];
  const float* sn2_w = (const float*)d_in[14];
  const float* sn2_b = (const float*)d_in[15];
  const float* lb_w = (const float*)d_in[16];
  const float* lb_b = (const float*)d_in[17];
  const float* ld_w = (const float*)d_in[18];
  const float* ld_b = (const float*)d_in[19];
  const float* ps_w = (const float*)d_in[20];
  const float* ps_b = (const float*)d_in[21];
  const float* pq_w = (const float*)d_in[22];
  const float* pq_b = (const float*)d_in[23];
  const float* fc1_w = (const float*)d_in[24];
  const float* fc1_b = (const float*)d_in[25];
  const float* fc2_w = (const float*)d_in[26];
  const float* fc2_b = (const float*)d_in[27];
  const float* db_g[4] = {(const float*)d_in[28], (const float*)d_in[32],
                          (const float*)d_in[36], (const float*)d_in[40]};
  const float* db_b[4] = {(const float*)d_in[29], (const float*)d_in[33],
                          (const float*)d_in[37], (const float*)d_in[41]};
  const float* db_w[4] = {(const float*)d_in[30], (const float*)d_in[34],
                          (const float*)d_in[38], (const float*)d_in[42]};
  const float* db_cb[4] = {(const float*)d_in[31], (const float*)d_in[35],
                           (const float*)d_in[39], (const float*)d_in[43]};

  float* outp = (float*)d_out;           // out  (B,C,H,W)
  float* knum = outp + BCN;              // new_num = k*v
  float* kden = outp + 2 * (size_t)BCN;  // new_den = k

  float* ws = (float*)d_ws;
  const size_t F_FEATS = 0;           // (B,256,N)  2359296
  const size_t F_HBUF = 2359296;      // z2 / sf
  const size_t F_A2 = 4718592;        // xrope / Wb(bf16) / z1 / Q
  const size_t F_A3 = 5898240;        // v / ht(bf16, dense block) / K2
  const size_t F_A4 = 7077888;        // r / V2 / x1
  const size_t F_A5 = 8257536;        // rec / combined
  const size_t F_BF = 9437184;        // Bf f32 (B,32,N); later V2b bf16
  const size_t F_DF = 9732096;        // Df f32 (B,32,N)
  const size_t F_BFT = 10321920;      // Bft bf16 (B,N,32)
  const size_t F_DFB = 10469376;      // Dfb bf16 (B,32,N)
  const size_t F_ATT1 = 10616832;
  const size_t F_ATT2 = 10911744;     // att2 f32 (B,128,N)
  const size_t F_QT = 12091392;       // Qt bf16 (B,N,128)
  const size_t F_K2T = 12681216;      // K2t bf16 (B,N,128)
  const size_t F_STATS = 13271040;    // mean[256], var[256], tau[1024]
  float* mean = ws + F_STATS;
  float* var = ws + F_STATS + 256;
  float* tau = ws + F_STATS + 512;

  dim3 blk(256);
  int ewBCN = (BCN + 255) / 256;  // 4608
  const int GX = BNTOT / 256;     // 36

  // --- recurrent path ---
  rope_kernel<<<ewBCN, blk, 0, stream>>>(x, ws + F_A2);
  conv1x1_kernel<0><<<dim3(GX, 16), blk, 0, stream>>>(ws + F_A2, k_w, k_b, nullptr, kden, 128, 128);
  conv1x1_kernel<0><<<dim3(GX, 16), blk, 0, stream>>>(ws + F_A2, v_w, v_b, nullptr, ws + F_A3, 128, 128);
  conv1x1_kernel<2><<<dim3(GX, 16), blk, 0, stream>>>(x, r_w, r_b, nullptr, ws + F_A4, 128, 128);
  recwkv_kernel<<<ewBCN, blk, 0, stream>>>(ws + F_A4, kden, ws + F_A3, u, knum, ws + F_A5);

  // --- dense block (MFMA conv3x3 over bf16 BN-ReLU'd input) ---
  copyx_kernel<<<ewBCN, blk, 0, stream>>>(x, ws + F_FEATS);
  bn_stats_kernel<<<128, blk, 0, stream>>>(ws + F_FEATS, 0, mean, var);
  __bf16* ht = (__bf16*)(ws + F_A3);   // (B,NSP,DCC) bf16 = 1179648 f32-slots, overlays dead v
  __bf16* Wb = (__bf16*)(ws + F_A2);   // [9][32][Cin] bf16, overlays dead xrope
  int cins[4] = {128, 160, 192, 224};
  for (int i = 0; i < 4; ++i) {
    int cin = cins[i];
    packw_kernel<<<(9 * 32 * cin + 255) / 256, blk, 0, stream>>>(db_w[i], Wb, cin);
    bnrelu_t_kernel<<<(BB * NSP * cin + 255) / 256, blk, 0, stream>>>(
        ws + F_FEATS, mean, var, db_g[i], db_b[i], ht, cin);
    switch (cin) {
      case 128: conv3x3_mfma_kernel<128><<<dim3(NSP / 16, BB), dim3(64), 0, stream>>>(ht, Wb, db_cb[i], ws + F_FEATS, cin); break;
      case 160: conv3x3_mfma_kernel<160><<<dim3(NSP / 16, BB), dim3(64), 0, stream>>>(ht, Wb, db_cb[i], ws + F_FEATS, cin); break;
      case 192: conv3x3_mfma_kernel<192><<<dim3(NSP / 16, BB), dim3(64), 0, stream>>>(ht, Wb, db_cb[i], ws + F_FEATS, cin); break;
      default:  conv3x3_mfma_kernel<224><<<dim3(NSP / 16, BB), dim3(64), 0, stream>>>(ht, Wb, db_cb[i], ws + F_FEATS, cin); break;
    }
    if (i < 3)
      bn_stats_kernel<<<32, blk, 0, stream>>>(ws + F_FEATS, cin, mean, var);
  }

  // --- spike path ---
  conv1x1_kernel<1><<<dim3(GX, 8), blk, 0, stream>>>(ws + F_FEATS, sn1_w, sn1_b, nullptr, ws + F_A2, 256, 64);
  conv1x1_kernel<2><<<dim3(GX, 32), blk, 0, stream>>>(ws + F_A2, sn2_w, sn2_b, nullptr, ws + F_HBUF, 64, 256);
  tau_kernel<<<BB * DCC, blk, 0, stream>>>(ws + F_HBUF, tau);
  sf_kernel<<<(BB * DCC * NSP + 255) / 256, blk, 0, stream>>>(ws + F_FEATS, tau, ws + F_HBUF);
  conv1x1_kernel<0><<<dim3(GX, 4), blk, 0, stream>>>(ws + F_HBUF, lb_w, lb_b, nullptr, ws + F_BF, 256, 32);
  conv1x1_kernel<0><<<dim3(GX, 4), blk, 0, stream>>>(ws + F_HBUF, ld_w, ld_b, nullptr, ws + F_DF, 256, 32);
  __bf16* Bft = (__bf16*)(ws + F_BFT);
  __bf16* Dfb = (__bf16*)(ws + F_DFB);
  trans_bf16_kernel<<<(BB * NSP * 32 + 255) / 256, blk, 0, stream>>>(ws + F_BF, Bft, 32, 1.0f);
  cvt_bf16_kernel<<<(BB * 32 * NSP + 255) / 256, blk, 0, stream>>>(ws + F_DF, Dfb, BB * 32 * NSP);
  attn_mfma_kernel<32><<<dim3(NSP / 16, BB), dim3(64), 0, stream>>>(Bft, Bft, Dfb, ws + F_ATT1);
  conv1x1_kernel<0><<<dim3(GX, 16), blk, 0, stream>>>(ws + F_ATT1, ps_w, ps_b, ws + F_A5, ws + F_A5, 32, 128);

  // --- final attention (bf16 MFMA) ---
  conv1x1_kernel<0><<<dim3(GX, 16), blk, 0, stream>>>(ws + F_A5, pq_w, pq_b, nullptr, ws + F_A2, 128, 128);
  conv1x1_kernel<0><<<dim3(GX, 16), blk, 0, stream>>>(ws + F_A5, k_w, k_b, nullptr, ws + F_A3, 128, 128);
  conv1x1_kernel<0><<<dim3(GX, 16), blk, 0, stream>>>(ws + F_A5, v_w, v_b, nullptr, ws + F_A4, 128, 128);
  __bf16* Qt = (__bf16*)(ws + F_QT);
  __bf16* K2t = (__bf16*)(ws + F_K2T);
  __bf16* V2b = (__bf16*)(ws + F_BF);
  trans_bf16_kernel<<<ewBCN, blk, 0, stream>>>(ws + F_A2, Qt, 128, 0.08838834764831845f);
  trans_bf16_kernel<<<ewBCN, blk, 0, stream>>>(ws + F_A3, K2t, 128, 1.0f);
  cvt_bf16_kernel<<<ewBCN, blk, 0, stream>>>(ws + F_A4, V2b, BCN);
  attn_mfma_kernel<128><<<dim3(NSP / 16, BB), dim3(64), 0, stream>>>(Qt, K2t, V2b, ws + F_ATT2);

  // --- FFN tail ---
  add_kernel<<<ewBCN, blk, 0, stream>>>(x, ws + F_ATT2, ws + F_A4, BCN);  // x1
  conv1x1_kernel<3><<<dim3(GX, 64), blk, 0, stream>>>(ws + F_A4, fc1_w, fc1_b, nullptr, ws + F_FEATS, 128, 512);
  conv1x1_kernel<0><<<dim3(GX, 16), blk, 0, stream>>>(ws + F_FEATS, fc2_w, fc2_b, ws + F_A4, outp, 512, 128);
}

// Round 6
// 1013.909 us; speedup vs baseline: 2.1307x; 1.0585x over previous
//
#include <hip/hip_runtime.h>
#include <math.h>

#define BB 4
#define CC 128
#define HH 48
#define WW 48
#define NSP (HH*WW)          // 2304
#define DCC 256
#define BCN (BB*CC*NSP)      // 1179648
#define BNTOT (BB*NSP)       // 9216

typedef float f32x4 __attribute__((ext_vector_type(4)));
typedef __bf16 bf16x8 __attribute__((ext_vector_type(8)));

__device__ __forceinline__ float sigmf(float v) { return 1.0f / (1.0f + expf(-v)); }

// ---------------- RoPE ----------------
__global__ __launch_bounds__(256) void rope_kernel(const float* __restrict__ x,
                                                   float* __restrict__ o) {
  int idx = blockIdx.x * 256 + threadIdx.x;
  if (idx >= BCN) return;
  int n = idx % NSP;
  int c = (idx / NSP) % CC;
  int b = idx / (NSP * CC);
  int h = n / WW, w = n % WW;
  int i = c >> 1;
  float theta = expf(-9.2103403719761836f * ((float)i) / 64.0f);  // 1/10000^(i/64)
  float pos = (float)(h + w) * theta;
  float cs = cosf(pos), sn = sinf(pos);
  size_t base = ((size_t)b * CC + (i << 1)) * NSP + n;
  float re = x[base], im = x[base + NSP];
  o[idx] = (c & 1) ? (re * sn + im * cs) : (re * cs - im * sn);
}

// ---------------- conv1x1 (GEMM over positions), ACT: 0 none, 1 relu, 2 sigmoid, 3 relu^2
template <int ACT>
__global__ __launch_bounds__(256) void conv1x1_kernel(
    const float* __restrict__ in, const float* __restrict__ w,
    const float* __restrict__ bias, const float* __restrict__ addsrc,
    float* __restrict__ out, int Cin, int O) {
  int t = blockIdx.x * 256 + threadIdx.x;  // over B*NSP (exact)
  int b = t / NSP, n = t % NSP;
  int o0 = blockIdx.y * 8;
  float acc[8];
#pragma unroll
  for (int j = 0; j < 8; ++j) acc[j] = bias[o0 + j];
  const float* xin = in + (size_t)b * Cin * NSP + n;
  const float* wp = w + (size_t)o0 * Cin;
  for (int c = 0; c < Cin; ++c) {
    float xv = xin[(size_t)c * NSP];
#pragma unroll
    for (int j = 0; j < 8; ++j) acc[j] += wp[(size_t)j * Cin + c] * xv;
  }
#pragma unroll
  for (int j = 0; j < 8; ++j) {
    float v = acc[j];
    if (ACT == 1) v = fmaxf(v, 0.0f);
    else if (ACT == 2) v = sigmf(v);
    else if (ACT == 3) { v = fmaxf(v, 0.0f); v = v * v; }
    size_t oi = ((size_t)b * O + o0 + j) * NSP + n;
    if (addsrc) v += addsrc[oi];
    out[oi] = v;
  }
}

// ---------------- batchnorm stats (per channel over B,H,W), channel offset ----------------
__global__ __launch_bounds__(256) void bn_stats_kernel(const float* __restrict__ feats, int coff,
                                                       float* __restrict__ mean,
                                                       float* __restrict__ var) {
  int c = coff + blockIdx.x;
  float s = 0.0f, s2 = 0.0f;
  for (int i = threadIdx.x; i < BB * NSP; i += 256) {
    int b = i / NSP, n = i % NSP;
    float v = feats[((size_t)b * DCC + c) * NSP + n];
    s += v;
    s2 += v * v;
  }
  __shared__ float rs[4], rs2[4];
#pragma unroll
  for (int off = 32; off > 0; off >>= 1) {
    s += __shfl_down(s, off);
    s2 += __shfl_down(s2, off);
  }
  int wid = threadIdx.x >> 6;
  if ((threadIdx.x & 63) == 0) { rs[wid] = s; rs2[wid] = s2; }
  __syncthreads();
  if (threadIdx.x == 0) {
    float S = rs[0] + rs[1] + rs[2] + rs[3];
    float S2 = rs2[0] + rs2[1] + rs2[2] + rs2[3];
    float m = S / (float)(BB * NSP);
    mean[c] = m;
    var[c] = S2 / (float)(BB * NSP) - m * m;
  }
}

// ---------------- dense-block prepasses ----------------
__global__ __launch_bounds__(256) void bnrelu_t_kernel(
    const float* __restrict__ feats, const float* __restrict__ mean,
    const float* __restrict__ var, const float* __restrict__ g,
    const float* __restrict__ bb, __bf16* __restrict__ ht, int Cin) {
  int idx = blockIdx.x * 256 + threadIdx.x;
  int tot = BB * NSP * Cin;
  if (idx >= tot) return;
  int c = idx % Cin;
  int n = (idx / Cin) % NSP;
  int b = idx / (Cin * NSP);
  float v = feats[((size_t)b * DCC + c) * NSP + n];
  float sc_ = rsqrtf(var[c] + 1e-5f) * g[c];
  float sh_ = bb[c] - mean[c] * sc_;
  ht[((size_t)b * NSP + n) * DCC + c] = (__bf16)fmaxf(v * sc_ + sh_, 0.0f);
}

// db_w (32, Cin, 3, 3) f32 -> wb[tap][o][c] bf16
__global__ __launch_bounds__(256) void packw_kernel(const float* __restrict__ w,
                                                    __bf16* __restrict__ wb, int Cin) {
  int idx = blockIdx.x * 256 + threadIdx.x;
  if (idx >= 9 * 32 * Cin) return;
  int c = idx % Cin;
  int o = (idx / Cin) % 32;
  int tap = idx / (Cin * 32);
  wb[idx] = (__bf16)w[((size_t)o * Cin + c) * 9 + tap];
}

// ---------------- conv3x3 as 9 shifted MFMA GEMMs ----------------
template <int Cin>
__global__ __launch_bounds__(64) void conv3x3_mfma_kernel(
    const __bf16* __restrict__ ht, const __bf16* __restrict__ wb,
    const float* __restrict__ cb, float* __restrict__ feats, int cout0) {
  int lane = threadIdx.x;
  int m15 = lane & 15, quad = lane >> 4;
  int b = blockIdx.y;
  int n0 = blockIdx.x * 16;
  int n = n0 + m15;
  int h = n / WW, w = n % WW;
  f32x4 of0 = (f32x4){0.f, 0.f, 0.f, 0.f};
  f32x4 of1 = (f32x4){0.f, 0.f, 0.f, 0.f};
  const __bf16* htb = ht + (size_t)b * NSP * DCC;
  const bf16x8 zf = {};
#pragma unroll
  for (int tap = 0; tap < 9; ++tap) {
    const int dh = tap / 3 - 1, dw = tap % 3 - 1;
    bool valid = ((unsigned)(h + dh) < HH) && ((unsigned)(w + dw) < WW);
    int pa = valid ? (n + dh * WW + dw) : 0;
    const __bf16* hrow = htb + (size_t)pa * DCC + quad * 8;
    const __bf16* wt = wb + tap * 32 * Cin + quad * 8;
#pragma unroll
    for (int kc = 0; kc < Cin; kc += 32) {
      bf16x8 bfr = *(const bf16x8*)(hrow + kc);
      if (!valid) bfr = zf;
      bf16x8 a0 = *(const bf16x8*)(wt + m15 * Cin + kc);
      bf16x8 a1 = *(const bf16x8*)(wt + (16 + m15) * Cin + kc);
      of0 = __builtin_amdgcn_mfma_f32_16x16x32_bf16(a0, bfr, of0, 0, 0, 0);
      of1 = __builtin_amdgcn_mfma_f32_16x16x32_bf16(a1, bfr, of1, 0, 0, 0);
    }
  }
#pragma unroll
  for (int reg = 0; reg < 4; ++reg) {
    int o = quad * 4 + reg;
    feats[((size_t)b * DCC + cout0 + o) * NSP + n] = of0[reg] + cb[o];
    feats[((size_t)b * DCC + cout0 + 16 + o) * NSP + n] = of1[reg] + cb[16 + o];
  }
}

// ---------------- small elementwise kernels ----------------
__global__ __launch_bounds__(256) void copyx_kernel(const float* __restrict__ x,
                                                    float* __restrict__ feats) {
  int idx = blockIdx.x * 256 + threadIdx.x;
  if (idx >= BCN) return;
  int n = idx % NSP;
  int c = (idx / NSP) % CC;
  int b = idx / (NSP * CC);
  feats[((size_t)b * DCC + c) * NSP + n] = x[idx];
}

__global__ __launch_bounds__(256) void add_kernel(const float* __restrict__ a,
                                                  const float* __restrict__ b,
                                                  float* __restrict__ o, int ntot) {
  int idx = blockIdx.x * 256 + threadIdx.x;
  if (idx < ntot) o[idx] = a[idx] + b[idx];
}

// knum = k*v; rec = sigmoid_r * ((k*v + eu*k*v) / (k + eu*k))
__global__ __launch_bounds__(256) void recwkv_kernel(
    const float* __restrict__ r, const float* __restrict__ k,
    const float* __restrict__ v, const float* __restrict__ u,
    float* __restrict__ knum, float* __restrict__ rec) {
  int idx = blockIdx.x * 256 + threadIdx.x;
  if (idx >= BCN) return;
  int c = (idx / NSP) % CC;
  float eu = expf(u[c]);
  float kk = k[idx], vv = v[idx];
  float nv = kk * vv;
  knum[idx] = nv;
  float t = eu * kk;
  rec[idx] = r[idx] * ((nv + t * vv) / (kk + t));
}

__global__ __launch_bounds__(256) void tau_kernel(const float* __restrict__ z2,
                                                  float* __restrict__ tau) {
  int bc = blockIdx.x;  // b*DCC + c
  float s = 0.0f;
  for (int n = threadIdx.x; n < NSP; n += 256) s += z2[(size_t)bc * NSP + n];
  __shared__ float rs[4];
#pragma unroll
  for (int off = 32; off > 0; off >>= 1) s += __shfl_down(s, off);
  int wid = threadIdx.x >> 6;
  if ((threadIdx.x & 63) == 0) rs[wid] = s;
  __syncthreads();
  if (threadIdx.x == 0) tau[bc] = (rs[0] + rs[1] + rs[2] + rs[3]) / (float)NSP;
}

__global__ __launch_bounds__(256) void sf_kernel(const float* __restrict__ feats,
                                                 const float* __restrict__ tau,
                                                 float* __restrict__ sf) {
  int idx = blockIdx.x * 256 + threadIdx.x;
  int tot = BB * DCC * NSP;
  if (idx >= tot) return;
  int c = (idx / NSP) % DCC;
  int b = idx / (NSP * DCC);
  float df = feats[idx];
  float sp = sigmf((df - 1.0f) * 5.0f);
  float e = expf(-1.0f / (tau[b * DCC + c] + 1e-6f));
  sf[idx] = sp * (df * e) + (1.0f - sp) * df;
}

// (B,C,N) f32 -> (B,N,C) bf16, with scale
__global__ __launch_bounds__(256) void trans_bf16_kernel(const float* __restrict__ in,
                                                         __bf16* __restrict__ out, int C,
                                                         float scale) {
  int idx = blockIdx.x * 256 + threadIdx.x;
  int tot = BB * NSP * C;
  if (idx >= tot) return;
  int c = idx % C;
  int n = (idx / C) % NSP;
  int b = idx / (C * NSP);
  out[idx] = (__bf16)(in[((size_t)b * C + c) * NSP + n] * scale);
}

// elementwise f32 -> bf16
__global__ __launch_bounds__(256) void cvt_bf16_kernel(const float* __restrict__ in,
                                                       __bf16* __restrict__ out, int tot) {
  int idx = blockIdx.x * 256 + threadIdx.x;
  if (idx < tot) out[idx] = (__bf16)in[idx];
}

// ---------------- MFMA flash attention, 4 waves/block with key-split ----------------
// No max-sub (|scores| << 88) -> num/den additive over keys -> waves split keys
// and combine partials at the end. Per-wave private LDS transpose buffer;
// no in-loop barriers (same-wave DS ops are in-order, compiler inserts lgkm waits).
template <int CD>
__global__ __launch_bounds__(256) void attn_mfma_kernel(
    const __bf16* __restrict__ Qt, const __bf16* __restrict__ Kt,
    const __bf16* __restrict__ Vb, float* __restrict__ outm) {
  constexpr int NC = CD / 16;
  constexpr int KC = CD / 32;
  constexpr int RW = NC * 4 + 4;   // of partials + 4 row-sum partials
  constexpr int KEYS = NSP / 4;    // 576 keys per wave
  __shared__ float pt[4][16][36];
  __shared__ float red[4][64][RW];
  int tid = threadIdx.x;
  int wv = tid >> 6, lane = tid & 63;
  int m15 = lane & 15, quad = lane >> 4;
  int b = blockIdx.y;
  int n0 = blockIdx.x * 16;

  bf16x8 qf[KC];
  const __bf16* qrow = Qt + ((size_t)b * NSP + n0 + m15) * CD + quad * 8;
#pragma unroll
  for (int kc = 0; kc < KC; ++kc) qf[kc] = *(const bf16x8*)(qrow + kc * 32);

  f32x4 of[NC];
#pragma unroll
  for (int i = 0; i < NC; ++i) of[i] = (f32x4){0.f, 0.f, 0.f, 0.f};
  float l0 = 0.f, l1 = 0.f, l2 = 0.f, l3 = 0.f;

  const __bf16* Kb = Kt + (size_t)b * NSP * CD;
  const __bf16* Vbb = Vb + (size_t)b * CD * NSP;
  float(*ptw)[36] = pt[wv];

  for (int m0 = wv * KEYS; m0 < (wv + 1) * KEYS; m0 += 32) {
    f32x4 s[2];
#pragma unroll
    for (int t = 0; t < 2; ++t) {
      f32x4 acc = (f32x4){0.f, 0.f, 0.f, 0.f};
      const __bf16* krow = Kb + (size_t)(m0 + t * 16 + m15) * CD + quad * 8;
#pragma unroll
      for (int kc = 0; kc < KC; ++kc) {
        bf16x8 kf = *(const bf16x8*)(krow + kc * 32);
        acc = __builtin_amdgcn_mfma_f32_16x16x32_bf16(qf[kc], kf, acc, 0, 0, 0);
      }
      s[t] = acc;
    }
#pragma unroll
    for (int t = 0; t < 2; ++t) {
      float e0 = expf(s[t].x), e1 = expf(s[t].y), e2 = expf(s[t].z), e3 = expf(s[t].w);
      l0 += e0; l1 += e1; l2 += e2; l3 += e3;
      ptw[quad * 4 + 0][t * 16 + m15] = e0;
      ptw[quad * 4 + 1][t * 16 + m15] = e1;
      ptw[quad * 4 + 2][t * 16 + m15] = e2;
      ptw[quad * 4 + 3][t * 16 + m15] = e3;
    }
    const float* prow = &ptw[m15][quad * 8];
    f32x4 pa = *(const f32x4*)(prow);
    f32x4 pb = *(const f32x4*)(prow + 4);
    bf16x8 pf;
    pf[0] = (__bf16)pa.x; pf[1] = (__bf16)pa.y; pf[2] = (__bf16)pa.z; pf[3] = (__bf16)pa.w;
    pf[4] = (__bf16)pb.x; pf[5] = (__bf16)pb.y; pf[6] = (__bf16)pb.z; pf[7] = (__bf16)pb.w;
#pragma unroll
    for (int ct = 0; ct < NC; ++ct) {
      bf16x8 vf = *(const bf16x8*)(Vbb + (size_t)(ct * 16 + m15) * NSP + m0 + quad * 8);
      of[ct] = __builtin_amdgcn_mfma_f32_16x16x32_bf16(pf, vf, of[ct], 0, 0, 0);
    }
  }

  // stash partials
  float* myred = red[wv][lane];
#pragma unroll
  for (int ct = 0; ct < NC; ++ct) {
    myred[ct * 4 + 0] = of[ct].x;
    myred[ct * 4 + 1] = of[ct].y;
    myred[ct * 4 + 2] = of[ct].z;
    myred[ct * 4 + 3] = of[ct].w;
  }
  myred[NC * 4 + 0] = l0; myred[NC * 4 + 1] = l1;
  myred[NC * 4 + 2] = l2; myred[NC * 4 + 3] = l3;
  __syncthreads();

  // combine row-sums (each wave redundantly)
  float L0 = 0.f, L1 = 0.f, L2 = 0.f, L3 = 0.f;
#pragma unroll
  for (int w = 0; w < 4; ++w) {
    L0 += red[w][lane][NC * 4 + 0];
    L1 += red[w][lane][NC * 4 + 1];
    L2 += red[w][lane][NC * 4 + 2];
    L3 += red[w][lane][NC * 4 + 3];
  }
#pragma unroll
  for (int off = 1; off < 16; off <<= 1) {
    L0 += __shfl_xor(L0, off);
    L1 += __shfl_xor(L1, off);
    L2 += __shfl_xor(L2, off);
    L3 += __shfl_xor(L3, off);
  }
  float i0 = 1.0f / L0, i1 = 1.0f / L1, i2 = 1.0f / L2, i3 = 1.0f / L3;

  // each wave writes its slice of output channel-tiles
  constexpr int CPW = (NC + 3) / 4;
#pragma unroll
  for (int ci = 0; ci < CPW; ++ci) {
    int ct = wv * CPW + ci;
    if (ct < NC) {
      f32x4 o;
      o.x = red[0][lane][ct * 4 + 0] + red[1][lane][ct * 4 + 0] +
            red[2][lane][ct * 4 + 0] + red[3][lane][ct * 4 + 0];
      o.y = red[0][lane][ct * 4 + 1] + red[1][lane][ct * 4 + 1] +
            red[2][lane][ct * 4 + 1] + red[3][lane][ct * 4 + 1];
      o.z = red[0][lane][ct * 4 + 2] + red[1][lane][ct * 4 + 2] +
            red[2][lane][ct * 4 + 2] + red[3][lane][ct * 4 + 2];
      o.w = red[0][lane][ct * 4 + 3] + red[1][lane][ct * 4 + 3] +
            red[2][lane][ct * 4 + 3] + red[3][lane][ct * 4 + 3];
      o.x *= i0; o.y *= i1; o.z *= i2; o.w *= i3;
      float* dst = outm + ((size_t)b * CD + ct * 16 + m15) * NSP + n0 + quad * 4;
      *(f32x4*)dst = o;
    }
  }
}

// ---------------- host ----------------
extern "C" void kernel_launch(void* const* d_in, const int* in_sizes, int n_in,
                              void* d_out, int out_size, void* d_ws, size_t ws_size,
                              hipStream_t stream) {
  const float* x = (const float*)d_in[0];
  const float* r_w = (const float*)d_in[1];
  const float* r_b = (const float*)d_in[2];
  const float* k_w = (const float*)d_in[3];
  const float* k_b = (const float*)d_in[4];
  const float* v_w = (const float*)d_in[5];
  const float* v_b = (const float*)d_in[6];
  // d_in[7..10]: wc1/wc2 — dead code (multiplied by zeros in reference)
  const float* u = (const float*)d_in[11];
  const float* sn1_w = (const float*)d_in[12];
  const float* sn1_b = (const float*)d_in[13];
  const float* sn2_w = (const float*)d_in[14];
  const float* sn2_b = (const float*)d_in[15];
  const float* lb_w = (const float*)d_in[16];
  const float* lb_b = (const float*)d_in[17];
  const float* ld_w = (const float*)d_in[18];
  const float* ld_b = (const float*)d_in[19];
  const float* ps_w = (const float*)d_in[20];
  const float* ps_b = (const float*)d_in[21];
  const float* pq_w = (const float*)d_in[22];
  const float* pq_b = (const float*)d_in[23];
  const float* fc1_w = (const float*)d_in[24];
  const float* fc1_b = (const float*)d_in[25];
  const float* fc2_w = (const float*)d_in[26];
  const float* fc2_b = (const float*)d_in[27];
  const float* db_g[4] = {(const float*)d_in[28], (const float*)d_in[32],
                          (const float*)d_in[36], (const float*)d_in[40]};
  const float* db_b[4] = {(const float*)d_in[29], (const float*)d_in[33],
                          (const float*)d_in[37], (const float*)d_in[41]};
  const float* db_w[4] = {(const float*)d_in[30], (const float*)d_in[34],
                          (const float*)d_in[38], (const float*)d_in[42]};
  const float* db_cb[4] = {(const float*)d_in[31], (const float*)d_in[35],
                           (const float*)d_in[39], (const float*)d_in[43]};

  float* outp = (float*)d_out;           // out  (B,C,H,W)
  float* knum = outp + BCN;              // new_num = k*v
  float* kden = outp + 2 * (size_t)BCN;  // new_den = k

  float* ws = (float*)d_ws;
  const size_t F_FEATS = 0;           // (B,256,N)  2359296
  const size_t F_HBUF = 2359296;      // z2 / sf
  const size_t F_A2 = 4718592;        // xrope / Wb(bf16) / z1 / Q
  const size_t F_A3 = 5898240;        // v / ht(bf16, dense block) / K2
  const size_t F_A4 = 7077888;        // r / V2 / x1
  const size_t F_A5 = 8257536;        // rec / combined
  const size_t F_BF = 9437184;        // Bf f32 (B,32,N); later V2b bf16
  const size_t F_DF = 9732096;        // Df f32 (B,32,N)
  const size_t F_BFT = 10321920;      // Bft bf16 (B,N,32)
  const size_t F_DFB = 10469376;      // Dfb bf16 (B,32,N)
  const size_t F_ATT1 = 10616832;
  const size_t F_ATT2 = 10911744;     // att2 f32 (B,128,N)
  const size_t F_QT = 12091392;       // Qt bf16 (B,N,128)
  const size_t F_K2T = 12681216;      // K2t bf16 (B,N,128)
  const size_t F_STATS = 13271040;    // mean[256], var[256], tau[1024]
  float* mean = ws + F_STATS;
  float* var = ws + F_STATS + 256;
  float* tau = ws + F_STATS + 512;

  dim3 blk(256);
  int ewBCN = (BCN + 255) / 256;  // 4608
  const int GX = BNTOT / 256;     // 36

  // --- recurrent path ---
  rope_kernel<<<ewBCN, blk, 0, stream>>>(x, ws + F_A2);
  conv1x1_kernel<0><<<dim3(GX, 16), blk, 0, stream>>>(ws + F_A2, k_w, k_b, nullptr, kden, 128, 128);
  conv1x1_kernel<0><<<dim3(GX, 16), blk, 0, stream>>>(ws + F_A2, v_w, v_b, nullptr, ws + F_A3, 128, 128);
  conv1x1_kernel<2><<<dim3(GX, 16), blk, 0, stream>>>(x, r_w, r_b, nullptr, ws + F_A4, 128, 128);
  recwkv_kernel<<<ewBCN, blk, 0, stream>>>(ws + F_A4, kden, ws + F_A3, u, knum, ws + F_A5);

  // --- dense block (MFMA conv3x3 over bf16 BN-ReLU'd input) ---
  copyx_kernel<<<ewBCN, blk, 0, stream>>>(x, ws + F_FEATS);
  bn_stats_kernel<<<128, blk, 0, stream>>>(ws + F_FEATS, 0, mean, var);
  __bf16* ht = (__bf16*)(ws + F_A3);
  __bf16* Wb = (__bf16*)(ws + F_A2);
  int cins[4] = {128, 160, 192, 224};
  for (int i = 0; i < 4; ++i) {
    int cin = cins[i];
    packw_kernel<<<(9 * 32 * cin + 255) / 256, blk, 0, stream>>>(db_w[i], Wb, cin);
    bnrelu_t_kernel<<<(BB * NSP * cin + 255) / 256, blk, 0, stream>>>(
        ws + F_FEATS, mean, var, db_g[i], db_b[i], ht, cin);
    switch (cin) {
      case 128: conv3x3_mfma_kernel<128><<<dim3(NSP / 16, BB), dim3(64), 0, stream>>>(ht, Wb, db_cb[i], ws + F_FEATS, cin); break;
      case 160: conv3x3_mfma_kernel<160><<<dim3(NSP / 16, BB), dim3(64), 0, stream>>>(ht, Wb, db_cb[i], ws + F_FEATS, cin); break;
      case 192: conv3x3_mfma_kernel<192><<<dim3(NSP / 16, BB), dim3(64), 0, stream>>>(ht, Wb, db_cb[i], ws + F_FEATS, cin); break;
      default:  conv3x3_mfma_kernel<224><<<dim3(NSP / 16, BB), dim3(64), 0, stream>>>(ht, Wb, db_cb[i], ws + F_FEATS, cin); break;
    }
    if (i < 3)
      bn_stats_kernel<<<32, blk, 0, stream>>>(ws + F_FEATS, cin, mean, var);
  }

  // --- spike path ---
  conv1x1_kernel<1><<<dim3(GX, 8), blk, 0, stream>>>(ws + F_FEATS, sn1_w, sn1_b, nullptr, ws + F_A2, 256, 64);
  conv1x1_kernel<2><<<dim3(GX, 32), blk, 0, stream>>>(ws + F_A2, sn2_w, sn2_b, nullptr, ws + F_HBUF, 64, 256);
  tau_kernel<<<BB * DCC, blk, 0, stream>>>(ws + F_HBUF, tau);
  sf_kernel<<<(BB * DCC * NSP + 255) / 256, blk, 0, stream>>>(ws + F_FEATS, tau, ws + F_HBUF);
  conv1x1_kernel<0><<<dim3(GX, 4), blk, 0, stream>>>(ws + F_HBUF, lb_w, lb_b, nullptr, ws + F_BF, 256, 32);
  conv1x1_kernel<0><<<dim3(GX, 4), blk, 0, stream>>>(ws + F_HBUF, ld_w, ld_b, nullptr, ws + F_DF, 256, 32);
  __bf16* Bft = (__bf16*)(ws + F_BFT);
  __bf16* Dfb = (__bf16*)(ws + F_DFB);
  trans_bf16_kernel<<<(BB * NSP * 32 + 255) / 256, blk, 0, stream>>>(ws + F_BF, Bft, 32, 1.0f);
  cvt_bf16_kernel<<<(BB * 32 * NSP + 255) / 256, blk, 0, stream>>>(ws + F_DF, Dfb, BB * 32 * NSP);
  attn_mfma_kernel<32><<<dim3(NSP / 16, BB), dim3(256), 0, stream>>>(Bft, Bft, Dfb, ws + F_ATT1);
  conv1x1_kernel<0><<<dim3(GX, 16), blk, 0, stream>>>(ws + F_ATT1, ps_w, ps_b, ws + F_A5, ws + F_A5, 32, 128);

  // --- final attention (bf16 MFMA) ---
  conv1x1_kernel<0><<<dim3(GX, 16), blk, 0, stream>>>(ws + F_A5, pq_w, pq_b, nullptr, ws + F_A2, 128, 128);
  conv1x1_kernel<0><<<dim3(GX, 16), blk, 0, stream>>>(ws + F_A5, k_w, k_b, nullptr, ws + F_A3, 128, 128);
  conv1x1_kernel<0><<<dim3(GX, 16), blk, 0, stream>>>(ws + F_A5, v_w, v_b, nullptr, ws + F_A4, 128, 128);
  __bf16* Qt = (__bf16*)(ws + F_QT);
  __bf16* K2t = (__bf16*)(ws + F_K2T);
  __bf16* V2b = (__bf16*)(ws + F_BF);
  trans_bf16_kernel<<<ewBCN, blk, 0, stream>>>(ws + F_A2, Qt, 128, 0.08838834764831845f);
  trans_bf16_kernel<<<ewBCN, blk, 0, stream>>>(ws + F_A3, K2t, 128, 1.0f);
  cvt_bf16_kernel<<<ewBCN, blk, 0, stream>>>(ws + F_A4, V2b, BCN);
  attn_mfma_kernel<128><<<dim3(NSP / 16, BB), dim3(256), 0, stream>>>(Qt, K2t, V2b, ws + F_ATT2);

  // --- FFN tail ---
  add_kernel<<<ewBCN, blk, 0, stream>>>(x, ws + F_ATT2, ws + F_A4, BCN);  // x1
  conv1x1_kernel<3><<<dim3(GX, 64), blk, 0, stream>>>(ws + F_A4, fc1_w, fc1_b, nullptr, ws + F_FEATS, 128, 512);
  conv1x1_kernel<0><<<dim3(GX, 16), blk, 0, stream>>>(ws + F_FEATS, fc2_w, fc2_b, ws + F_A4, outp, 512, 128);
}

// Round 7
// 540.442 us; speedup vs baseline: 3.9974x; 1.8761x over previous
//
#include <hip/hip_runtime.h>
#include <math.h>

#define BB 4
#define CC 128
#define HH 48
#define WW 48
#define NSP (HH*WW)          // 2304
#define DCC 256
#define BCN (BB*CC*NSP)      // 1179648
#define BNTOT (BB*NSP)       // 9216

typedef float f32x4 __attribute__((ext_vector_type(4)));
typedef __bf16 bf16x8 __attribute__((ext_vector_type(8)));
typedef __bf16 bf16x4 __attribute__((ext_vector_type(4)));

__device__ __forceinline__ float sigmf(float v) { return 1.0f / (1.0f + expf(-v)); }

// ---------------- LDS-tiled transpose f32(B,C,N) -> bf16(B,N,C), fused elementwise ----------------
// MODE 0: plain  1: RoPE  2: spike-fn (aux = tau)
template <int C, int MODE>
__global__ __launch_bounds__(256) void trans_kernel(const float* __restrict__ in,
                                                    __bf16* __restrict__ out,
                                                    const float* __restrict__ aux) {
  __shared__ float lds[32][33];
  int b = blockIdx.z;
  int n0 = blockIdx.x * 32;
  int c0 = blockIdx.y * 32;
  int tid = threadIdx.x;
  int nn = tid & 31, cs = tid >> 5;
#pragma unroll
  for (int j = 0; j < 4; ++j) {
    int cc = cs * 4 + j;
    lds[cc][nn] = in[((size_t)b * C + c0 + cc) * NSP + n0 + nn];
  }
  __syncthreads();
  int c = tid & 31, ns = tid >> 5;
#pragma unroll
  for (int j = 0; j < 4; ++j) {
    int n2 = ns * 4 + j;
    float v;
    if (MODE == 1) {
      int gc = c0 + c;
      int i = gc >> 1;
      float re = lds[c & ~1][n2];
      float im = lds[c | 1][n2];
      int n = n0 + n2;
      int h = n / WW, w = n % WW;
      float theta = expf(-9.2103403719761836f * ((float)i) / 64.0f);
      float pos = (float)(h + w) * theta;
      float cs_ = cosf(pos), sn_ = sinf(pos);
      v = (gc & 1) ? (re * sn_ + im * cs_) : (re * cs_ - im * sn_);
    } else if (MODE == 2) {
      float df = lds[c][n2];
      float sp = sigmf((df - 1.0f) * 5.0f);
      float e = expf(-1.0f / (aux[b * C + c0 + c] + 1e-6f));
      v = sp * (df * e) + (1.0f - sp) * df;
    } else {
      v = lds[c][n2];
    }
    out[((size_t)b * NSP + n0 + n2) * C + c0 + c] = (__bf16)v;
  }
}

// ---------------- batched weight f32->bf16 convert ----------------
struct WCvt {
  const float* src[11];
  int len[11];
  int off[11];
};
__global__ __launch_bounds__(256) void wcvt_kernel(WCvt a, __bf16* __restrict__ dst) {
  int g = blockIdx.y;
  int idx = blockIdx.x * 256 + threadIdx.x;
  if (idx < a.len[g]) dst[a.off[g] + idx] = (__bf16)a.src[g][idx];
}

// ---------------- MFMA GEMM: out(B,O,N) = W(O,K) x in_t(B,N,K) ----------------
// ACT: 0 none, 1 relu, 2 sigmoid, 3 relu^2.  OUT: 0 f32 planar, 1 bf16 transposed, 2 bf16 planar.
// v = act(acc + bias) * oscale + addsrc(planar f32, optional)
template <int K, int ACT, int OUT>
__global__ __launch_bounds__(256) void gemm_mfma_kernel(
    const __bf16* __restrict__ in_t, const __bf16* __restrict__ wb,
    const float* __restrict__ bias, const float* __restrict__ addsrc,
    void* __restrict__ outp, int O, float oscale) {
  int tid = threadIdx.x;
  int wv = tid >> 6, lane = tid & 63;
  int m15 = lane & 15, quad = lane >> 4;
  int b = blockIdx.y;
  int n0 = blockIdx.x * 16;
  int o0 = (blockIdx.z * 4 + wv) * 32;
  if (o0 >= O) return;
  int n = n0 + m15;
  const __bf16* brow = in_t + ((size_t)b * NSP + n) * K + quad * 8;
  const __bf16* a0p = wb + (size_t)(o0 + m15) * K + quad * 8;
  const __bf16* a1p = wb + (size_t)(o0 + 16 + m15) * K + quad * 8;
  f32x4 of0 = (f32x4){0.f, 0.f, 0.f, 0.f};
  f32x4 of1 = (f32x4){0.f, 0.f, 0.f, 0.f};
#pragma unroll
  for (int kc = 0; kc < K; kc += 32) {
    bf16x8 bfr = *(const bf16x8*)(brow + kc);
    bf16x8 a0 = *(const bf16x8*)(a0p + kc);
    bf16x8 a1 = *(const bf16x8*)(a1p + kc);
    of0 = __builtin_amdgcn_mfma_f32_16x16x32_bf16(a0, bfr, of0, 0, 0, 0);
    of1 = __builtin_amdgcn_mfma_f32_16x16x32_bf16(a1, bfr, of1, 0, 0, 0);
  }
#pragma unroll
  for (int t = 0; t < 2; ++t) {
    f32x4 acc = t ? of1 : of0;
    float vr[4];
#pragma unroll
    for (int reg = 0; reg < 4; ++reg) {
      int o = o0 + t * 16 + quad * 4 + reg;
      float v = acc[reg] + bias[o];
      if (ACT == 1) v = fmaxf(v, 0.0f);
      else if (ACT == 2) v = sigmf(v);
      else if (ACT == 3) { v = fmaxf(v, 0.0f); v = v * v; }
      v *= oscale;
      if (addsrc) v += addsrc[((size_t)b * O + o) * NSP + n];
      vr[reg] = v;
    }
    if (OUT == 0) {
      float* op = (float*)outp;
#pragma unroll
      for (int reg = 0; reg < 4; ++reg)
        op[((size_t)b * O + o0 + t * 16 + quad * 4 + reg) * NSP + n] = vr[reg];
    } else if (OUT == 1) {
      __bf16* op = (__bf16*)outp;
      bf16x4 pk;
#pragma unroll
      for (int reg = 0; reg < 4; ++reg) pk[reg] = (__bf16)vr[reg];
      *(bf16x4*)(op + ((size_t)b * NSP + n) * O + o0 + t * 16 + quad * 4) = pk;
    } else {
      __bf16* op = (__bf16*)outp;
#pragma unroll
      for (int reg = 0; reg < 4; ++reg)
        op[((size_t)b * O + o0 + t * 16 + quad * 4 + reg) * NSP + n] = (__bf16)vr[reg];
    }
  }
}

// ---------------- batchnorm stats (per channel over B,H,W) ----------------
__global__ __launch_bounds__(256) void bn_stats_kernel(const float* __restrict__ feats, int coff,
                                                       float* __restrict__ mean,
                                                       float* __restrict__ var) {
  int c = coff + blockIdx.x;
  float s = 0.0f, s2 = 0.0f;
  for (int i = threadIdx.x; i < BB * NSP; i += 256) {
    int b = i / NSP, n = i % NSP;
    float v = feats[((size_t)b * DCC + c) * NSP + n];
    s += v;
    s2 += v * v;
  }
  __shared__ float rs[4], rs2[4];
#pragma unroll
  for (int off = 32; off > 0; off >>= 1) {
    s += __shfl_down(s, off);
    s2 += __shfl_down(s2, off);
  }
  int wid = threadIdx.x >> 6;
  if ((threadIdx.x & 63) == 0) { rs[wid] = s; rs2[wid] = s2; }
  __syncthreads();
  if (threadIdx.x == 0) {
    float S = rs[0] + rs[1] + rs[2] + rs[3];
    float S2 = rs2[0] + rs2[1] + rs2[2] + rs2[3];
    float m = S / (float)(BB * NSP);
    mean[c] = m;
    var[c] = S2 / (float)(BB * NSP) - m * m;
  }
}

// ---------------- tiled BN+ReLU -> ht (B,N,DCC-stride) bf16 ----------------
__global__ __launch_bounds__(256) void bnrelu_t_kernel(
    const float* __restrict__ feats, const float* __restrict__ mean,
    const float* __restrict__ var, const float* __restrict__ g,
    const float* __restrict__ bb, __bf16* __restrict__ ht) {
  __shared__ float lds[32][33];
  int b = blockIdx.z;
  int n0 = blockIdx.x * 32;
  int c0 = blockIdx.y * 32;
  int tid = threadIdx.x;
  int nn = tid & 31, cs = tid >> 5;
#pragma unroll
  for (int j = 0; j < 4; ++j) {
    int cc = cs * 4 + j;
    lds[cc][nn] = feats[((size_t)b * DCC + c0 + cc) * NSP + n0 + nn];
  }
  __syncthreads();
  int c = tid & 31, ns = tid >> 5;
  int gc = c0 + c;
  float sc_ = rsqrtf(var[gc] + 1e-5f) * g[gc];
  float sh_ = bb[gc] - mean[gc] * sc_;
#pragma unroll
  for (int j = 0; j < 4; ++j) {
    int n2 = ns * 4 + j;
    float v = fmaxf(lds[c][n2] * sc_ + sh_, 0.0f);
    ht[((size_t)b * NSP + n0 + n2) * DCC + gc] = (__bf16)v;
  }
}

// db_w (32, Cin, 3, 3) f32 -> wb[tap][o][c] bf16
__global__ __launch_bounds__(256) void packw_kernel(const float* __restrict__ w,
                                                    __bf16* __restrict__ wb, int Cin) {
  int idx = blockIdx.x * 256 + threadIdx.x;
  if (idx >= 9 * 32 * Cin) return;
  int c = idx % Cin;
  int o = (idx / Cin) % 32;
  int tap = idx / (Cin * 32);
  wb[idx] = (__bf16)w[((size_t)o * Cin + c) * 9 + tap];
}

// ---------------- conv3x3: 4 waves split tap x K chunks, LDS partial reduce ----------------
template <int Cin>
__global__ __launch_bounds__(256) void conv3x3_mfma_kernel(
    const __bf16* __restrict__ ht, const __bf16* __restrict__ wb,
    const float* __restrict__ cb, float* __restrict__ feats, int cout0) {
  constexpr int KCin = Cin / 32;
  __shared__ float red[4][64][8];
  int tid = threadIdx.x;
  int wv = tid >> 6, lane = tid & 63;
  int m15 = lane & 15, quad = lane >> 4;
  int b = blockIdx.y;
  int n0 = blockIdx.x * 16;
  int n = n0 + m15;
  int h = n / WW, w = n % WW;
  f32x4 of0 = (f32x4){0.f, 0.f, 0.f, 0.f};
  f32x4 of1 = (f32x4){0.f, 0.f, 0.f, 0.f};
  const __bf16* htb = ht + (size_t)b * NSP * DCC;
  const bf16x8 zf = {};
  for (int ci = wv; ci < 9 * KCin; ci += 4) {
    int tap = ci / KCin;
    int kc = (ci % KCin) * 32;
    int dh = tap / 3 - 1, dw = tap % 3 - 1;
    bool valid = ((unsigned)(h + dh) < HH) && ((unsigned)(w + dw) < WW);
    int pa = valid ? (n + dh * WW + dw) : 0;
    bf16x8 bfr = *(const bf16x8*)(htb + (size_t)pa * DCC + kc + quad * 8);
    if (!valid) bfr = zf;
    const __bf16* wt = wb + (size_t)tap * 32 * Cin + kc + quad * 8;
    bf16x8 a0 = *(const bf16x8*)(wt + (size_t)m15 * Cin);
    bf16x8 a1 = *(const bf16x8*)(wt + (size_t)(16 + m15) * Cin);
    of0 = __builtin_amdgcn_mfma_f32_16x16x32_bf16(a0, bfr, of0, 0, 0, 0);
    of1 = __builtin_amdgcn_mfma_f32_16x16x32_bf16(a1, bfr, of1, 0, 0, 0);
  }
  float* myred = red[wv][lane];
#pragma unroll
  for (int reg = 0; reg < 4; ++reg) {
    myred[reg] = of0[reg];
    myred[4 + reg] = of1[reg];
  }
  __syncthreads();
  if (wv == 0) {
#pragma unroll
    for (int reg = 0; reg < 4; ++reg) {
      int o = quad * 4 + reg;
      float s0 = red[0][lane][reg] + red[1][lane][reg] + red[2][lane][reg] + red[3][lane][reg];
      float s1 = red[0][lane][4 + reg] + red[1][lane][4 + reg] + red[2][lane][4 + reg] +
                 red[3][lane][4 + reg];
      feats[((size_t)b * DCC + cout0 + o) * NSP + n] = s0 + cb[o];
      feats[((size_t)b * DCC + cout0 + 16 + o) * NSP + n] = s1 + cb[16 + o];
    }
  }
}

// ---------------- small elementwise kernels ----------------
__global__ __launch_bounds__(256) void copyx_kernel(const float* __restrict__ x,
                                                    float* __restrict__ feats) {
  int idx = blockIdx.x * 256 + threadIdx.x;
  if (idx >= BCN) return;
  int n = idx % NSP;
  int c = (idx / NSP) % CC;
  int b = idx / (NSP * CC);
  feats[((size_t)b * DCC + c) * NSP + n] = x[idx];
}

__global__ __launch_bounds__(256) void add_kernel(const float* __restrict__ a,
                                                  const float* __restrict__ b,
                                                  float* __restrict__ o, int ntot) {
  int idx = blockIdx.x * 256 + threadIdx.x;
  if (idx < ntot) o[idx] = a[idx] + b[idx];
}

// knum = k*v; rec = sigmoid_r * ((k*v + eu*k*v) / (k + eu*k))
__global__ __launch_bounds__(256) void recwkv_kernel(
    const float* __restrict__ r, const float* __restrict__ k,
    const float* __restrict__ v, const float* __restrict__ u,
    float* __restrict__ knum, float* __restrict__ rec) {
  int idx = blockIdx.x * 256 + threadIdx.x;
  if (idx >= BCN) return;
  int c = (idx / NSP) % CC;
  float eu = expf(u[c]);
  float kk = k[idx], vv = v[idx];
  float nv = kk * vv;
  knum[idx] = nv;
  float t = eu * kk;
  rec[idx] = r[idx] * ((nv + t * vv) / (kk + t));
}

__global__ __launch_bounds__(256) void tau_kernel(const float* __restrict__ z2,
                                                  float* __restrict__ tau) {
  int bc = blockIdx.x;  // b*DCC + c
  float s = 0.0f;
  for (int n = threadIdx.x; n < NSP; n += 256) s += z2[(size_t)bc * NSP + n];
  __shared__ float rs[4];
#pragma unroll
  for (int off = 32; off > 0; off >>= 1) s += __shfl_down(s, off);
  int wid = threadIdx.x >> 6;
  if ((threadIdx.x & 63) == 0) rs[wid] = s;
  __syncthreads();
  if (threadIdx.x == 0) tau[bc] = (rs[0] + rs[1] + rs[2] + rs[3]) / (float)NSP;
}

// ---------------- MFMA flash attention, 4 waves/block with key-split ----------------
template <int CD>
__global__ __launch_bounds__(256) void attn_mfma_kernel(
    const __bf16* __restrict__ Qt, const __bf16* __restrict__ Kt,
    const __bf16* __restrict__ Vb, float* __restrict__ outm) {
  constexpr int NC = CD / 16;
  constexpr int KC = CD / 32;
  constexpr int RW = NC * 4 + 4;
  constexpr int KEYS = NSP / 4;
  __shared__ float pt[4][16][36];
  __shared__ float red[4][64][RW];
  int tid = threadIdx.x;
  int wv = tid >> 6, lane = tid & 63;
  int m15 = lane & 15, quad = lane >> 4;
  int b = blockIdx.y;
  int n0 = blockIdx.x * 16;

  bf16x8 qf[KC];
  const __bf16* qrow = Qt + ((size_t)b * NSP + n0 + m15) * CD + quad * 8;
#pragma unroll
  for (int kc = 0; kc < KC; ++kc) qf[kc] = *(const bf16x8*)(qrow + kc * 32);

  f32x4 of[NC];
#pragma unroll
  for (int i = 0; i < NC; ++i) of[i] = (f32x4){0.f, 0.f, 0.f, 0.f};
  float l0 = 0.f, l1 = 0.f, l2 = 0.f, l3 = 0.f;

  const __bf16* Kb = Kt + (size_t)b * NSP * CD;
  const __bf16* Vbb = Vb + (size_t)b * CD * NSP;
  float(*ptw)[36] = pt[wv];

  for (int m0 = wv * KEYS; m0 < (wv + 1) * KEYS; m0 += 32) {
    f32x4 s[2];
#pragma unroll
    for (int t = 0; t < 2; ++t) {
      f32x4 acc = (f32x4){0.f, 0.f, 0.f, 0.f};
      const __bf16* krow = Kb + (size_t)(m0 + t * 16 + m15) * CD + quad * 8;
#pragma unroll
      for (int kc = 0; kc < KC; ++kc) {
        bf16x8 kf = *(const bf16x8*)(krow + kc * 32);
        acc = __builtin_amdgcn_mfma_f32_16x16x32_bf16(qf[kc], kf, acc, 0, 0, 0);
      }
      s[t] = acc;
    }
#pragma unroll
    for (int t = 0; t < 2; ++t) {
      float e0 = expf(s[t].x), e1 = expf(s[t].y), e2 = expf(s[t].z), e3 = expf(s[t].w);
      l0 += e0; l1 += e1; l2 += e2; l3 += e3;
      ptw[quad * 4 + 0][t * 16 + m15] = e0;
      ptw[quad * 4 + 1][t * 16 + m15] = e1;
      ptw[quad * 4 + 2][t * 16 + m15] = e2;
      ptw[quad * 4 + 3][t * 16 + m15] = e3;
    }
    const float* prow = &ptw[m15][quad * 8];
    f32x4 pa = *(const f32x4*)(prow);
    f32x4 pb = *(const f32x4*)(prow + 4);
    bf16x8 pf;
    pf[0] = (__bf16)pa.x; pf[1] = (__bf16)pa.y; pf[2] = (__bf16)pa.z; pf[3] = (__bf16)pa.w;
    pf[4] = (__bf16)pb.x; pf[5] = (__bf16)pb.y; pf[6] = (__bf16)pb.z; pf[7] = (__bf16)pb.w;
#pragma unroll
    for (int ct = 0; ct < NC; ++ct) {
      bf16x8 vf = *(const bf16x8*)(Vbb + (size_t)(ct * 16 + m15) * NSP + m0 + quad * 8);
      of[ct] = __builtin_amdgcn_mfma_f32_16x16x32_bf16(pf, vf, of[ct], 0, 0, 0);
    }
  }

  float* myred = red[wv][lane];
#pragma unroll
  for (int ct = 0; ct < NC; ++ct) {
    myred[ct * 4 + 0] = of[ct].x;
    myred[ct * 4 + 1] = of[ct].y;
    myred[ct * 4 + 2] = of[ct].z;
    myred[ct * 4 + 3] = of[ct].w;
  }
  myred[NC * 4 + 0] = l0; myred[NC * 4 + 1] = l1;
  myred[NC * 4 + 2] = l2; myred[NC * 4 + 3] = l3;
  __syncthreads();

  float L0 = 0.f, L1 = 0.f, L2 = 0.f, L3 = 0.f;
#pragma unroll
  for (int w = 0; w < 4; ++w) {
    L0 += red[w][lane][NC * 4 + 0];
    L1 += red[w][lane][NC * 4 + 1];
    L2 += red[w][lane][NC * 4 + 2];
    L3 += red[w][lane][NC * 4 + 3];
  }
#pragma unroll
  for (int off = 1; off < 16; off <<= 1) {
    L0 += __shfl_xor(L0, off);
    L1 += __shfl_xor(L1, off);
    L2 += __shfl_xor(L2, off);
    L3 += __shfl_xor(L3, off);
  }
  float i0 = 1.0f / L0, i1 = 1.0f / L1, i2 = 1.0f / L2, i3 = 1.0f / L3;

  constexpr int CPW = (NC + 3) / 4;
#pragma unroll
  for (int ci = 0; ci < CPW; ++ci) {
    int ct = wv * CPW + ci;
    if (ct < NC) {
      f32x4 o;
      o.x = red[0][lane][ct * 4 + 0] + red[1][lane][ct * 4 + 0] +
            red[2][lane][ct * 4 + 0] + red[3][lane][ct * 4 + 0];
      o.y = red[0][lane][ct * 4 + 1] + red[1][lane][ct * 4 + 1] +
            red[2][lane][ct * 4 + 1] + red[3][lane][ct * 4 + 1];
      o.z = red[0][lane][ct * 4 + 2] + red[1][lane][ct * 4 + 2] +
            red[2][lane][ct * 4 + 2] + red[3][lane][ct * 4 + 2];
      o.w = red[0][lane][ct * 4 + 3] + red[1][lane][ct * 4 + 3] +
            red[2][lane][ct * 4 + 3] + red[3][lane][ct * 4 + 3];
      o.x *= i0; o.y *= i1; o.z *= i2; o.w *= i3;
      float* dst = outm + ((size_t)b * CD + ct * 16 + m15) * NSP + n0 + quad * 4;
      *(f32x4*)dst = o;
    }
  }
}

// ---------------- host ----------------
extern "C" void kernel_launch(void* const* d_in, const int* in_sizes, int n_in,
                              void* d_out, int out_size, void* d_ws, size_t ws_size,
                              hipStream_t stream) {
  const float* x = (const float*)d_in[0];
  const float* r_w = (const float*)d_in[1];
  const float* r_b = (const float*)d_in[2];
  const float* k_w = (const float*)d_in[3];
  const float* k_b = (const float*)d_in[4];
  const float* v_w = (const float*)d_in[5];
  const float* v_b = (const float*)d_in[6];
  // d_in[7..10]: wc1/wc2 — dead code (multiplied by zeros in reference)
  const float* u = (const float*)d_in[11];
  const float* sn1_w = (const float*)d_in[12];
  const float* sn1_b = (const float*)d_in[13];
  const float* sn2_w = (const float*)d_in[14];
  const float* sn2_b = (const float*)d_in[15];
  const float* lb_w = (const float*)d_in[16];
  const float* lb_b = (const float*)d_in[17];
  const float* ld_w = (const float*)d_in[18];
  const float* ld_b = (const float*)d_in[19];
  const float* ps_w = (const float*)d_in[20];
  const float* ps_b = (const float*)d_in[21];
  const float* pq_w = (const float*)d_in[22];
  const float* pq_b = (const float*)d_in[23];
  const float* fc1_w = (const float*)d_in[24];
  const float* fc1_b = (const float*)d_in[25];
  const float* fc2_w = (const float*)d_in[26];
  const float* fc2_b = (const float*)d_in[27];
  const float* db_g[4] = {(const float*)d_in[28], (const float*)d_in[32],
                          (const float*)d_in[36], (const float*)d_in[40]};
  const float* db_b[4] = {(const float*)d_in[29], (const float*)d_in[33],
                          (const float*)d_in[37], (const float*)d_in[41]};
  const float* db_w[4] = {(const float*)d_in[30], (const float*)d_in[34],
                          (const float*)d_in[38], (const float*)d_in[42]};
  const float* db_cb[4] = {(const float*)d_in[31], (const float*)d_in[35],
                           (const float*)d_in[39], (const float*)d_in[43]};

  float* outp = (float*)d_out;           // out  (B,C,H,W)
  float* knum = outp + BCN;              // new_num = k*v
  float* kden = outp + 2 * (size_t)BCN;  // new_den = k

  float* ws = (float*)d_ws;
  // region map (f32 slots); sequential reuse commented
  const size_t F_FEATS = 0;         // feats f32 (2359296) -> h_t bf16 (B,N,512)
  const size_t F_Z2 = 2359296;      // z2 f32 (2359296) -> x1_t bf16 (B,N,128)
  const size_t F_REC = 4718592;     // rec f32 (1179648)
  const size_t F_V = 5898240;       // v f32 -> ht bf16 -> sf_t bf16 (1179648)
  const size_t F_R = 7077888;       // r f32 -> feats_t bf16 -> V2b bf16 -> x1 f32 (1179648)
  const size_t F_XR = 8257536;      // xrope_t bf16 -> Wb -> z1_t -> att1 f32 -> Qt (589824)
  const size_t F_XT = 8847360;      // x_t bf16 -> Bft -> K2t (589824)
  const size_t F_DFB = 9437184;     // Dfb bf16 (147456)
  const size_t F_AT1T = 9584640;    // att1_t bf16 (147456)
  const size_t F_CT = 9732096;      // combined_t bf16 (589824)
  const size_t F_ATT2 = 10321920;   // att2 f32 (1179648)
  const size_t F_STATS = 11501568;  // mean[256] var[256] tau[1024]
  const size_t F_WB = 11503104;     // conv1x1 weights bf16 (124928 slots)
  float* mean = ws + F_STATS;
  float* var = ws + F_STATS + 256;
  float* tau = ws + F_STATS + 512;
  __bf16* wbase = (__bf16*)(ws + F_WB);
  // bf16-unit offsets into wbase
  const int W_K = 0, W_V = 16384, W_R = 32768, W_SN1 = 49152, W_SN2 = 65536,
            W_LB = 81920, W_LD = 90112, W_PS = 98304, W_PQ = 102400,
            W_FC1 = 118784, W_FC2 = 184320;

  dim3 blk(256);
  int ewBCN = (BCN + 255) / 256;

  // --- weights -> bf16, one launch ---
  WCvt wc;
  wc.src[0] = k_w;   wc.len[0] = 16384; wc.off[0] = W_K;
  wc.src[1] = v_w;   wc.len[1] = 16384; wc.off[1] = W_V;
  wc.src[2] = r_w;   wc.len[2] = 16384; wc.off[2] = W_R;
  wc.src[3] = sn1_w; wc.len[3] = 16384; wc.off[3] = W_SN1;
  wc.src[4] = sn2_w; wc.len[4] = 16384; wc.off[4] = W_SN2;
  wc.src[5] = lb_w;  wc.len[5] = 8192;  wc.off[5] = W_LB;
  wc.src[6] = ld_w;  wc.len[6] = 8192;  wc.off[6] = W_LD;
  wc.src[7] = ps_w;  wc.len[7] = 4096;  wc.off[7] = W_PS;
  wc.src[8] = pq_w;  wc.len[8] = 16384; wc.off[8] = W_PQ;
  wc.src[9] = fc1_w; wc.len[9] = 65536; wc.off[9] = W_FC1;
  wc.src[10] = fc2_w; wc.len[10] = 65536; wc.off[10] = W_FC2;
  wcvt_kernel<<<dim3(256, 11), blk, 0, stream>>>(wc, wbase);

  __bf16* xrope_t = (__bf16*)(ws + F_XR);
  __bf16* x_t = (__bf16*)(ws + F_XT);
  trans_kernel<128, 1><<<dim3(72, 4, 4), blk, 0, stream>>>(x, xrope_t, nullptr);
  trans_kernel<128, 0><<<dim3(72, 4, 4), blk, 0, stream>>>(x, x_t, nullptr);

  // --- recurrent path (k, v, r GEMMs + recwkv) ---
  gemm_mfma_kernel<128, 0, 0><<<dim3(144, 4, 1), blk, 0, stream>>>(
      xrope_t, wbase + W_K, k_b, nullptr, kden, 128, 1.0f);
  gemm_mfma_kernel<128, 0, 0><<<dim3(144, 4, 1), blk, 0, stream>>>(
      xrope_t, wbase + W_V, v_b, nullptr, ws + F_V, 128, 1.0f);
  gemm_mfma_kernel<128, 2, 0><<<dim3(144, 4, 1), blk, 0, stream>>>(
      x_t, wbase + W_R, r_b, nullptr, ws + F_R, 128, 1.0f);
  recwkv_kernel<<<ewBCN, blk, 0, stream>>>(ws + F_R, kden, ws + F_V, u, knum, ws + F_REC);

  // --- dense block ---
  copyx_kernel<<<ewBCN, blk, 0, stream>>>(x, ws + F_FEATS);
  bn_stats_kernel<<<128, blk, 0, stream>>>(ws + F_FEATS, 0, mean, var);
  __bf16* ht = (__bf16*)(ws + F_V);
  __bf16* Wb = (__bf16*)(ws + F_XR);
  int cins[4] = {128, 160, 192, 224};
  for (int i = 0; i < 4; ++i) {
    int cin = cins[i];
    packw_kernel<<<(9 * 32 * cin + 255) / 256, blk, 0, stream>>>(db_w[i], Wb, cin);
    bnrelu_t_kernel<<<dim3(72, cin / 32, 4), blk, 0, stream>>>(
        ws + F_FEATS, mean, var, db_g[i], db_b[i], ht);
    switch (cin) {
      case 128: conv3x3_mfma_kernel<128><<<dim3(144, 4), blk, 0, stream>>>(ht, Wb, db_cb[i], ws + F_FEATS, cin); break;
      case 160: conv3x3_mfma_kernel<160><<<dim3(144, 4), blk, 0, stream>>>(ht, Wb, db_cb[i], ws + F_FEATS, cin); break;
      case 192: conv3x3_mfma_kernel<192><<<dim3(144, 4), blk, 0, stream>>>(ht, Wb, db_cb[i], ws + F_FEATS, cin); break;
      default:  conv3x3_mfma_kernel<224><<<dim3(144, 4), blk, 0, stream>>>(ht, Wb, db_cb[i], ws + F_FEATS, cin); break;
    }
    if (i < 3)
      bn_stats_kernel<<<32, blk, 0, stream>>>(ws + F_FEATS, cin, mean, var);
  }

  // --- spike path ---
  __bf16* feats_t = (__bf16*)(ws + F_R);
  trans_kernel<256, 0><<<dim3(72, 8, 4), blk, 0, stream>>>(ws + F_FEATS, feats_t, nullptr);
  __bf16* z1_t = (__bf16*)(ws + F_XR);
  gemm_mfma_kernel<256, 1, 1><<<dim3(144, 4, 1), blk, 0, stream>>>(
      feats_t, wbase + W_SN1, sn1_b, nullptr, z1_t, 64, 1.0f);
  gemm_mfma_kernel<64, 2, 0><<<dim3(144, 4, 2), blk, 0, stream>>>(
      z1_t, wbase + W_SN2, sn2_b, nullptr, ws + F_Z2, 256, 1.0f);
  tau_kernel<<<BB * DCC, blk, 0, stream>>>(ws + F_Z2, tau);
  __bf16* sf_t = (__bf16*)(ws + F_V);
  trans_kernel<256, 2><<<dim3(72, 8, 4), blk, 0, stream>>>(ws + F_FEATS, sf_t, tau);
  __bf16* Bft = (__bf16*)(ws + F_XT);
  __bf16* Dfb = (__bf16*)(ws + F_DFB);
  gemm_mfma_kernel<256, 0, 1><<<dim3(144, 4, 1), blk, 0, stream>>>(
      sf_t, wbase + W_LB, lb_b, nullptr, Bft, 32, 1.0f);
  gemm_mfma_kernel<256, 0, 2><<<dim3(144, 4, 1), blk, 0, stream>>>(
      sf_t, wbase + W_LD, ld_b, nullptr, Dfb, 32, 1.0f);
  attn_mfma_kernel<32><<<dim3(144, 4), blk, 0, stream>>>(Bft, Bft, Dfb, ws + F_XR);
  __bf16* att1_t = (__bf16*)(ws + F_AT1T);
  trans_kernel<32, 0><<<dim3(72, 1, 4), blk, 0, stream>>>(ws + F_XR, att1_t, nullptr);
  __bf16* comb_t = (__bf16*)(ws + F_CT);
  gemm_mfma_kernel<32, 0, 1><<<dim3(144, 4, 1), blk, 0, stream>>>(
      att1_t, wbase + W_PS, ps_b, ws + F_REC, comb_t, 128, 1.0f);

  // --- final attention ---
  __bf16* Qt = (__bf16*)(ws + F_XR);
  __bf16* K2t = (__bf16*)(ws + F_XT);
  __bf16* V2b = (__bf16*)(ws + F_R);
  gemm_mfma_kernel<128, 0, 1><<<dim3(144, 4, 1), blk, 0, stream>>>(
      comb_t, wbase + W_PQ, pq_b, nullptr, Qt, 128, 0.08838834764831845f);
  gemm_mfma_kernel<128, 0, 1><<<dim3(144, 4, 1), blk, 0, stream>>>(
      comb_t, wbase + W_K, k_b, nullptr, K2t, 128, 1.0f);
  gemm_mfma_kernel<128, 0, 2><<<dim3(144, 4, 1), blk, 0, stream>>>(
      comb_t, wbase + W_V, v_b, nullptr, V2b, 128, 1.0f);
  attn_mfma_kernel<128><<<dim3(144, 4), blk, 0, stream>>>(Qt, K2t, V2b, ws + F_ATT2);

  // --- FFN tail ---
  float* x1 = ws + F_R;
  add_kernel<<<ewBCN, blk, 0, stream>>>(x, ws + F_ATT2, x1, BCN);
  __bf16* x1_t = (__bf16*)(ws + F_Z2);
  trans_kernel<128, 0><<<dim3(72, 4, 4), blk, 0, stream>>>(x1, x1_t, nullptr);
  __bf16* h_t = (__bf16*)(ws + F_FEATS);
  gemm_mfma_kernel<128, 3, 1><<<dim3(144, 4, 4), blk, 0, stream>>>(
      x1_t, wbase + W_FC1, fc1_b, nullptr, h_t, 512, 1.0f);
  gemm_mfma_kernel<512, 0, 0><<<dim3(144, 4, 1), blk, 0, stream>>>(
      h_t, wbase + W_FC2, fc2_b, x1, outp, 128, 1.0f);
}

// Round 8
// 530.520 us; speedup vs baseline: 4.0722x; 1.0187x over previous
//
#include <hip/hip_runtime.h>
#include <math.h>

#define BB 4
#define CC 128
#define HH 48
#define WW 48
#define NSP (HH*WW)          // 2304
#define DCC 256
#define BCN (BB*CC*NSP)      // 1179648
#define BNTOT (BB*NSP)       // 9216

typedef float f32x4 __attribute__((ext_vector_type(4)));
typedef __bf16 bf16x8 __attribute__((ext_vector_type(8)));
typedef __bf16 bf16x4 __attribute__((ext_vector_type(4)));

__device__ __forceinline__ float sigmf(float v) { return 1.0f / (1.0f + expf(-v)); }

// ---------------- LDS-tiled transpose f32(B,C,N) -> bf16(B,N,C), fused elementwise ----------------
// MODE 0: plain  1: RoPE  2: spike-fn (aux = tau)
template <int C, int MODE>
__global__ __launch_bounds__(256) void trans_kernel(const float* __restrict__ in,
                                                    __bf16* __restrict__ out,
                                                    const float* __restrict__ aux) {
  __shared__ float lds[32][33];
  int b = blockIdx.z;
  int n0 = blockIdx.x * 32;
  int c0 = blockIdx.y * 32;
  int tid = threadIdx.x;
  int nn = tid & 31, cs = tid >> 5;
#pragma unroll
  for (int j = 0; j < 4; ++j) {
    int cc = cs * 4 + j;
    lds[cc][nn] = in[((size_t)b * C + c0 + cc) * NSP + n0 + nn];
  }
  __syncthreads();
  int c = tid & 31, ns = tid >> 5;
#pragma unroll
  for (int j = 0; j < 4; ++j) {
    int n2 = ns * 4 + j;
    float v;
    if (MODE == 1) {
      int gc = c0 + c;
      int i = gc >> 1;
      float re = lds[c & ~1][n2];
      float im = lds[c | 1][n2];
      int n = n0 + n2;
      int h = n / WW, w = n % WW;
      float theta = expf(-9.2103403719761836f * ((float)i) / 64.0f);
      float pos = (float)(h + w) * theta;
      float cs_ = cosf(pos), sn_ = sinf(pos);
      v = (gc & 1) ? (re * sn_ + im * cs_) : (re * cs_ - im * sn_);
    } else if (MODE == 2) {
      float df = lds[c][n2];
      float sp = sigmf((df - 1.0f) * 5.0f);
      float e = expf(-1.0f / (aux[b * C + c0 + c] + 1e-6f));
      v = sp * (df * e) + (1.0f - sp) * df;
    } else {
      v = lds[c][n2];
    }
    out[((size_t)b * NSP + n0 + n2) * C + c0 + c] = (__bf16)v;
  }
}

// ---------------- batched weight f32->bf16 convert ----------------
struct WCvt {
  const float* src[11];
  int len[11];
  int off[11];
};
__global__ __launch_bounds__(256) void wcvt_kernel(WCvt a, __bf16* __restrict__ dst) {
  int g = blockIdx.y;
  int idx = blockIdx.x * 256 + threadIdx.x;
  if (idx < a.len[g]) dst[a.off[g] + idx] = (__bf16)a.src[g][idx];
}

// ---------------- MFMA GEMM: out(B,O,N) = W(O,K) x in_t(B,N,K) ----------------
// ACT: 0 none, 1 relu, 2 sigmoid, 3 relu^2.  OUT: 0 f32 planar, 1 bf16 transposed, 2 bf16 planar.
template <int K, int ACT, int OUT>
__global__ __launch_bounds__(256) void gemm_mfma_kernel(
    const __bf16* __restrict__ in_t, const __bf16* __restrict__ wb,
    const float* __restrict__ bias, const float* __restrict__ addsrc,
    void* __restrict__ outp, int O, float oscale) {
  int tid = threadIdx.x;
  int wv = tid >> 6, lane = tid & 63;
  int m15 = lane & 15, quad = lane >> 4;
  int b = blockIdx.y;
  int n0 = blockIdx.x * 16;
  int o0 = (blockIdx.z * 4 + wv) * 32;
  if (o0 >= O) return;
  int n = n0 + m15;
  const __bf16* brow = in_t + ((size_t)b * NSP + n) * K + quad * 8;
  const __bf16* a0p = wb + (size_t)(o0 + m15) * K + quad * 8;
  const __bf16* a1p = wb + (size_t)(o0 + 16 + m15) * K + quad * 8;
  f32x4 of0 = (f32x4){0.f, 0.f, 0.f, 0.f};
  f32x4 of1 = (f32x4){0.f, 0.f, 0.f, 0.f};
#pragma unroll
  for (int kc = 0; kc < K; kc += 32) {
    bf16x8 bfr = *(const bf16x8*)(brow + kc);
    bf16x8 a0 = *(const bf16x8*)(a0p + kc);
    bf16x8 a1 = *(const bf16x8*)(a1p + kc);
    of0 = __builtin_amdgcn_mfma_f32_16x16x32_bf16(a0, bfr, of0, 0, 0, 0);
    of1 = __builtin_amdgcn_mfma_f32_16x16x32_bf16(a1, bfr, of1, 0, 0, 0);
  }
#pragma unroll
  for (int t = 0; t < 2; ++t) {
    f32x4 acc = t ? of1 : of0;
    float vr[4];
#pragma unroll
    for (int reg = 0; reg < 4; ++reg) {
      int o = o0 + t * 16 + quad * 4 + reg;
      float v = acc[reg] + bias[o];
      if (ACT == 1) v = fmaxf(v, 0.0f);
      else if (ACT == 2) v = sigmf(v);
      else if (ACT == 3) { v = fmaxf(v, 0.0f); v = v * v; }
      v *= oscale;
      if (addsrc) v += addsrc[((size_t)b * O + o) * NSP + n];
      vr[reg] = v;
    }
    if (OUT == 0) {
      float* op = (float*)outp;
#pragma unroll
      for (int reg = 0; reg < 4; ++reg)
        op[((size_t)b * O + o0 + t * 16 + quad * 4 + reg) * NSP + n] = vr[reg];
    } else if (OUT == 1) {
      __bf16* op = (__bf16*)outp;
      bf16x4 pk;
#pragma unroll
      for (int reg = 0; reg < 4; ++reg) pk[reg] = (__bf16)vr[reg];
      *(bf16x4*)(op + ((size_t)b * NSP + n) * O + o0 + t * 16 + quad * 4) = pk;
    } else {
      __bf16* op = (__bf16*)outp;
#pragma unroll
      for (int reg = 0; reg < 4; ++reg)
        op[((size_t)b * O + o0 + t * 16 + quad * 4 + reg) * NSP + n] = (__bf16)vr[reg];
    }
  }
}

// ---------------- batchnorm stats (per channel over B,H,W) ----------------
__global__ __launch_bounds__(256) void bn_stats_kernel(const float* __restrict__ feats, int coff,
                                                       float* __restrict__ mean,
                                                       float* __restrict__ var) {
  int c = coff + blockIdx.x;
  float s = 0.0f, s2 = 0.0f;
  for (int i = threadIdx.x; i < BB * NSP; i += 256) {
    int b = i / NSP, n = i % NSP;
    float v = feats[((size_t)b * DCC + c) * NSP + n];
    s += v;
    s2 += v * v;
  }
  __shared__ float rs[4], rs2[4];
#pragma unroll
  for (int off = 32; off > 0; off >>= 1) {
    s += __shfl_down(s, off);
    s2 += __shfl_down(s2, off);
  }
  int wid = threadIdx.x >> 6;
  if ((threadIdx.x & 63) == 0) { rs[wid] = s; rs2[wid] = s2; }
  __syncthreads();
  if (threadIdx.x == 0) {
    float S = rs[0] + rs[1] + rs[2] + rs[3];
    float S2 = rs2[0] + rs2[1] + rs2[2] + rs2[3];
    float m = S / (float)(BB * NSP);
    mean[c] = m;
    var[c] = S2 / (float)(BB * NSP) - m * m;
  }
}

// ---------------- tiled BN+ReLU -> ht (B,N,DCC-stride) bf16 ----------------
__global__ __launch_bounds__(256) void bnrelu_t_kernel(
    const float* __restrict__ feats, const float* __restrict__ mean,
    const float* __restrict__ var, const float* __restrict__ g,
    const float* __restrict__ bb, __bf16* __restrict__ ht) {
  __shared__ float lds[32][33];
  int b = blockIdx.z;
  int n0 = blockIdx.x * 32;
  int c0 = blockIdx.y * 32;
  int tid = threadIdx.x;
  int nn = tid & 31, cs = tid >> 5;
#pragma unroll
  for (int j = 0; j < 4; ++j) {
    int cc = cs * 4 + j;
    lds[cc][nn] = feats[((size_t)b * DCC + c0 + cc) * NSP + n0 + nn];
  }
  __syncthreads();
  int c = tid & 31, ns = tid >> 5;
  int gc = c0 + c;
  float sc_ = rsqrtf(var[gc] + 1e-5f) * g[gc];
  float sh_ = bb[gc] - mean[gc] * sc_;
#pragma unroll
  for (int j = 0; j < 4; ++j) {
    int n2 = ns * 4 + j;
    float v = fmaxf(lds[c][n2] * sc_ + sh_, 0.0f);
    ht[((size_t)b * NSP + n0 + n2) * DCC + gc] = (__bf16)v;
  }
}

// db_w (32, Cin, 3, 3) f32 -> wb[tap][o][c] bf16
__global__ __launch_bounds__(256) void packw_kernel(const float* __restrict__ w,
                                                    __bf16* __restrict__ wb, int Cin) {
  int idx = blockIdx.x * 256 + threadIdx.x;
  if (idx >= 9 * 32 * Cin) return;
  int c = idx % Cin;
  int o = (idx / Cin) % 32;
  int tap = idx / (Cin * 32);
  wb[idx] = (__bf16)w[((size_t)o * Cin + c) * 9 + tap];
}

// ---------------- conv3x3: 4 waves split tap x K chunks, LDS partial reduce ----------------
template <int Cin>
__global__ __launch_bounds__(256) void conv3x3_mfma_kernel(
    const __bf16* __restrict__ ht, const __bf16* __restrict__ wb,
    const float* __restrict__ cb, float* __restrict__ feats, int cout0) {
  constexpr int KCin = Cin / 32;
  __shared__ float red[4][64][8];
  int tid = threadIdx.x;
  int wv = tid >> 6, lane = tid & 63;
  int m15 = lane & 15, quad = lane >> 4;
  int b = blockIdx.y;
  int n0 = blockIdx.x * 16;
  int n = n0 + m15;
  int h = n / WW, w = n % WW;
  f32x4 of0 = (f32x4){0.f, 0.f, 0.f, 0.f};
  f32x4 of1 = (f32x4){0.f, 0.f, 0.f, 0.f};
  const __bf16* htb = ht + (size_t)b * NSP * DCC;
  const bf16x8 zf = {};
  for (int ci = wv; ci < 9 * KCin; ci += 4) {
    int tap = ci / KCin;
    int kc = (ci % KCin) * 32;
    int dh = tap / 3 - 1, dw = tap % 3 - 1;
    bool valid = ((unsigned)(h + dh) < HH) && ((unsigned)(w + dw) < WW);
    int pa = valid ? (n + dh * WW + dw) : 0;
    bf16x8 bfr = *(const bf16x8*)(htb + (size_t)pa * DCC + kc + quad * 8);
    if (!valid) bfr = zf;
    const __bf16* wt = wb + (size_t)tap * 32 * Cin + kc + quad * 8;
    bf16x8 a0 = *(const bf16x8*)(wt + (size_t)m15 * Cin);
    bf16x8 a1 = *(const bf16x8*)(wt + (size_t)(16 + m15) * Cin);
    of0 = __builtin_amdgcn_mfma_f32_16x16x32_bf16(a0, bfr, of0, 0, 0, 0);
    of1 = __builtin_amdgcn_mfma_f32_16x16x32_bf16(a1, bfr, of1, 0, 0, 0);
  }
  float* myred = red[wv][lane];
#pragma unroll
  for (int reg = 0; reg < 4; ++reg) {
    myred[reg] = of0[reg];
    myred[4 + reg] = of1[reg];
  }
  __syncthreads();
  if (wv == 0) {
#pragma unroll
    for (int reg = 0; reg < 4; ++reg) {
      int o = quad * 4 + reg;
      float s0 = red[0][lane][reg] + red[1][lane][reg] + red[2][lane][reg] + red[3][lane][reg];
      float s1 = red[0][lane][4 + reg] + red[1][lane][4 + reg] + red[2][lane][4 + reg] +
                 red[3][lane][4 + reg];
      feats[((size_t)b * DCC + cout0 + o) * NSP + n] = s0 + cb[o];
      feats[((size_t)b * DCC + cout0 + 16 + o) * NSP + n] = s1 + cb[16 + o];
    }
  }
}

// ---------------- small elementwise kernels ----------------
__global__ __launch_bounds__(256) void copyx_kernel(const float* __restrict__ x,
                                                    float* __restrict__ feats) {
  int idx = blockIdx.x * 256 + threadIdx.x;
  if (idx >= BCN) return;
  int n = idx % NSP;
  int c = (idx / NSP) % CC;
  int b = idx / (NSP * CC);
  feats[((size_t)b * DCC + c) * NSP + n] = x[idx];
}

// knum = k*v; rec = sigmoid_r * ((k*v + eu*k*v) / (k + eu*k))
__global__ __launch_bounds__(256) void recwkv_kernel(
    const float* __restrict__ r, const float* __restrict__ k,
    const float* __restrict__ v, const float* __restrict__ u,
    float* __restrict__ knum, float* __restrict__ rec) {
  int idx = blockIdx.x * 256 + threadIdx.x;
  if (idx >= BCN) return;
  int c = (idx / NSP) % CC;
  float eu = expf(u[c]);
  float kk = k[idx], vv = v[idx];
  float nv = kk * vv;
  knum[idx] = nv;
  float t = eu * kk;
  rec[idx] = r[idx] * ((nv + t * vv) / (kk + t));
}

__global__ __launch_bounds__(256) void tau_kernel(const float* __restrict__ z2,
                                                  float* __restrict__ tau) {
  int bc = blockIdx.x;  // b*DCC + c
  float s = 0.0f;
  for (int n = threadIdx.x; n < NSP; n += 256) s += z2[(size_t)bc * NSP + n];
  __shared__ float rs[4];
#pragma unroll
  for (int off = 32; off > 0; off >>= 1) s += __shfl_down(s, off);
  int wid = threadIdx.x >> 6;
  if ((threadIdx.x & 63) == 0) rs[wid] = s;
  __syncthreads();
  if (threadIdx.x == 0) tau[bc] = (rs[0] + rs[1] + rs[2] + rs[3]) / (float)NSP;
}

// ---------------- MFMA attention, key-split ACROSS blocks (KS=8), bf16 partials ----------------
// Writes unnormalized O partials (bf16, planar per ks) + row-sum partials lp.
template <int CD>
__global__ __launch_bounds__(256) void attn_part_kernel(
    const __bf16* __restrict__ Qt, const __bf16* __restrict__ Kt,
    const __bf16* __restrict__ Vb, __bf16* __restrict__ Op,
    float* __restrict__ lp) {
  constexpr int NC = CD / 16;
  constexpr int KC = CD / 32;
  constexpr int KEYS = NSP / 8;  // 288
  __shared__ float pt[4][16][36];
  int tid = threadIdx.x;
  int wv = tid >> 6, lane = tid & 63;
  int m15 = lane & 15, quad = lane >> 4;
  int b = blockIdx.y, ks = blockIdx.z;
  int n0 = blockIdx.x * 64 + wv * 16;

  bf16x8 qf[KC];
  const __bf16* qrow = Qt + ((size_t)b * NSP + n0 + m15) * CD + quad * 8;
#pragma unroll
  for (int kc = 0; kc < KC; ++kc) qf[kc] = *(const bf16x8*)(qrow + kc * 32);

  f32x4 of[NC];
#pragma unroll
  for (int i = 0; i < NC; ++i) of[i] = (f32x4){0.f, 0.f, 0.f, 0.f};
  float l0 = 0.f, l1 = 0.f, l2 = 0.f, l3 = 0.f;

  const __bf16* Kb = Kt + (size_t)b * NSP * CD;
  const __bf16* Vbb = Vb + (size_t)b * CD * NSP;
  float(*ptw)[36] = pt[wv];

  for (int m0 = ks * KEYS; m0 < (ks + 1) * KEYS; m0 += 32) {
    f32x4 s[2];
#pragma unroll
    for (int t = 0; t < 2; ++t) {
      f32x4 acc = (f32x4){0.f, 0.f, 0.f, 0.f};
      const __bf16* krow = Kb + (size_t)(m0 + t * 16 + m15) * CD + quad * 8;
#pragma unroll
      for (int kc = 0; kc < KC; ++kc) {
        bf16x8 kf = *(const bf16x8*)(krow + kc * 32);
        acc = __builtin_amdgcn_mfma_f32_16x16x32_bf16(qf[kc], kf, acc, 0, 0, 0);
      }
      s[t] = acc;
    }
#pragma unroll
    for (int t = 0; t < 2; ++t) {
      float e0 = expf(s[t].x), e1 = expf(s[t].y), e2 = expf(s[t].z), e3 = expf(s[t].w);
      l0 += e0; l1 += e1; l2 += e2; l3 += e3;
      ptw[quad * 4 + 0][t * 16 + m15] = e0;
      ptw[quad * 4 + 1][t * 16 + m15] = e1;
      ptw[quad * 4 + 2][t * 16 + m15] = e2;
      ptw[quad * 4 + 3][t * 16 + m15] = e3;
    }
    const float* prow = &ptw[m15][quad * 8];
    f32x4 pa = *(const f32x4*)(prow);
    f32x4 pb = *(const f32x4*)(prow + 4);
    bf16x8 pf;
    pf[0] = (__bf16)pa.x; pf[1] = (__bf16)pa.y; pf[2] = (__bf16)pa.z; pf[3] = (__bf16)pa.w;
    pf[4] = (__bf16)pb.x; pf[5] = (__bf16)pb.y; pf[6] = (__bf16)pb.z; pf[7] = (__bf16)pb.w;
#pragma unroll
    for (int ct = 0; ct < NC; ++ct) {
      bf16x8 vf = *(const bf16x8*)(Vbb + (size_t)(ct * 16 + m15) * NSP + m0 + quad * 8);
      of[ct] = __builtin_amdgcn_mfma_f32_16x16x32_bf16(pf, vf, of[ct], 0, 0, 0);
    }
  }

  // sum over keys (the 16 m15 lanes of each quad)
#pragma unroll
  for (int off = 1; off < 16; off <<= 1) {
    l0 += __shfl_xor(l0, off);
    l1 += __shfl_xor(l1, off);
    l2 += __shfl_xor(l2, off);
    l3 += __shfl_xor(l3, off);
  }
  float* lpb = lp + (size_t)(ks * BB + b) * NSP + n0;
  if (m15 == 0) {
    lpb[quad * 4 + 0] = l0;
    lpb[quad * 4 + 1] = l1;
    lpb[quad * 4 + 2] = l2;
    lpb[quad * 4 + 3] = l3;
  }
  __bf16* Ob = Op + (size_t)(ks * BB + b) * CD * NSP;
#pragma unroll
  for (int ct = 0; ct < NC; ++ct) {
    bf16x4 pk;
#pragma unroll
    for (int reg = 0; reg < 4; ++reg) pk[reg] = (__bf16)of[ct][reg];
    *(bf16x4*)(Ob + (size_t)(ct * 16 + m15) * NSP + n0 + quad * 4) = pk;
  }
}

// ltot[b][n] = 1 / sum_ks lp[ks][b][n]
__global__ __launch_bounds__(256) void ltot_kernel(const float* __restrict__ lp,
                                                   float* __restrict__ ltot) {
  int idx = blockIdx.x * 256 + threadIdx.x;
  if (idx >= BNTOT) return;
  float s = 0.f;
#pragma unroll
  for (int ks = 0; ks < 8; ++ks) s += lp[(size_t)ks * BNTOT + idx];
  ltot[idx] = 1.0f / s;
}

// combine partials for CD=32 -> att1_t (B,N,32) bf16
__global__ __launch_bounds__(256) void combine32_kernel(const __bf16* __restrict__ Op,
                                                        const float* __restrict__ ltot,
                                                        __bf16* __restrict__ att1_t) {
  __shared__ float lds[32][33];
  int b = blockIdx.z;
  int n0 = blockIdx.x * 32;
  int tid = threadIdx.x;
  int nn = tid & 31, cs = tid >> 5;
  float linv = ltot[b * NSP + n0 + nn];
#pragma unroll
  for (int j = 0; j < 4; ++j) {
    int cc = cs * 4 + j;
    float s = 0.f;
#pragma unroll
    for (int ks = 0; ks < 8; ++ks)
      s += (float)Op[((size_t)(ks * BB + b) * 32 + cc) * NSP + n0 + nn];
    lds[cc][nn] = s * linv;
  }
  __syncthreads();
  int c = tid & 31, ns = tid >> 5;
#pragma unroll
  for (int j = 0; j < 4; ++j) {
    int n2 = ns * 4 + j;
    att1_t[((size_t)b * NSP + n0 + n2) * 32 + c] = (__bf16)lds[c][n2];
  }
}

// combine partials for CD=128, + x residual -> x1 (f32 planar) AND x1_t (bf16 transposed)
__global__ __launch_bounds__(256) void combine128_kernel(
    const __bf16* __restrict__ Op, const float* __restrict__ ltot,
    const float* __restrict__ x, float* __restrict__ x1, __bf16* __restrict__ x1_t) {
  __shared__ float lds[32][33];
  int b = blockIdx.z;
  int n0 = blockIdx.x * 32;
  int c0 = blockIdx.y * 32;
  int tid = threadIdx.x;
  int nn = tid & 31, cs = tid >> 5;
  float linv = ltot[b * NSP + n0 + nn];
#pragma unroll
  for (int j = 0; j < 4; ++j) {
    int gc = c0 + cs * 4 + j;
    float s = 0.f;
#pragma unroll
    for (int ks = 0; ks < 8; ++ks)
      s += (float)Op[((size_t)(ks * BB + b) * CC + gc) * NSP + n0 + nn];
    float v = s * linv + x[((size_t)b * CC + gc) * NSP + n0 + nn];
    lds[cs * 4 + j][nn] = v;
    x1[((size_t)b * CC + gc) * NSP + n0 + nn] = v;
  }
  __syncthreads();
  int c = tid & 31, ns = tid >> 5;
#pragma unroll
  for (int j = 0; j < 4; ++j) {
    int n2 = ns * 4 + j;
    x1_t[((size_t)b * NSP + n0 + n2) * CC + c0 + c] = (__bf16)lds[c][n2];
  }
}

// ---------------- host ----------------
extern "C" void kernel_launch(void* const* d_in, const int* in_sizes, int n_in,
                              void* d_out, int out_size, void* d_ws, size_t ws_size,
                              hipStream_t stream) {
  const float* x = (const float*)d_in[0];
  const float* r_w = (const float*)d_in[1];
  const float* r_b = (const float*)d_in[2];
  const float* k_w = (const float*)d_in[3];
  const float* k_b = (const float*)d_in[4];
  const float* v_w = (const float*)d_in[5];
  const float* v_b = (const float*)d_in[6];
  // d_in[7..10]: wc1/wc2 — dead code (multiplied by zeros in reference)
  const float* u = (const float*)d_in[11];
  const float* sn1_w = (const float*)d_in[12];
  const float* sn1_b = (const float*)d_in[13];
  const float* sn2_w = (const float*)d_in[14];
  const float* sn2_b = (const float*)d_in[15];
  const float* lb_w = (const float*)d_in[16];
  const float* lb_b = (const float*)d_in[17];
  const float* ld_w = (const float*)d_in[18];
  const float* ld_b = (const float*)d_in[19];
  const float* ps_w = (const float*)d_in[20];
  const float* ps_b = (const float*)d_in[21];
  const float* pq_w = (const float*)d_in[22];
  const float* pq_b = (const float*)d_in[23];
  const float* fc1_w = (const float*)d_in[24];
  const float* fc1_b = (const float*)d_in[25];
  const float* fc2_w = (const float*)d_in[26];
  const float* fc2_b = (const float*)d_in[27];
  const float* db_g[4] = {(const float*)d_in[28], (const float*)d_in[32],
                          (const float*)d_in[36], (const float*)d_in[40]};
  const float* db_b[4] = {(const float*)d_in[29], (const float*)d_in[33],
                          (const float*)d_in[37], (const float*)d_in[41]};
  const float* db_w[4] = {(const float*)d_in[30], (const float*)d_in[34],
                          (const float*)d_in[38], (const float*)d_in[42]};
  const float* db_cb[4] = {(const float*)d_in[31], (const float*)d_in[35],
                           (const float*)d_in[39], (const float*)d_in[43]};

  float* outp = (float*)d_out;           // out  (B,C,H,W)
  float* knum = outp + BCN;              // new_num = k*v
  float* kden = outp + 2 * (size_t)BCN;  // new_den = k

  float* ws = (float*)d_ws;
  // region map (f32 slots)
  const size_t F_FEATS = 0;         // feats f32 (2359296) -> Op bf16 partials -> h_t bf16
  const size_t F_Z2 = 2359296;      // z2 f32 (2359296) -> Op (contiguous with F_FEATS)
  const size_t F_REC = 4718592;     // rec f32 (1179648)
  const size_t F_V = 5898240;       // v f32 -> ht bf16 -> sf_t bf16 -> x1_t bf16 (1179648)
  const size_t F_R = 7077888;       // r f32 -> feats_t bf16 -> V2b bf16 -> x1 f32 (1179648)
  const size_t F_XR = 8257536;      // xrope_t bf16 -> Wb -> z1_t -> Qt (589824)
  const size_t F_XT = 8847360;      // x_t bf16 -> Bft -> K2t (589824)
  const size_t F_DFB = 9437184;     // Dfb bf16 (147456)
  const size_t F_AT1T = 9584640;    // att1_t bf16 (147456)
  const size_t F_CT = 9732096;      // combined_t bf16 (589824)
  const size_t F_LP = 10321920;     // lp f32 (73728)
  const size_t F_LTOT = 10395648;   // ltot f32 (9216)
  const size_t F_STATS = 11501568;  // mean[256] var[256] tau[1024]
  const size_t F_WB = 11503104;     // conv1x1 weights bf16
  float* mean = ws + F_STATS;
  float* var = ws + F_STATS + 256;
  float* tau = ws + F_STATS + 512;
  float* lp = ws + F_LP;
  float* ltot = ws + F_LTOT;
  __bf16* wbase = (__bf16*)(ws + F_WB);
  const int W_K = 0, W_V = 16384, W_R = 32768, W_SN1 = 49152, W_SN2 = 65536,
            W_LB = 81920, W_LD = 90112, W_PS = 98304, W_PQ = 102400,
            W_FC1 = 118784, W_FC2 = 184320;

  dim3 blk(256);
  int ewBCN = (BCN + 255) / 256;

  // --- weights -> bf16, one launch ---
  WCvt wc;
  wc.src[0] = k_w;   wc.len[0] = 16384; wc.off[0] = W_K;
  wc.src[1] = v_w;   wc.len[1] = 16384; wc.off[1] = W_V;
  wc.src[2] = r_w;   wc.len[2] = 16384; wc.off[2] = W_R;
  wc.src[3] = sn1_w; wc.len[3] = 16384; wc.off[3] = W_SN1;
  wc.src[4] = sn2_w; wc.len[4] = 16384; wc.off[4] = W_SN2;
  wc.src[5] = lb_w;  wc.len[5] = 8192;  wc.off[5] = W_LB;
  wc.src[6] = ld_w;  wc.len[6] = 8192;  wc.off[6] = W_LD;
  wc.src[7] = ps_w;  wc.len[7] = 4096;  wc.off[7] = W_PS;
  wc.src[8] = pq_w;  wc.len[8] = 16384; wc.off[8] = W_PQ;
  wc.src[9] = fc1_w; wc.len[9] = 65536; wc.off[9] = W_FC1;
  wc.src[10] = fc2_w; wc.len[10] = 65536; wc.off[10] = W_FC2;
  wcvt_kernel<<<dim3(256, 11), blk, 0, stream>>>(wc, wbase);

  __bf16* xrope_t = (__bf16*)(ws + F_XR);
  __bf16* x_t = (__bf16*)(ws + F_XT);
  trans_kernel<128, 1><<<dim3(72, 4, 4), blk, 0, stream>>>(x, xrope_t, nullptr);
  trans_kernel<128, 0><<<dim3(72, 4, 4), blk, 0, stream>>>(x, x_t, nullptr);

  // --- recurrent path ---
  gemm_mfma_kernel<128, 0, 0><<<dim3(144, 4, 1), blk, 0, stream>>>(
      xrope_t, wbase + W_K, k_b, nullptr, kden, 128, 1.0f);
  gemm_mfma_kernel<128, 0, 0><<<dim3(144, 4, 1), blk, 0, stream>>>(
      xrope_t, wbase + W_V, v_b, nullptr, ws + F_V, 128, 1.0f);
  gemm_mfma_kernel<128, 2, 0><<<dim3(144, 4, 1), blk, 0, stream>>>(
      x_t, wbase + W_R, r_b, nullptr, ws + F_R, 128, 1.0f);
  recwkv_kernel<<<ewBCN, blk, 0, stream>>>(ws + F_R, kden, ws + F_V, u, knum, ws + F_REC);

  // --- dense block ---
  copyx_kernel<<<ewBCN, blk, 0, stream>>>(x, ws + F_FEATS);
  bn_stats_kernel<<<128, blk, 0, stream>>>(ws + F_FEATS, 0, mean, var);
  __bf16* ht = (__bf16*)(ws + F_V);
  __bf16* Wb = (__bf16*)(ws + F_XR);
  int cins[4] = {128, 160, 192, 224};
  for (int i = 0; i < 4; ++i) {
    int cin = cins[i];
    packw_kernel<<<(9 * 32 * cin + 255) / 256, blk, 0, stream>>>(db_w[i], Wb, cin);
    bnrelu_t_kernel<<<dim3(72, cin / 32, 4), blk, 0, stream>>>(
        ws + F_FEATS, mean, var, db_g[i], db_b[i], ht);
    switch (cin) {
      case 128: conv3x3_mfma_kernel<128><<<dim3(144, 4), blk, 0, stream>>>(ht, Wb, db_cb[i], ws + F_FEATS, cin); break;
      case 160: conv3x3_mfma_kernel<160><<<dim3(144, 4), blk, 0, stream>>>(ht, Wb, db_cb[i], ws + F_FEATS, cin); break;
      case 192: conv3x3_mfma_kernel<192><<<dim3(144, 4), blk, 0, stream>>>(ht, Wb, db_cb[i], ws + F_FEATS, cin); break;
      default:  conv3x3_mfma_kernel<224><<<dim3(144, 4), blk, 0, stream>>>(ht, Wb, db_cb[i], ws + F_FEATS, cin); break;
    }
    if (i < 3)
      bn_stats_kernel<<<32, blk, 0, stream>>>(ws + F_FEATS, cin, mean, var);
  }

  // --- spike path ---
  __bf16* feats_t = (__bf16*)(ws + F_R);
  trans_kernel<256, 0><<<dim3(72, 8, 4), blk, 0, stream>>>(ws + F_FEATS, feats_t, nullptr);
  __bf16* z1_t = (__bf16*)(ws + F_XR);
  gemm_mfma_kernel<256, 1, 1><<<dim3(144, 4, 1), blk, 0, stream>>>(
      feats_t, wbase + W_SN1, sn1_b, nullptr, z1_t, 64, 1.0f);
  gemm_mfma_kernel<64, 2, 0><<<dim3(144, 4, 2), blk, 0, stream>>>(
      z1_t, wbase + W_SN2, sn2_b, nullptr, ws + F_Z2, 256, 1.0f);
  tau_kernel<<<BB * DCC, blk, 0, stream>>>(ws + F_Z2, tau);
  __bf16* sf_t = (__bf16*)(ws + F_V);
  trans_kernel<256, 2><<<dim3(72, 8, 4), blk, 0, stream>>>(ws + F_FEATS, sf_t, tau);
  __bf16* Bft = (__bf16*)(ws + F_XT);
  __bf16* Dfb = (__bf16*)(ws + F_DFB);
  gemm_mfma_kernel<256, 0, 1><<<dim3(144, 4, 1), blk, 0, stream>>>(
      sf_t, wbase + W_LB, lb_b, nullptr, Bft, 32, 1.0f);
  gemm_mfma_kernel<256, 0, 2><<<dim3(144, 4, 1), blk, 0, stream>>>(
      sf_t, wbase + W_LD, ld_b, nullptr, Dfb, 32, 1.0f);
  __bf16* Opart = (__bf16*)(ws + F_FEATS);  // feats f32 dead from here
  attn_part_kernel<32><<<dim3(36, 4, 8), blk, 0, stream>>>(Bft, Bft, Dfb, Opart, lp);
  ltot_kernel<<<36, blk, 0, stream>>>(lp, ltot);
  __bf16* att1_t = (__bf16*)(ws + F_AT1T);
  combine32_kernel<<<dim3(72, 1, 4), blk, 0, stream>>>(Opart, ltot, att1_t);
  __bf16* comb_t = (__bf16*)(ws + F_CT);
  gemm_mfma_kernel<32, 0, 1><<<dim3(144, 4, 1), blk, 0, stream>>>(
      att1_t, wbase + W_PS, ps_b, ws + F_REC, comb_t, 128, 1.0f);

  // --- final attention ---
  __bf16* Qt = (__bf16*)(ws + F_XR);
  __bf16* K2t = (__bf16*)(ws + F_XT);
  __bf16* V2b = (__bf16*)(ws + F_R);
  gemm_mfma_kernel<128, 0, 1><<<dim3(144, 4, 1), blk, 0, stream>>>(
      comb_t, wbase + W_PQ, pq_b, nullptr, Qt, 128, 0.08838834764831845f);
  gemm_mfma_kernel<128, 0, 1><<<dim3(144, 4, 1), blk, 0, stream>>>(
      comb_t, wbase + W_K, k_b, nullptr, K2t, 128, 1.0f);
  gemm_mfma_kernel<128, 0, 2><<<dim3(144, 4, 1), blk, 0, stream>>>(
      comb_t, wbase + W_V, v_b, nullptr, V2b, 128, 1.0f);
  attn_part_kernel<128><<<dim3(36, 4, 8), blk, 0, stream>>>(Qt, K2t, V2b, Opart, lp);
  ltot_kernel<<<36, blk, 0, stream>>>(lp, ltot);
  float* x1 = ws + F_R;                    // V2b dead after attn
  __bf16* x1_t = (__bf16*)(ws + F_V);      // sf_t dead
  combine128_kernel<<<dim3(72, 4, 4), blk, 0, stream>>>(Opart, ltot, x, x1, x1_t);

  // --- FFN tail ---
  __bf16* h_t = (__bf16*)(ws + F_FEATS);   // Op partials dead after combine
  gemm_mfma_kernel<128, 3, 1><<<dim3(144, 4, 4), blk, 0, stream>>>(
      x1_t, wbase + W_FC1, fc1_b, nullptr, h_t, 512, 1.0f);
  gemm_mfma_kernel<512, 0, 0><<<dim3(144, 4, 1), blk, 0, stream>>>(
      h_t, wbase + W_FC2, fc2_b, x1, outp, 128, 1.0f);
}

// Round 9
// 529.147 us; speedup vs baseline: 4.0828x; 1.0026x over previous
//
#include <hip/hip_runtime.h>
#include <math.h>

#define BB 4
#define CC 128
#define HH 48
#define WW 48
#define NSP (HH*WW)          // 2304
#define DCC 256
#define BCN (BB*CC*NSP)      // 1179648
#define BNTOT (BB*NSP)       // 9216
#define KS 12                // attention key-splits

typedef float f32x4 __attribute__((ext_vector_type(4)));
typedef __bf16 bf16x8 __attribute__((ext_vector_type(8)));
typedef __bf16 bf16x4 __attribute__((ext_vector_type(4)));

__device__ __forceinline__ float sigmf(float v) { return 1.0f / (1.0f + __expf(-v)); }

// ---------------- LDS-tiled transpose f32(B,C,N) -> bf16(B,N,C), fused elementwise ----------------
// MODE 0: plain  1: RoPE  2: spike-fn (aux = tau)
template <int C, int MODE>
__global__ __launch_bounds__(256) void trans_kernel(const float* __restrict__ in,
                                                    __bf16* __restrict__ out,
                                                    const float* __restrict__ aux) {
  __shared__ float lds[32][33];
  int b = blockIdx.z;
  int n0 = blockIdx.x * 32;
  int c0 = blockIdx.y * 32;
  int tid = threadIdx.x;
  int nn = tid & 31, cs = tid >> 5;
#pragma unroll
  for (int j = 0; j < 4; ++j) {
    int cc = cs * 4 + j;
    lds[cc][nn] = in[((size_t)b * C + c0 + cc) * NSP + n0 + nn];
  }
  __syncthreads();
  int c = tid & 31, ns = tid >> 5;
#pragma unroll
  for (int j = 0; j < 4; ++j) {
    int n2 = ns * 4 + j;
    float v;
    if (MODE == 1) {
      int gc = c0 + c;
      int i = gc >> 1;
      float re = lds[c & ~1][n2];
      float im = lds[c | 1][n2];
      int n = n0 + n2;
      int h = n / WW, w = n % WW;
      float theta = __expf(-9.2103403719761836f * ((float)i) / 64.0f);
      float pos = (float)(h + w) * theta;
      float cs_ = cosf(pos), sn_ = sinf(pos);
      v = (gc & 1) ? (re * sn_ + im * cs_) : (re * cs_ - im * sn_);
    } else if (MODE == 2) {
      float df = lds[c][n2];
      float sp = sigmf((df - 1.0f) * 5.0f);
      float e = __expf(-1.0f / (aux[b * C + c0 + c] + 1e-6f));
      v = sp * (df * e) + (1.0f - sp) * df;
    } else {
      v = lds[c][n2];
    }
    out[((size_t)b * NSP + n0 + n2) * C + c0 + c] = (__bf16)v;
  }
}

// ---------------- batched weight f32->bf16 convert (12 slots) ----------------
struct WCvt {
  const float* src[12];
  int len[12];
  int off[12];
};
__global__ __launch_bounds__(256) void wcvt_kernel(WCvt a, __bf16* __restrict__ dst) {
  int g = blockIdx.y;
  int idx = blockIdx.x * 256 + threadIdx.x;
  if (idx < a.len[g]) dst[a.off[g] + idx] = (__bf16)a.src[g][idx];
}

// ---------------- segmented-epilogue MFMA GEMM ----------------
// out(seg) = act(W x in_t + bias)*sc [+ addsrc].  Weights for both segments
// contiguous in wb (rows 0..osplit-1 seg0, osplit..O-1 seg1).
// OUT: 0 f32 planar, 1 bf16 transposed, 2 bf16 planar.
template <int OUT>
__device__ __forceinline__ void gemm_store(void* outp, int b, int n, int Oseg,
                                           int obase, int quad, const float* vr) {
  if (OUT == 0) {
    float* op = (float*)outp;
#pragma unroll
    for (int reg = 0; reg < 4; ++reg)
      op[((size_t)b * Oseg + obase + quad * 4 + reg) * NSP + n] = vr[reg];
  } else if (OUT == 1) {
    __bf16* op = (__bf16*)outp;
    bf16x4 pk;
#pragma unroll
    for (int reg = 0; reg < 4; ++reg) pk[reg] = (__bf16)vr[reg];
    *(bf16x4*)(op + ((size_t)b * NSP + n) * Oseg + obase + quad * 4) = pk;
  } else {
    __bf16* op = (__bf16*)outp;
#pragma unroll
    for (int reg = 0; reg < 4; ++reg)
      op[((size_t)b * Oseg + obase + quad * 4 + reg) * NSP + n] = (__bf16)vr[reg];
  }
}

template <int K, int ACT, int OUT0, int OUT1>
__global__ __launch_bounds__(256) void gemm_mfma_kernel(
    const __bf16* __restrict__ in_t, const __bf16* __restrict__ wb,
    const float* __restrict__ bias0, const float* __restrict__ bias1,
    const float* __restrict__ add0, const float* __restrict__ add1,
    void* __restrict__ out0, void* __restrict__ out1,
    int osplit, int Ototal, float sc0, float sc1) {
  int tid = threadIdx.x;
  int wv = tid >> 6, lane = tid & 63;
  int m15 = lane & 15, quad = lane >> 4;
  int b = blockIdx.y;
  int n0 = blockIdx.x * 16;
  int wpb = blockDim.x >> 6;
  int o0 = (blockIdx.z * wpb + wv) * 32;
  if (o0 >= Ototal) return;
  int n = n0 + m15;
  const __bf16* brow = in_t + ((size_t)b * NSP + n) * K + quad * 8;
  const __bf16* a0p = wb + (size_t)(o0 + m15) * K + quad * 8;
  const __bf16* a1p = wb + (size_t)(o0 + 16 + m15) * K + quad * 8;
  f32x4 of0 = (f32x4){0.f, 0.f, 0.f, 0.f};
  f32x4 of1 = (f32x4){0.f, 0.f, 0.f, 0.f};
#pragma unroll
  for (int kc = 0; kc < K; kc += 32) {
    bf16x8 bfr = *(const bf16x8*)(brow + kc);
    bf16x8 a0 = *(const bf16x8*)(a0p + kc);
    bf16x8 a1 = *(const bf16x8*)(a1p + kc);
    of0 = __builtin_amdgcn_mfma_f32_16x16x32_bf16(a0, bfr, of0, 0, 0, 0);
    of1 = __builtin_amdgcn_mfma_f32_16x16x32_bf16(a1, bfr, of1, 0, 0, 0);
  }
  bool s1 = (o0 >= osplit);
  int Oseg = s1 ? (Ototal - osplit) : osplit;
  int ol0 = o0 - (s1 ? osplit : 0);
  const float* bias = s1 ? bias1 : bias0;
  const float* add = s1 ? add1 : add0;
  void* outp = s1 ? out1 : out0;
  float sc = s1 ? sc1 : sc0;
#pragma unroll
  for (int t = 0; t < 2; ++t) {
    f32x4 acc = t ? of1 : of0;
    float vr[4];
#pragma unroll
    for (int reg = 0; reg < 4; ++reg) {
      int ol = ol0 + t * 16 + quad * 4 + reg;
      float v = acc[reg] + bias[ol];
      if (ACT == 1) v = fmaxf(v, 0.0f);
      else if (ACT == 2) v = sigmf(v);
      else if (ACT == 3) { v = fmaxf(v, 0.0f); v = v * v; }
      v *= sc;
      if (add) v += add[((size_t)b * Oseg + ol) * NSP + n];
      vr[reg] = v;
    }
    if (!s1)
      gemm_store<OUT0>(outp, b, n, Oseg, ol0 + t * 16, quad, vr);
    else
      gemm_store<OUT1>(outp, b, n, Oseg, ol0 + t * 16, quad, vr);
  }
}

// ---------------- batchnorm stats (per channel over B,H,W) ----------------
__global__ __launch_bounds__(256) void bn_stats_kernel(const float* __restrict__ feats, int coff,
                                                       float* __restrict__ mean,
                                                       float* __restrict__ var) {
  int c = coff + blockIdx.x;
  float s = 0.0f, s2 = 0.0f;
  for (int i = threadIdx.x; i < BB * NSP; i += 256) {
    int b = i / NSP, n = i % NSP;
    float v = feats[((size_t)b * DCC + c) * NSP + n];
    s += v;
    s2 += v * v;
  }
  __shared__ float rs[4], rs2[4];
#pragma unroll
  for (int off = 32; off > 0; off >>= 1) {
    s += __shfl_down(s, off);
    s2 += __shfl_down(s2, off);
  }
  int wid = threadIdx.x >> 6;
  if ((threadIdx.x & 63) == 0) { rs[wid] = s; rs2[wid] = s2; }
  __syncthreads();
  if (threadIdx.x == 0) {
    float S = rs[0] + rs[1] + rs[2] + rs[3];
    float S2 = rs2[0] + rs2[1] + rs2[2] + rs2[3];
    float m = S / (float)(BB * NSP);
    mean[c] = m;
    var[c] = S2 / (float)(BB * NSP) - m * m;
  }
}

// ---------------- tiled BN+ReLU -> ht (B,N,DCC-stride) bf16 ----------------
__global__ __launch_bounds__(256) void bnrelu_t_kernel(
    const float* __restrict__ feats, const float* __restrict__ mean,
    const float* __restrict__ var, const float* __restrict__ g,
    const float* __restrict__ bb, __bf16* __restrict__ ht) {
  __shared__ float lds[32][33];
  int b = blockIdx.z;
  int n0 = blockIdx.x * 32;
  int c0 = blockIdx.y * 32;
  int tid = threadIdx.x;
  int nn = tid & 31, cs = tid >> 5;
#pragma unroll
  for (int j = 0; j < 4; ++j) {
    int cc = cs * 4 + j;
    lds[cc][nn] = feats[((size_t)b * DCC + c0 + cc) * NSP + n0 + nn];
  }
  __syncthreads();
  int c = tid & 31, ns = tid >> 5;
  int gc = c0 + c;
  float sc_ = rsqrtf(var[gc] + 1e-5f) * g[gc];
  float sh_ = bb[gc] - mean[gc] * sc_;
#pragma unroll
  for (int j = 0; j < 4; ++j) {
    int n2 = ns * 4 + j;
    float v = fmaxf(lds[c][n2] * sc_ + sh_, 0.0f);
    ht[((size_t)b * NSP + n0 + n2) * DCC + gc] = (__bf16)v;
  }
}

// db_w (32, Cin, 3, 3) f32 -> wb[tap][o][c] bf16
__global__ __launch_bounds__(256) void packw_kernel(const float* __restrict__ w,
                                                    __bf16* __restrict__ wb, int Cin) {
  int idx = blockIdx.x * 256 + threadIdx.x;
  if (idx >= 9 * 32 * Cin) return;
  int c = idx % Cin;
  int o = (idx / Cin) % 32;
  int tap = idx / (Cin * 32);
  wb[idx] = (__bf16)w[((size_t)o * Cin + c) * 9 + tap];
}

// ---------------- conv3x3: 4 waves split tap x K chunks, LDS partial reduce ----------------
template <int Cin>
__global__ __launch_bounds__(256) void conv3x3_mfma_kernel(
    const __bf16* __restrict__ ht, const __bf16* __restrict__ wb,
    const float* __restrict__ cb, float* __restrict__ feats, int cout0) {
  constexpr int KCin = Cin / 32;
  __shared__ float red[4][64][8];
  int tid = threadIdx.x;
  int wv = tid >> 6, lane = tid & 63;
  int m15 = lane & 15, quad = lane >> 4;
  int b = blockIdx.y;
  int n0 = blockIdx.x * 16;
  int n = n0 + m15;
  int h = n / WW, w = n % WW;
  f32x4 of0 = (f32x4){0.f, 0.f, 0.f, 0.f};
  f32x4 of1 = (f32x4){0.f, 0.f, 0.f, 0.f};
  const __bf16* htb = ht + (size_t)b * NSP * DCC;
  const bf16x8 zf = {};
  for (int ci = wv; ci < 9 * KCin; ci += 4) {
    int tap = ci / KCin;
    int kc = (ci % KCin) * 32;
    int dh = tap / 3 - 1, dw = tap % 3 - 1;
    bool valid = ((unsigned)(h + dh) < HH) && ((unsigned)(w + dw) < WW);
    int pa = valid ? (n + dh * WW + dw) : 0;
    bf16x8 bfr = *(const bf16x8*)(htb + (size_t)pa * DCC + kc + quad * 8);
    if (!valid) bfr = zf;
    const __bf16* wt = wb + (size_t)tap * 32 * Cin + kc + quad * 8;
    bf16x8 a0 = *(const bf16x8*)(wt + (size_t)m15 * Cin);
    bf16x8 a1 = *(const bf16x8*)(wt + (size_t)(16 + m15) * Cin);
    of0 = __builtin_amdgcn_mfma_f32_16x16x32_bf16(a0, bfr, of0, 0, 0, 0);
    of1 = __builtin_amdgcn_mfma_f32_16x16x32_bf16(a1, bfr, of1, 0, 0, 0);
  }
  float* myred = red[wv][lane];
#pragma unroll
  for (int reg = 0; reg < 4; ++reg) {
    myred[reg] = of0[reg];
    myred[4 + reg] = of1[reg];
  }
  __syncthreads();
  if (wv == 0) {
#pragma unroll
    for (int reg = 0; reg < 4; ++reg) {
      int o = quad * 4 + reg;
      float s0 = red[0][lane][reg] + red[1][lane][reg] + red[2][lane][reg] + red[3][lane][reg];
      float s1 = red[0][lane][4 + reg] + red[1][lane][4 + reg] + red[2][lane][4 + reg] +
                 red[3][lane][4 + reg];
      feats[((size_t)b * DCC + cout0 + o) * NSP + n] = s0 + cb[o];
      feats[((size_t)b * DCC + cout0 + 16 + o) * NSP + n] = s1 + cb[16 + o];
    }
  }
}

// ---------------- small elementwise kernels ----------------
__global__ __launch_bounds__(256) void copyx_kernel(const float* __restrict__ x,
                                                    float* __restrict__ feats) {
  int idx = blockIdx.x * 256 + threadIdx.x;
  if (idx >= BCN) return;
  int n = idx % NSP;
  int c = (idx / NSP) % CC;
  int b = idx / (NSP * CC);
  feats[((size_t)b * DCC + c) * NSP + n] = x[idx];
}

// knum = k*v; rec = sigmoid_r * ((k*v + eu*k*v) / (k + eu*k))
__global__ __launch_bounds__(256) void recwkv_kernel(
    const float* __restrict__ r, const float* __restrict__ k,
    const float* __restrict__ v, const float* __restrict__ u,
    float* __restrict__ knum, float* __restrict__ rec) {
  int idx = blockIdx.x * 256 + threadIdx.x;
  if (idx >= BCN) return;
  int c = (idx / NSP) % CC;
  float eu = __expf(u[c]);
  float kk = k[idx], vv = v[idx];
  float nv = kk * vv;
  knum[idx] = nv;
  float t = eu * kk;
  rec[idx] = r[idx] * ((nv + t * vv) / (kk + t));
}

__global__ __launch_bounds__(256) void tau_kernel(const float* __restrict__ z2,
                                                  float* __restrict__ tau) {
  int bc = blockIdx.x;  // b*DCC + c
  float s = 0.0f;
  for (int n = threadIdx.x; n < NSP; n += 256) s += z2[(size_t)bc * NSP + n];
  __shared__ float rs[4];
#pragma unroll
  for (int off = 32; off > 0; off >>= 1) s += __shfl_down(s, off);
  int wid = threadIdx.x >> 6;
  if ((threadIdx.x & 63) == 0) rs[wid] = s;
  __syncthreads();
  if (threadIdx.x == 0) tau[bc] = (rs[0] + rs[1] + rs[2] + rs[3]) / (float)NSP;
}

// ---------------- MFMA attention, KS key-splits, 1-wave blocks, bf16 partials ----------------
template <int CD>
__global__ __launch_bounds__(64) void attn_part_kernel(
    const __bf16* __restrict__ Qt, const __bf16* __restrict__ Kt,
    const __bf16* __restrict__ Vb, __bf16* __restrict__ Op,
    float* __restrict__ lp) {
  constexpr int NC = CD / 16;
  constexpr int KC = CD / 32;
  constexpr int KEYS = NSP / KS;  // 192
  __shared__ float pt[2][16][36];
  int lane = threadIdx.x;
  int m15 = lane & 15, quad = lane >> 4;
  int b = blockIdx.y, ks = blockIdx.z;
  int n0 = blockIdx.x * 16;

  bf16x8 qf[KC];
  const __bf16* qrow = Qt + ((size_t)b * NSP + n0 + m15) * CD + quad * 8;
#pragma unroll
  for (int kc = 0; kc < KC; ++kc) qf[kc] = *(const bf16x8*)(qrow + kc * 32);

  f32x4 of[NC];
#pragma unroll
  for (int i = 0; i < NC; ++i) of[i] = (f32x4){0.f, 0.f, 0.f, 0.f};
  float l0 = 0.f, l1 = 0.f, l2 = 0.f, l3 = 0.f;

  const __bf16* Kb = Kt + (size_t)b * NSP * CD;
  const __bf16* Vbb = Vb + (size_t)b * CD * NSP;
  int par = 0;

  for (int m0 = ks * KEYS; m0 < (ks + 1) * KEYS; m0 += 32, par ^= 1) {
    f32x4 s[2];
#pragma unroll
    for (int t = 0; t < 2; ++t) {
      f32x4 acc = (f32x4){0.f, 0.f, 0.f, 0.f};
      const __bf16* krow = Kb + (size_t)(m0 + t * 16 + m15) * CD + quad * 8;
#pragma unroll
      for (int kc = 0; kc < KC; ++kc) {
        bf16x8 kf = *(const bf16x8*)(krow + kc * 32);
        acc = __builtin_amdgcn_mfma_f32_16x16x32_bf16(qf[kc], kf, acc, 0, 0, 0);
      }
      s[t] = acc;
    }
    // prefetch V frags before the exp/LDS chain
    bf16x8 vf[NC];
#pragma unroll
    for (int ct = 0; ct < NC; ++ct)
      vf[ct] = *(const bf16x8*)(Vbb + (size_t)(ct * 16 + m15) * NSP + m0 + quad * 8);

    float(*ptw)[36] = pt[par];
#pragma unroll
    for (int t = 0; t < 2; ++t) {
      float e0 = __expf(s[t].x), e1 = __expf(s[t].y), e2 = __expf(s[t].z), e3 = __expf(s[t].w);
      l0 += e0; l1 += e1; l2 += e2; l3 += e3;
      ptw[quad * 4 + 0][t * 16 + m15] = e0;
      ptw[quad * 4 + 1][t * 16 + m15] = e1;
      ptw[quad * 4 + 2][t * 16 + m15] = e2;
      ptw[quad * 4 + 3][t * 16 + m15] = e3;
    }
    const float* prow = &ptw[m15][quad * 8];
    f32x4 pa = *(const f32x4*)(prow);
    f32x4 pb = *(const f32x4*)(prow + 4);
    bf16x8 pf;
    pf[0] = (__bf16)pa.x; pf[1] = (__bf16)pa.y; pf[2] = (__bf16)pa.z; pf[3] = (__bf16)pa.w;
    pf[4] = (__bf16)pb.x; pf[5] = (__bf16)pb.y; pf[6] = (__bf16)pb.z; pf[7] = (__bf16)pb.w;
#pragma unroll
    for (int ct = 0; ct < NC; ++ct)
      of[ct] = __builtin_amdgcn_mfma_f32_16x16x32_bf16(pf, vf[ct], of[ct], 0, 0, 0);
  }

#pragma unroll
  for (int off = 1; off < 16; off <<= 1) {
    l0 += __shfl_xor(l0, off);
    l1 += __shfl_xor(l1, off);
    l2 += __shfl_xor(l2, off);
    l3 += __shfl_xor(l3, off);
  }
  float* lpb = lp + (size_t)(ks * BB + b) * NSP + n0;
  if (m15 == 0) {
    lpb[quad * 4 + 0] = l0;
    lpb[quad * 4 + 1] = l1;
    lpb[quad * 4 + 2] = l2;
    lpb[quad * 4 + 3] = l3;
  }
  __bf16* Ob = Op + (size_t)(ks * BB + b) * CD * NSP;
#pragma unroll
  for (int ct = 0; ct < NC; ++ct) {
    bf16x4 pk;
#pragma unroll
    for (int reg = 0; reg < 4; ++reg) pk[reg] = (__bf16)of[ct][reg];
    *(bf16x4*)(Ob + (size_t)(ct * 16 + m15) * NSP + n0 + quad * 4) = pk;
  }
}

// ltot[b][n] = 1 / sum_ks lp[ks][b][n]
__global__ __launch_bounds__(256) void ltot_kernel(const float* __restrict__ lp,
                                                   float* __restrict__ ltot) {
  int idx = blockIdx.x * 256 + threadIdx.x;
  if (idx >= BNTOT) return;
  float s = 0.f;
#pragma unroll
  for (int ks = 0; ks < KS; ++ks) s += lp[(size_t)ks * BNTOT + idx];
  ltot[idx] = 1.0f / s;
}

// combine partials for CD=32 -> att1_t (B,N,32) bf16
__global__ __launch_bounds__(256) void combine32_kernel(const __bf16* __restrict__ Op,
                                                        const float* __restrict__ ltot,
                                                        __bf16* __restrict__ att1_t) {
  __shared__ float lds[32][33];
  int b = blockIdx.z;
  int n0 = blockIdx.x * 32;
  int tid = threadIdx.x;
  int nn = tid & 31, cs = tid >> 5;
  float linv = ltot[b * NSP + n0 + nn];
#pragma unroll
  for (int j = 0; j < 4; ++j) {
    int cc = cs * 4 + j;
    float s = 0.f;
#pragma unroll
    for (int ks = 0; ks < KS; ++ks)
      s += (float)Op[((size_t)(ks * BB + b) * 32 + cc) * NSP + n0 + nn];
    lds[cc][nn] = s * linv;
  }
  __syncthreads();
  int c = tid & 31, ns = tid >> 5;
#pragma unroll
  for (int j = 0; j < 4; ++j) {
    int n2 = ns * 4 + j;
    att1_t[((size_t)b * NSP + n0 + n2) * 32 + c] = (__bf16)lds[c][n2];
  }
}

// combine partials for CD=128, + x residual -> x1 (f32 planar) AND x1_t (bf16 transposed)
__global__ __launch_bounds__(256) void combine128_kernel(
    const __bf16* __restrict__ Op, const float* __restrict__ ltot,
    const float* __restrict__ x, float* __restrict__ x1, __bf16* __restrict__ x1_t) {
  __shared__ float lds[32][33];
  int b = blockIdx.z;
  int n0 = blockIdx.x * 32;
  int c0 = blockIdx.y * 32;
  int tid = threadIdx.x;
  int nn = tid & 31, cs = tid >> 5;
  float linv = ltot[b * NSP + n0 + nn];
#pragma unroll
  for (int j = 0; j < 4; ++j) {
    int gc = c0 + cs * 4 + j;
    float s = 0.f;
#pragma unroll
    for (int ks = 0; ks < KS; ++ks)
      s += (float)Op[((size_t)(ks * BB + b) * CC + gc) * NSP + n0 + nn];
    float v = s * linv + x[((size_t)b * CC + gc) * NSP + n0 + nn];
    lds[cs * 4 + j][nn] = v;
    x1[((size_t)b * CC + gc) * NSP + n0 + nn] = v;
  }
  __syncthreads();
  int c = tid & 31, ns = tid >> 5;
#pragma unroll
  for (int j = 0; j < 4; ++j) {
    int n2 = ns * 4 + j;
    x1_t[((size_t)b * NSP + n0 + n2) * CC + c0 + c] = (__bf16)lds[c][n2];
  }
}

// ---------------- host ----------------
extern "C" void kernel_launch(void* const* d_in, const int* in_sizes, int n_in,
                              void* d_out, int out_size, void* d_ws, size_t ws_size,
                              hipStream_t stream) {
  const float* x = (const float*)d_in[0];
  const float* r_w = (const float*)d_in[1];
  const float* r_b = (const float*)d_in[2];
  const float* k_w = (const float*)d_in[3];
  const float* k_b = (const float*)d_in[4];
  const float* v_w = (const float*)d_in[5];
  const float* v_b = (const float*)d_in[6];
  // d_in[7..10]: wc1/wc2 — dead code (multiplied by zeros in reference)
  const float* u = (const float*)d_in[11];
  const float* sn1_w = (const float*)d_in[12];
  const float* sn1_b = (const float*)d_in[13];
  const float* sn2_w = (const float*)d_in[14];
  const float* sn2_b = (const float*)d_in[15];
  const float* lb_w = (const float*)d_in[16];
  const float* lb_b = (const float*)d_in[17];
  const float* ld_w = (const float*)d_in[18];
  const float* ld_b = (const float*)d_in[19];
  const float* ps_w = (const float*)d_in[20];
  const float* ps_b = (const float*)d_in[21];
  const float* pq_w = (const float*)d_in[22];
  const float* pq_b = (const float*)d_in[23];
  const float* fc1_w = (const float*)d_in[24];
  const float* fc1_b = (const float*)d_in[25];
  const float* fc2_w = (const float*)d_in[26];
  const float* fc2_b = (const float*)d_in[27];
  const float* db_g[4] = {(const float*)d_in[28], (const float*)d_in[32],
                          (const float*)d_in[36], (const float*)d_in[40]};
  const float* db_b[4] = {(const float*)d_in[29], (const float*)d_in[33],
                          (const float*)d_in[37], (const float*)d_in[41]};
  const float* db_w[4] = {(const float*)d_in[30], (const float*)d_in[34],
                          (const float*)d_in[38], (const float*)d_in[42]};
  const float* db_cb[4] = {(const float*)d_in[31], (const float*)d_in[35],
                           (const float*)d_in[39], (const float*)d_in[43]};

  float* outp = (float*)d_out;           // out  (B,C,H,W)
  float* knum = outp + BCN;              // new_num = k*v
  float* kden = outp + 2 * (size_t)BCN;  // new_den = k

  float* ws = (float*)d_ws;
  // region map (f32 slots)
  const size_t F_FEATS = 0;         // feats f32 -> Op partials (0..7077888 w/ REC,V) -> h_t bf16
  const size_t F_Z2 = 2359296;      // z2 f32 (2359296)
  const size_t F_REC = 4718592;     // rec f32 (1179648)
  const size_t F_V = 5898240;       // v f32 -> ht bf16 -> sf_t bf16 (1179648)
  const size_t F_R = 7077888;       // r f32 -> feats_t bf16 -> V2b bf16 -> x1 f32 (1179648)
  const size_t F_XR = 8257536;      // xrope_t bf16 -> Wb -> z1_t -> Qt (589824)
  const size_t F_XT = 8847360;      // x_t bf16 -> Bft -> K2t (589824)
  const size_t F_DFB = 9437184;     // Dfb bf16 (147456)
  const size_t F_AT1T = 9584640;    // att1_t bf16 (147456)
  const size_t F_CT = 9732096;      // combined_t bf16 -> x1_t bf16 (589824)
  const size_t F_LP = 10321920;     // lp f32 (110592)
  const size_t F_LTOT = 10432512;   // ltot f32 (9216)
  const size_t F_STATS = 10441728;  // mean[256] var[256] tau[1024]
  const size_t F_WB = 10443264;     // conv1x1 weights bf16 (266240 bf16 = 133120 slots)
  float* mean = ws + F_STATS;
  float* var = ws + F_STATS + 256;
  float* tau = ws + F_STATS + 512;
  float* lp = ws + F_LP;
  float* ltot = ws + F_LTOT;
  __bf16* wbase = (__bf16*)(ws + F_WB);
  // bf16-unit offsets (fusion pairs contiguous)
  const int W_KV = 0;        // k(16384) | v(16384)
  const int W_R = 32768;     // 16384
  const int W_SN1 = 49152;   // 16384
  const int W_SN2 = 65536;   // 16384
  const int W_LBLD = 81920;  // lb(8192) | ld(8192)
  const int W_PS = 98304;    // 4096
  const int W_PQK = 102400;  // pq(16384) | k dup(16384)
  const int W_FC1 = 135168;  // 65536
  const int W_FC2 = 200704;  // 65536

  dim3 blk(256);
  int ewBCN = (BCN + 255) / 256;

  // --- weights -> bf16, one launch ---
  WCvt wc;
  wc.src[0] = k_w;    wc.len[0] = 16384; wc.off[0] = W_KV;
  wc.src[1] = v_w;    wc.len[1] = 16384; wc.off[1] = W_KV + 16384;
  wc.src[2] = r_w;    wc.len[2] = 16384; wc.off[2] = W_R;
  wc.src[3] = sn1_w;  wc.len[3] = 16384; wc.off[3] = W_SN1;
  wc.src[4] = sn2_w;  wc.len[4] = 16384; wc.off[4] = W_SN2;
  wc.src[5] = lb_w;   wc.len[5] = 8192;  wc.off[5] = W_LBLD;
  wc.src[6] = ld_w;   wc.len[6] = 8192;  wc.off[6] = W_LBLD + 8192;
  wc.src[7] = ps_w;   wc.len[7] = 4096;  wc.off[7] = W_PS;
  wc.src[8] = pq_w;   wc.len[8] = 16384; wc.off[8] = W_PQK;
  wc.src[9] = k_w;    wc.len[9] = 16384; wc.off[9] = W_PQK + 16384;
  wc.src[10] = fc1_w; wc.len[10] = 65536; wc.off[10] = W_FC1;
  wc.src[11] = fc2_w; wc.len[11] = 65536; wc.off[11] = W_FC2;
  wcvt_kernel<<<dim3(256, 12), blk, 0, stream>>>(wc, wbase);

  __bf16* xrope_t = (__bf16*)(ws + F_XR);
  __bf16* x_t = (__bf16*)(ws + F_XT);
  trans_kernel<128, 1><<<dim3(72, 4, 4), blk, 0, stream>>>(x, xrope_t, nullptr);
  trans_kernel<128, 0><<<dim3(72, 4, 4), blk, 0, stream>>>(x, x_t, nullptr);

  // --- recurrent path: fused k|v GEMM + r GEMM + recwkv ---
  gemm_mfma_kernel<128, 0, 0, 0><<<dim3(144, 4, 2), blk, 0, stream>>>(
      xrope_t, wbase + W_KV, k_b, v_b, nullptr, nullptr, kden, ws + F_V, 128, 256, 1.f, 1.f);
  gemm_mfma_kernel<128, 2, 0, 0><<<dim3(144, 4, 1), blk, 0, stream>>>(
      x_t, wbase + W_R, r_b, r_b, nullptr, nullptr, ws + F_R, ws + F_R, 128, 128, 1.f, 1.f);
  recwkv_kernel<<<ewBCN, blk, 0, stream>>>(ws + F_R, kden, ws + F_V, u, knum, ws + F_REC);

  // --- dense block ---
  copyx_kernel<<<ewBCN, blk, 0, stream>>>(x, ws + F_FEATS);
  bn_stats_kernel<<<128, blk, 0, stream>>>(ws + F_FEATS, 0, mean, var);
  __bf16* ht = (__bf16*)(ws + F_V);
  __bf16* Wb = (__bf16*)(ws + F_XR);
  int cins[4] = {128, 160, 192, 224};
  for (int i = 0; i < 4; ++i) {
    int cin = cins[i];
    packw_kernel<<<(9 * 32 * cin + 255) / 256, blk, 0, stream>>>(db_w[i], Wb, cin);
    bnrelu_t_kernel<<<dim3(72, cin / 32, 4), blk, 0, stream>>>(
        ws + F_FEATS, mean, var, db_g[i], db_b[i], ht);
    switch (cin) {
      case 128: conv3x3_mfma_kernel<128><<<dim3(144, 4), blk, 0, stream>>>(ht, Wb, db_cb[i], ws + F_FEATS, cin); break;
      case 160: conv3x3_mfma_kernel<160><<<dim3(144, 4), blk, 0, stream>>>(ht, Wb, db_cb[i], ws + F_FEATS, cin); break;
      case 192: conv3x3_mfma_kernel<192><<<dim3(144, 4), blk, 0, stream>>>(ht, Wb, db_cb[i], ws + F_FEATS, cin); break;
      default:  conv3x3_mfma_kernel<224><<<dim3(144, 4), blk, 0, stream>>>(ht, Wb, db_cb[i], ws + F_FEATS, cin); break;
    }
    if (i < 3)
      bn_stats_kernel<<<32, blk, 0, stream>>>(ws + F_FEATS, cin, mean, var);
  }

  // --- spike path ---
  __bf16* feats_t = (__bf16*)(ws + F_R);
  trans_kernel<256, 0><<<dim3(72, 8, 4), blk, 0, stream>>>(ws + F_FEATS, feats_t, nullptr);
  __bf16* z1_t = (__bf16*)(ws + F_XR);
  gemm_mfma_kernel<256, 1, 1, 1><<<dim3(144, 4, 1), dim3(128), 0, stream>>>(
      feats_t, wbase + W_SN1, sn1_b, sn1_b, nullptr, nullptr, z1_t, z1_t, 64, 64, 1.f, 1.f);
  gemm_mfma_kernel<64, 2, 0, 0><<<dim3(144, 4, 2), blk, 0, stream>>>(
      z1_t, wbase + W_SN2, sn2_b, sn2_b, nullptr, nullptr, ws + F_Z2, ws + F_Z2, 256, 256, 1.f, 1.f);
  tau_kernel<<<BB * DCC, blk, 0, stream>>>(ws + F_Z2, tau);
  __bf16* sf_t = (__bf16*)(ws + F_V);
  trans_kernel<256, 2><<<dim3(72, 8, 4), blk, 0, stream>>>(ws + F_FEATS, sf_t, tau);
  __bf16* Bft = (__bf16*)(ws + F_XT);
  __bf16* Dfb = (__bf16*)(ws + F_DFB);
  gemm_mfma_kernel<256, 0, 1, 2><<<dim3(144, 4, 1), dim3(128), 0, stream>>>(
      sf_t, wbase + W_LBLD, lb_b, ld_b, nullptr, nullptr, Bft, Dfb, 32, 64, 1.f, 1.f);
  __bf16* Opart = (__bf16*)(ws + F_FEATS);  // feats f32 dead from here
  attn_part_kernel<32><<<dim3(144, 4, KS), dim3(64), 0, stream>>>(Bft, Bft, Dfb, Opart, lp);
  ltot_kernel<<<36, blk, 0, stream>>>(lp, ltot);
  __bf16* att1_t = (__bf16*)(ws + F_AT1T);
  combine32_kernel<<<dim3(72, 1, 4), blk, 0, stream>>>(Opart, ltot, att1_t);
  __bf16* comb_t = (__bf16*)(ws + F_CT);
  gemm_mfma_kernel<32, 0, 1, 1><<<dim3(144, 4, 1), blk, 0, stream>>>(
      att1_t, wbase + W_PS, ps_b, ps_b, ws + F_REC, ws + F_REC, comb_t, comb_t, 128, 128, 1.f, 1.f);

  // --- final attention: fused Q|K2 GEMM, V2 GEMM, key-split attn ---
  __bf16* Qt = (__bf16*)(ws + F_XR);
  __bf16* K2t = (__bf16*)(ws + F_XT);
  __bf16* V2b = (__bf16*)(ws + F_R);
  gemm_mfma_kernel<128, 0, 1, 1><<<dim3(144, 4, 2), blk, 0, stream>>>(
      comb_t, wbase + W_PQK, pq_b, k_b, nullptr, nullptr, Qt, K2t, 128, 256,
      0.08838834764831845f, 1.f);
  gemm_mfma_kernel<128, 0, 2, 2><<<dim3(144, 4, 1), blk, 0, stream>>>(
      comb_t, wbase + W_KV + 16384, v_b, v_b, nullptr, nullptr, V2b, V2b, 128, 128, 1.f, 1.f);
  attn_part_kernel<128><<<dim3(144, 4, KS), dim3(64), 0, stream>>>(Qt, K2t, V2b, Opart, lp);
  ltot_kernel<<<36, blk, 0, stream>>>(lp, ltot);
  float* x1 = ws + F_R;                 // V2b dead after attn
  __bf16* x1_t = (__bf16*)(ws + F_CT);  // comb_t dead after V2 gemm
  combine128_kernel<<<dim3(72, 4, 4), blk, 0, stream>>>(Opart, ltot, x, x1, x1_t);

  // --- FFN tail ---
  __bf16* h_t = (__bf16*)(ws + F_FEATS);  // Op partials dead after combine
  gemm_mfma_kernel<128, 3, 1, 1><<<dim3(144, 4, 4), blk, 0, stream>>>(
      x1_t, wbase + W_FC1, fc1_b, fc1_b, nullptr, nullptr, h_t, h_t, 512, 512, 1.f, 1.f);
  gemm_mfma_kernel<512, 0, 0, 0><<<dim3(144, 4, 1), blk, 0, stream>>>(
      h_t, wbase + W_FC2, fc2_b, fc2_b, x1, x1, outp, outp, 128, 128, 1.f, 1.f);
}

// Round 10
// 468.639 us; speedup vs baseline: 4.6099x; 1.1291x over previous
//
#include <hip/hip_runtime.h>
#include <math.h>

#define BB 4
#define CC 128
#define HH 48
#define WW 48
#define NSP (HH*WW)          // 2304
#define DCC 256
#define BCN (BB*CC*NSP)      // 1179648
#define BNTOT (BB*NSP)       // 9216
#define KS 12                // attention key-splits

typedef float f32x4 __attribute__((ext_vector_type(4)));
typedef __bf16 bf16x8 __attribute__((ext_vector_type(8)));
typedef __bf16 bf16x4 __attribute__((ext_vector_type(4)));

__device__ __forceinline__ float sigmf(float v) { return 1.0f / (1.0f + __expf(-v)); }

// ---------------- LDS-tiled transpose f32(B,C,N) -> bf16(B,N,C), fused elementwise ----------------
// MODE 0: plain  1: RoPE  2: spike-fn (aux = tau)
template <int C, int MODE>
__global__ __launch_bounds__(256) void trans_kernel(const float* __restrict__ in,
                                                    __bf16* __restrict__ out,
                                                    const float* __restrict__ aux) {
  __shared__ float lds[32][33];
  int b = blockIdx.z;
  int n0 = blockIdx.x * 32;
  int c0 = blockIdx.y * 32;
  int tid = threadIdx.x;
  int nn = tid & 31, cs = tid >> 5;
#pragma unroll
  for (int j = 0; j < 4; ++j) {
    int cc = cs * 4 + j;
    lds[cc][nn] = in[((size_t)b * C + c0 + cc) * NSP + n0 + nn];
  }
  __syncthreads();
  int c = tid & 31, ns = tid >> 5;
#pragma unroll
  for (int j = 0; j < 4; ++j) {
    int n2 = ns * 4 + j;
    float v;
    if (MODE == 1) {
      int gc = c0 + c;
      int i = gc >> 1;
      float re = lds[c & ~1][n2];
      float im = lds[c | 1][n2];
      int n = n0 + n2;
      int h = n / WW, w = n % WW;
      float theta = __expf(-9.2103403719761836f * ((float)i) / 64.0f);
      float pos = (float)(h + w) * theta;
      float cs_ = cosf(pos), sn_ = sinf(pos);
      v = (gc & 1) ? (re * sn_ + im * cs_) : (re * cs_ - im * sn_);
    } else if (MODE == 2) {
      float df = lds[c][n2];
      float sp = sigmf((df - 1.0f) * 5.0f);
      float e = __expf(-1.0f / (aux[b * C + c0 + c] + 1e-6f));
      v = sp * (df * e) + (1.0f - sp) * df;
    } else {
      v = lds[c][n2];
    }
    out[((size_t)b * NSP + n0 + n2) * C + c0 + c] = (__bf16)v;
  }
}

// ---------------- batched weight f32->bf16 convert (12 slots) ----------------
struct WCvt {
  const float* src[12];
  int len[12];
  int off[12];
};
__global__ __launch_bounds__(256) void wcvt_kernel(WCvt a, __bf16* __restrict__ dst) {
  int g = blockIdx.y;
  int idx = blockIdx.x * 256 + threadIdx.x;
  if (idx < a.len[g]) dst[a.off[g] + idx] = (__bf16)a.src[g][idx];
}

// ---------------- batched conv3x3 weight pack: (32,Cin,3,3) f32 -> [tap][o][c] bf16 ----------------
struct PackW {
  const float* src[4];
  int cin[4];
  int off[4];
};
__global__ __launch_bounds__(256) void packw4_kernel(PackW a, __bf16* __restrict__ wb) {
  int layer = blockIdx.y;
  int cin = a.cin[layer];
  int idx = blockIdx.x * 256 + threadIdx.x;
  if (idx >= 9 * 32 * cin) return;
  int c = idx % cin;
  int o = (idx / cin) % 32;
  int tap = idx / (cin * 32);
  wb[a.off[layer] + idx] = (__bf16)a.src[layer][((size_t)o * cin + c) * 9 + tap];
}

// ---------------- segmented-epilogue MFMA GEMM ----------------
// OUT: 0 f32 planar, 1 bf16 transposed, 2 bf16 planar.
template <int OUT>
__device__ __forceinline__ void gemm_store(void* outp, int b, int n, int Oseg,
                                           int obase, int quad, const float* vr) {
  if (OUT == 0) {
    float* op = (float*)outp;
#pragma unroll
    for (int reg = 0; reg < 4; ++reg)
      op[((size_t)b * Oseg + obase + quad * 4 + reg) * NSP + n] = vr[reg];
  } else if (OUT == 1) {
    __bf16* op = (__bf16*)outp;
    bf16x4 pk;
#pragma unroll
    for (int reg = 0; reg < 4; ++reg) pk[reg] = (__bf16)vr[reg];
    *(bf16x4*)(op + ((size_t)b * NSP + n) * Oseg + obase + quad * 4) = pk;
  } else {
    __bf16* op = (__bf16*)outp;
#pragma unroll
    for (int reg = 0; reg < 4; ++reg)
      op[((size_t)b * Oseg + obase + quad * 4 + reg) * NSP + n] = (__bf16)vr[reg];
  }
}

template <int K, int ACT, int OUT0, int OUT1>
__global__ __launch_bounds__(256) void gemm_mfma_kernel(
    const __bf16* __restrict__ in_t, const __bf16* __restrict__ wb,
    const float* __restrict__ bias0, const float* __restrict__ bias1,
    const float* __restrict__ add0, const float* __restrict__ add1,
    void* __restrict__ out0, void* __restrict__ out1,
    int osplit, int Ototal, float sc0, float sc1) {
  int tid = threadIdx.x;
  int wv = tid >> 6, lane = tid & 63;
  int m15 = lane & 15, quad = lane >> 4;
  int b = blockIdx.y;
  int n0 = blockIdx.x * 16;
  int wpb = blockDim.x >> 6;
  int o0 = (blockIdx.z * wpb + wv) * 32;
  if (o0 >= Ototal) return;
  int n = n0 + m15;
  const __bf16* brow = in_t + ((size_t)b * NSP + n) * K + quad * 8;
  const __bf16* a0p = wb + (size_t)(o0 + m15) * K + quad * 8;
  const __bf16* a1p = wb + (size_t)(o0 + 16 + m15) * K + quad * 8;
  f32x4 of0 = (f32x4){0.f, 0.f, 0.f, 0.f};
  f32x4 of1 = (f32x4){0.f, 0.f, 0.f, 0.f};
#pragma unroll
  for (int kc = 0; kc < K; kc += 32) {
    bf16x8 bfr = *(const bf16x8*)(brow + kc);
    bf16x8 a0 = *(const bf16x8*)(a0p + kc);
    bf16x8 a1 = *(const bf16x8*)(a1p + kc);
    of0 = __builtin_amdgcn_mfma_f32_16x16x32_bf16(a0, bfr, of0, 0, 0, 0);
    of1 = __builtin_amdgcn_mfma_f32_16x16x32_bf16(a1, bfr, of1, 0, 0, 0);
  }
  bool s1 = (o0 >= osplit);
  int Oseg = s1 ? (Ototal - osplit) : osplit;
  int ol0 = o0 - (s1 ? osplit : 0);
  const float* bias = s1 ? bias1 : bias0;
  const float* add = s1 ? add1 : add0;
  void* outp = s1 ? out1 : out0;
  float sc = s1 ? sc1 : sc0;
#pragma unroll
  for (int t = 0; t < 2; ++t) {
    f32x4 acc = t ? of1 : of0;
    float vr[4];
#pragma unroll
    for (int reg = 0; reg < 4; ++reg) {
      int ol = ol0 + t * 16 + quad * 4 + reg;
      float v = acc[reg] + bias[ol];
      if (ACT == 1) v = fmaxf(v, 0.0f);
      else if (ACT == 2) v = sigmf(v);
      else if (ACT == 3) { v = fmaxf(v, 0.0f); v = v * v; }
      v *= sc;
      if (add) v += add[((size_t)b * Oseg + ol) * NSP + n];
      vr[reg] = v;
    }
    if (!s1)
      gemm_store<OUT0>(outp, b, n, Oseg, ol0 + t * 16, quad, vr);
    else
      gemm_store<OUT1>(outp, b, n, Oseg, ol0 + t * 16, quad, vr);
  }
}

// ---------------- batchnorm stats (per channel over B,H,W) ----------------
__global__ __launch_bounds__(256) void bn_stats_kernel(const float* __restrict__ feats, int coff,
                                                       float* __restrict__ mean,
                                                       float* __restrict__ var) {
  int c = coff + blockIdx.x;
  float s = 0.0f, s2 = 0.0f;
  for (int i = threadIdx.x; i < BB * NSP; i += 256) {
    int b = i / NSP, n = i % NSP;
    float v = feats[((size_t)b * DCC + c) * NSP + n];
    s += v;
    s2 += v * v;
  }
  __shared__ float rs[4], rs2[4];
#pragma unroll
  for (int off = 32; off > 0; off >>= 1) {
    s += __shfl_down(s, off);
    s2 += __shfl_down(s2, off);
  }
  int wid = threadIdx.x >> 6;
  if ((threadIdx.x & 63) == 0) { rs[wid] = s; rs2[wid] = s2; }
  __syncthreads();
  if (threadIdx.x == 0) {
    float S = rs[0] + rs[1] + rs[2] + rs[3];
    float S2 = rs2[0] + rs2[1] + rs2[2] + rs2[3];
    float m = S / (float)(BB * NSP);
    mean[c] = m;
    var[c] = S2 / (float)(BB * NSP) - m * m;
  }
}

// ---------------- tiled BN+ReLU -> ht (B,N,DCC-stride) bf16 ----------------
__global__ __launch_bounds__(256) void bnrelu_t_kernel(
    const float* __restrict__ feats, const float* __restrict__ mean,
    const float* __restrict__ var, const float* __restrict__ g,
    const float* __restrict__ bb, __bf16* __restrict__ ht) {
  __shared__ float lds[32][33];
  int b = blockIdx.z;
  int n0 = blockIdx.x * 32;
  int c0 = blockIdx.y * 32;
  int tid = threadIdx.x;
  int nn = tid & 31, cs = tid >> 5;
#pragma unroll
  for (int j = 0; j < 4; ++j) {
    int cc = cs * 4 + j;
    lds[cc][nn] = feats[((size_t)b * DCC + c0 + cc) * NSP + n0 + nn];
  }
  __syncthreads();
  int c = tid & 31, ns = tid >> 5;
  int gc = c0 + c;
  float sc_ = rsqrtf(var[gc] + 1e-5f) * g[gc];
  float sh_ = bb[gc] - mean[gc] * sc_;
#pragma unroll
  for (int j = 0; j < 4; ++j) {
    int n2 = ns * 4 + j;
    float v = fmaxf(lds[c][n2] * sc_ + sh_, 0.0f);
    ht[((size_t)b * NSP + n0 + n2) * DCC + gc] = (__bf16)v;
  }
}

// ---------------- conv3x3: 4 waves split tap x K chunks, LDS partial reduce ----------------
template <int Cin>
__global__ __launch_bounds__(256) void conv3x3_mfma_kernel(
    const __bf16* __restrict__ ht, const __bf16* __restrict__ wb,
    const float* __restrict__ cb, float* __restrict__ feats, int cout0) {
  constexpr int KCin = Cin / 32;
  __shared__ float red[4][64][8];
  int tid = threadIdx.x;
  int wv = tid >> 6, lane = tid & 63;
  int m15 = lane & 15, quad = lane >> 4;
  int b = blockIdx.y;
  int n0 = blockIdx.x * 16;
  int n = n0 + m15;
  int h = n / WW, w = n % WW;
  f32x4 of0 = (f32x4){0.f, 0.f, 0.f, 0.f};
  f32x4 of1 = (f32x4){0.f, 0.f, 0.f, 0.f};
  const __bf16* htb = ht + (size_t)b * NSP * DCC;
  const bf16x8 zf = {};
  for (int ci = wv; ci < 9 * KCin; ci += 4) {
    int tap = ci / KCin;
    int kc = (ci % KCin) * 32;
    int dh = tap / 3 - 1, dw = tap % 3 - 1;
    bool valid = ((unsigned)(h + dh) < HH) && ((unsigned)(w + dw) < WW);
    int pa = valid ? (n + dh * WW + dw) : 0;
    bf16x8 bfr = *(const bf16x8*)(htb + (size_t)pa * DCC + kc + quad * 8);
    if (!valid) bfr = zf;
    const __bf16* wt = wb + (size_t)tap * 32 * Cin + kc + quad * 8;
    bf16x8 a0 = *(const bf16x8*)(wt + (size_t)m15 * Cin);
    bf16x8 a1 = *(const bf16x8*)(wt + (size_t)(16 + m15) * Cin);
    of0 = __builtin_amdgcn_mfma_f32_16x16x32_bf16(a0, bfr, of0, 0, 0, 0);
    of1 = __builtin_amdgcn_mfma_f32_16x16x32_bf16(a1, bfr, of1, 0, 0, 0);
  }
  float* myred = red[wv][lane];
#pragma unroll
  for (int reg = 0; reg < 4; ++reg) {
    myred[reg] = of0[reg];
    myred[4 + reg] = of1[reg];
  }
  __syncthreads();
  if (wv == 0) {
#pragma unroll
    for (int reg = 0; reg < 4; ++reg) {
      int o = quad * 4 + reg;
      float s0 = red[0][lane][reg] + red[1][lane][reg] + red[2][lane][reg] + red[3][lane][reg];
      float s1 = red[0][lane][4 + reg] + red[1][lane][4 + reg] + red[2][lane][4 + reg] +
                 red[3][lane][4 + reg];
      feats[((size_t)b * DCC + cout0 + o) * NSP + n] = s0 + cb[o];
      feats[((size_t)b * DCC + cout0 + 16 + o) * NSP + n] = s1 + cb[16 + o];
    }
  }
}

// ---------------- small elementwise kernels ----------------
__global__ __launch_bounds__(256) void copyx_kernel(const float* __restrict__ x,
                                                    float* __restrict__ feats) {
  int idx = blockIdx.x * 256 + threadIdx.x;
  if (idx >= BCN) return;
  int n = idx % NSP;
  int c = (idx / NSP) % CC;
  int b = idx / (NSP * CC);
  feats[((size_t)b * DCC + c) * NSP + n] = x[idx];
}

// knum = k*v; rec = sigmoid_r * ((k*v + eu*k*v) / (k + eu*k))
__global__ __launch_bounds__(256) void recwkv_kernel(
    const float* __restrict__ r, const float* __restrict__ k,
    const float* __restrict__ v, const float* __restrict__ u,
    float* __restrict__ knum, float* __restrict__ rec) {
  int idx = blockIdx.x * 256 + threadIdx.x;
  if (idx >= BCN) return;
  int c = (idx / NSP) % CC;
  float eu = __expf(u[c]);
  float kk = k[idx], vv = v[idx];
  float nv = kk * vv;
  knum[idx] = nv;
  float t = eu * kk;
  rec[idx] = r[idx] * ((nv + t * vv) / (kk + t));
}

__global__ __launch_bounds__(256) void tau_kernel(const float* __restrict__ z2,
                                                  float* __restrict__ tau) {
  int bc = blockIdx.x;  // b*DCC + c
  float s = 0.0f;
  for (int n = threadIdx.x; n < NSP; n += 256) s += z2[(size_t)bc * NSP + n];
  __shared__ float rs[4];
#pragma unroll
  for (int off = 32; off > 0; off >>= 1) s += __shfl_down(s, off);
  int wid = threadIdx.x >> 6;
  if ((threadIdx.x & 63) == 0) rs[wid] = s;
  __syncthreads();
  if (threadIdx.x == 0) tau[bc] = (rs[0] + rs[1] + rs[2] + rs[3]) / (float)NSP;
}

// ---------------- flash-LDS MFMA attention: 4 waves share K/V tiles via LDS ----------------
// 64 Q-rows/block (16/wave), KS key-split blocks, bf16 unnormalized partials + lp row-sums.
template <int CD>
__global__ __launch_bounds__(256) void attn_part_kernel(
    const __bf16* __restrict__ Qt, const __bf16* __restrict__ Kt,
    const __bf16* __restrict__ Vb, __bf16* __restrict__ Op,
    float* __restrict__ lp) {
  constexpr int NC = CD / 16;
  constexpr int KC = CD / 32;
  constexpr int KEYS = NSP / KS;  // 192
  constexpr int KP = CD + 4;      // kl row pad (bank-conflict <= 2-way)
  constexpr int VP = 36;          // vl row pad
  __shared__ __bf16 kl[32][KP];   // [key][ch]
  __shared__ __bf16 vl[CD][VP];   // [ch][key]
  __shared__ float pt[4][16][36];
  int tid = threadIdx.x;
  int wv = tid >> 6, lane = tid & 63;
  int m15 = lane & 15, quad = lane >> 4;
  int b = blockIdx.y, ks = blockIdx.z;
  int n0 = blockIdx.x * 64 + wv * 16;

  bf16x8 qf[KC];
  const __bf16* qrow = Qt + ((size_t)b * NSP + n0 + m15) * CD + quad * 8;
#pragma unroll
  for (int kc = 0; kc < KC; ++kc) qf[kc] = *(const bf16x8*)(qrow + kc * 32);

  f32x4 of[NC];
#pragma unroll
  for (int i = 0; i < NC; ++i) of[i] = (f32x4){0.f, 0.f, 0.f, 0.f};
  float l0 = 0.f, l1 = 0.f, l2 = 0.f, l3 = 0.f;

  const __bf16* Kb = Kt + (size_t)b * NSP * CD;
  const __bf16* Vbb = Vb + (size_t)b * CD * NSP;
  float(*ptw)[36] = pt[wv];

  for (int m0 = ks * KEYS; m0 < (ks + 1) * KEYS; m0 += 32) {
    __syncthreads();  // previous iter's LDS reads done
    // stage K tile: 32 keys x CD ch, coalesced 16B chunks
    for (int i = tid; i < 32 * CD / 8; i += 256) {
      int row = i / (CD / 8);
      int cc8 = (i % (CD / 8)) * 8;
      *(bf16x8*)&kl[row][cc8] = *(const bf16x8*)(Kb + (size_t)(m0 + row) * CD + cc8);
    }
    // stage V tile: CD ch x 32 keys
    for (int i = tid; i < CD * 4; i += 256) {
      int ch = i / 4;
      int k8 = (i % 4) * 8;
      *(bf16x8*)&vl[ch][k8] = *(const bf16x8*)(Vbb + (size_t)ch * NSP + m0 + k8);
    }
    __syncthreads();
    // QK^T from LDS
    f32x4 s[2];
#pragma unroll
    for (int t = 0; t < 2; ++t) {
      f32x4 acc = (f32x4){0.f, 0.f, 0.f, 0.f};
#pragma unroll
      for (int kc = 0; kc < KC; ++kc) {
        bf16x8 kf = *(const bf16x8*)&kl[t * 16 + m15][kc * 32 + quad * 8];
        acc = __builtin_amdgcn_mfma_f32_16x16x32_bf16(qf[kc], kf, acc, 0, 0, 0);
      }
      s[t] = acc;
    }
    // exp + transpose via per-wave private pt
#pragma unroll
    for (int t = 0; t < 2; ++t) {
      float e0 = __expf(s[t].x), e1 = __expf(s[t].y), e2 = __expf(s[t].z), e3 = __expf(s[t].w);
      l0 += e0; l1 += e1; l2 += e2; l3 += e3;
      ptw[quad * 4 + 0][t * 16 + m15] = e0;
      ptw[quad * 4 + 1][t * 16 + m15] = e1;
      ptw[quad * 4 + 2][t * 16 + m15] = e2;
      ptw[quad * 4 + 3][t * 16 + m15] = e3;
    }
    const float* prow = &ptw[m15][quad * 8];
    f32x4 pa = *(const f32x4*)(prow);
    f32x4 pb = *(const f32x4*)(prow + 4);
    bf16x8 pf;
    pf[0] = (__bf16)pa.x; pf[1] = (__bf16)pa.y; pf[2] = (__bf16)pa.z; pf[3] = (__bf16)pa.w;
    pf[4] = (__bf16)pb.x; pf[5] = (__bf16)pb.y; pf[6] = (__bf16)pb.z; pf[7] = (__bf16)pb.w;
    // P·V from LDS
#pragma unroll
    for (int ct = 0; ct < NC; ++ct) {
      bf16x8 vf = *(const bf16x8*)&vl[ct * 16 + m15][quad * 8];
      of[ct] = __builtin_amdgcn_mfma_f32_16x16x32_bf16(pf, vf, of[ct], 0, 0, 0);
    }
  }

#pragma unroll
  for (int off = 1; off < 16; off <<= 1) {
    l0 += __shfl_xor(l0, off);
    l1 += __shfl_xor(l1, off);
    l2 += __shfl_xor(l2, off);
    l3 += __shfl_xor(l3, off);
  }
  float* lpb = lp + (size_t)(ks * BB + b) * NSP + n0;
  if (m15 == 0) {
    lpb[quad * 4 + 0] = l0;
    lpb[quad * 4 + 1] = l1;
    lpb[quad * 4 + 2] = l2;
    lpb[quad * 4 + 3] = l3;
  }
  __bf16* Ob = Op + (size_t)(ks * BB + b) * CD * NSP;
#pragma unroll
  for (int ct = 0; ct < NC; ++ct) {
    bf16x4 pk;
#pragma unroll
    for (int reg = 0; reg < 4; ++reg) pk[reg] = (__bf16)of[ct][reg];
    *(bf16x4*)(Ob + (size_t)(ct * 16 + m15) * NSP + n0 + quad * 4) = pk;
  }
}

// combine partials for CD=32 -> att1_t (B,N,32) bf16 (ltot fused)
__global__ __launch_bounds__(256) void combine32_kernel(const __bf16* __restrict__ Op,
                                                        const float* __restrict__ lp,
                                                        __bf16* __restrict__ att1_t) {
  __shared__ float lds[32][33];
  int b = blockIdx.z;
  int n0 = blockIdx.x * 32;
  int tid = threadIdx.x;
  int nn = tid & 31, cs = tid >> 5;
  float ltot = 0.f;
#pragma unroll
  for (int ks = 0; ks < KS; ++ks) ltot += lp[(size_t)(ks * BB + b) * NSP + n0 + nn];
  float linv = 1.0f / ltot;
#pragma unroll
  for (int j = 0; j < 4; ++j) {
    int cc = cs * 4 + j;
    float s = 0.f;
#pragma unroll
    for (int ks = 0; ks < KS; ++ks)
      s += (float)Op[((size_t)(ks * BB + b) * 32 + cc) * NSP + n0 + nn];
    lds[cc][nn] = s * linv;
  }
  __syncthreads();
  int c = tid & 31, ns = tid >> 5;
#pragma unroll
  for (int j = 0; j < 4; ++j) {
    int n2 = ns * 4 + j;
    att1_t[((size_t)b * NSP + n0 + n2) * 32 + c] = (__bf16)lds[c][n2];
  }
}

// combine partials for CD=128, + x residual -> x1 (f32 planar) AND x1_t (bf16 transposed)
__global__ __launch_bounds__(256) void combine128_kernel(
    const __bf16* __restrict__ Op, const float* __restrict__ lp,
    const float* __restrict__ x, float* __restrict__ x1, __bf16* __restrict__ x1_t) {
  __shared__ float lds[32][33];
  int b = blockIdx.z;
  int n0 = blockIdx.x * 32;
  int c0 = blockIdx.y * 32;
  int tid = threadIdx.x;
  int nn = tid & 31, cs = tid >> 5;
  float ltot = 0.f;
#pragma unroll
  for (int ks = 0; ks < KS; ++ks) ltot += lp[(size_t)(ks * BB + b) * NSP + n0 + nn];
  float linv = 1.0f / ltot;
#pragma unroll
  for (int j = 0; j < 4; ++j) {
    int gc = c0 + cs * 4 + j;
    float s = 0.f;
#pragma unroll
    for (int ks = 0; ks < KS; ++ks)
      s += (float)Op[((size_t)(ks * BB + b) * CC + gc) * NSP + n0 + nn];
    float v = s * linv + x[((size_t)b * CC + gc) * NSP + n0 + nn];
    lds[cs * 4 + j][nn] = v;
    x1[((size_t)b * CC + gc) * NSP + n0 + nn] = v;
  }
  __syncthreads();
  int c = tid & 31, ns = tid >> 5;
#pragma unroll
  for (int j = 0; j < 4; ++j) {
    int n2 = ns * 4 + j;
    x1_t[((size_t)b * NSP + n0 + n2) * CC + c0 + c] = (__bf16)lds[c][n2];
  }
}

// ---------------- host ----------------
extern "C" void kernel_launch(void* const* d_in, const int* in_sizes, int n_in,
                              void* d_out, int out_size, void* d_ws, size_t ws_size,
                              hipStream_t stream) {
  const float* x = (const float*)d_in[0];
  const float* r_w = (const float*)d_in[1];
  const float* r_b = (const float*)d_in[2];
  const float* k_w = (const float*)d_in[3];
  const float* k_b = (const float*)d_in[4];
  const float* v_w = (const float*)d_in[5];
  const float* v_b = (const float*)d_in[6];
  // d_in[7..10]: wc1/wc2 — dead code (multiplied by zeros in reference)
  const float* u = (const float*)d_in[11];
  const float* sn1_w = (const float*)d_in[12];
  const float* sn1_b = (const float*)d_in[13];
  const float* sn2_w = (const float*)d_in[14];
  const float* sn2_b = (const float*)d_in[15];
  const float* lb_w = (const float*)d_in[16];
  const float* lb_b = (const float*)d_in[17];
  const float* ld_w = (const float*)d_in[18];
  const float* ld_b = (const float*)d_in[19];
  const float* ps_w = (const float*)d_in[20];
  const float* ps_b = (const float*)d_in[21];
  const float* pq_w = (const float*)d_in[22];
  const float* pq_b = (const float*)d_in[23];
  const float* fc1_w = (const float*)d_in[24];
  const float* fc1_b = (const float*)d_in[25];
  const float* fc2_w = (const float*)d_in[26];
  const float* fc2_b = (const float*)d_in[27];
  const float* db_g[4] = {(const float*)d_in[28], (const float*)d_in[32],
                          (const float*)d_in[36], (const float*)d_in[40]};
  const float* db_b[4] = {(const float*)d_in[29], (const float*)d_in[33],
                          (const float*)d_in[37], (const float*)d_in[41]};
  const float* db_w[4] = {(const float*)d_in[30], (const float*)d_in[34],
                          (const float*)d_in[38], (const float*)d_in[42]};
  const float* db_cb[4] = {(const float*)d_in[31], (const float*)d_in[35],
                           (const float*)d_in[39], (const float*)d_in[43]};

  float* outp = (float*)d_out;           // out  (B,C,H,W)
  float* knum = outp + BCN;              // new_num = k*v
  float* kden = outp + 2 * (size_t)BCN;  // new_den = k

  float* ws = (float*)d_ws;
  // region map (f32 slots)
  const size_t F_FEATS = 0;         // feats f32 -> Op partials -> h_t bf16
  const size_t F_Z2 = 2359296;      // z2 f32 (2359296)
  const size_t F_REC = 4718592;     // rec f32 (1179648)
  const size_t F_V = 5898240;       // v f32 -> ht bf16 -> sf_t bf16 (1179648)
  const size_t F_R = 7077888;       // r f32 -> feats_t bf16 -> V2b bf16 -> x1 f32 (1179648)
  const size_t F_XR = 8257536;      // xrope_t bf16 -> z1_t -> Qt (589824)
  const size_t F_XT = 8847360;      // x_t bf16 -> Bft -> K2t (589824)
  const size_t F_DFB = 9437184;     // Dfb bf16 (147456)
  const size_t F_AT1T = 9584640;    // att1_t bf16 (147456)
  const size_t F_CT = 9732096;      // combined_t bf16 -> x1_t bf16 (589824)
  const size_t F_LP = 10321920;     // lp f32 (110592)
  const size_t F_STATS = 10432512;  // mean[256] var[256] tau[1024]
  const size_t F_WB = 10434048;     // conv1x1 weights bf16 (266240 bf16 = 133120 slots)
  const size_t F_WB3 = 10567168;    // conv3x3 packed weights bf16 (202752 bf16 = 101376 slots)
  float* mean = ws + F_STATS;
  float* var = ws + F_STATS + 256;
  float* tau = ws + F_STATS + 512;
  float* lp = ws + F_LP;
  __bf16* wbase = (__bf16*)(ws + F_WB);
  __bf16* wb3 = (__bf16*)(ws + F_WB3);
  // bf16-unit offsets (fusion pairs contiguous)
  const int W_KV = 0;        // k(16384) | v(16384)
  const int W_R = 32768;     // 16384
  const int W_SN1 = 49152;   // 16384
  const int W_SN2 = 65536;   // 16384
  const int W_LBLD = 81920;  // lb(8192) | ld(8192)
  const int W_PS = 98304;    // 4096
  const int W_PQK = 102400;  // pq(16384) | k dup(16384)
  const int W_FC1 = 135168;  // 65536
  const int W_FC2 = 200704;  // 65536
  const int W3_OFF[4] = {0, 36864, 82944, 138240};  // 9*32*cin cumulative

  dim3 blk(256);
  int ewBCN = (BCN + 255) / 256;

  // --- all weight conversions up front ---
  WCvt wc;
  wc.src[0] = k_w;    wc.len[0] = 16384; wc.off[0] = W_KV;
  wc.src[1] = v_w;    wc.len[1] = 16384; wc.off[1] = W_KV + 16384;
  wc.src[2] = r_w;    wc.len[2] = 16384; wc.off[2] = W_R;
  wc.src[3] = sn1_w;  wc.len[3] = 16384; wc.off[3] = W_SN1;
  wc.src[4] = sn2_w;  wc.len[4] = 16384; wc.off[4] = W_SN2;
  wc.src[5] = lb_w;   wc.len[5] = 8192;  wc.off[5] = W_LBLD;
  wc.src[6] = ld_w;   wc.len[6] = 8192;  wc.off[6] = W_LBLD + 8192;
  wc.src[7] = ps_w;   wc.len[7] = 4096;  wc.off[7] = W_PS;
  wc.src[8] = pq_w;   wc.len[8] = 16384; wc.off[8] = W_PQK;
  wc.src[9] = k_w;    wc.len[9] = 16384; wc.off[9] = W_PQK + 16384;
  wc.src[10] = fc1_w; wc.len[10] = 65536; wc.off[10] = W_FC1;
  wc.src[11] = fc2_w; wc.len[11] = 65536; wc.off[11] = W_FC2;
  wcvt_kernel<<<dim3(256, 12), blk, 0, stream>>>(wc, wbase);
  PackW pw;
  for (int i = 0; i < 4; ++i) {
    pw.src[i] = db_w[i];
    pw.cin[i] = 128 + 32 * i;
    pw.off[i] = W3_OFF[i];
  }
  packw4_kernel<<<dim3(252, 4), blk, 0, stream>>>(pw, wb3);

  __bf16* xrope_t = (__bf16*)(ws + F_XR);
  __bf16* x_t = (__bf16*)(ws + F_XT);
  trans_kernel<128, 1><<<dim3(72, 4, 4), blk, 0, stream>>>(x, xrope_t, nullptr);
  trans_kernel<128, 0><<<dim3(72, 4, 4), blk, 0, stream>>>(x, x_t, nullptr);

  // --- recurrent path: fused k|v GEMM + r GEMM + recwkv ---
  gemm_mfma_kernel<128, 0, 0, 0><<<dim3(144, 4, 2), blk, 0, stream>>>(
      xrope_t, wbase + W_KV, k_b, v_b, nullptr, nullptr, kden, ws + F_V, 128, 256, 1.f, 1.f);
  gemm_mfma_kernel<128, 2, 0, 0><<<dim3(144, 4, 1), blk, 0, stream>>>(
      x_t, wbase + W_R, r_b, r_b, nullptr, nullptr, ws + F_R, ws + F_R, 128, 128, 1.f, 1.f);
  recwkv_kernel<<<ewBCN, blk, 0, stream>>>(ws + F_R, kden, ws + F_V, u, knum, ws + F_REC);

  // --- dense block ---
  copyx_kernel<<<ewBCN, blk, 0, stream>>>(x, ws + F_FEATS);
  bn_stats_kernel<<<128, blk, 0, stream>>>(ws + F_FEATS, 0, mean, var);
  __bf16* ht = (__bf16*)(ws + F_V);
  int cins[4] = {128, 160, 192, 224};
  for (int i = 0; i < 4; ++i) {
    int cin = cins[i];
    bnrelu_t_kernel<<<dim3(72, cin / 32, 4), blk, 0, stream>>>(
        ws + F_FEATS, mean, var, db_g[i], db_b[i], ht);
    switch (cin) {
      case 128: conv3x3_mfma_kernel<128><<<dim3(144, 4), blk, 0, stream>>>(ht, wb3 + W3_OFF[i], db_cb[i], ws + F_FEATS, cin); break;
      case 160: conv3x3_mfma_kernel<160><<<dim3(144, 4), blk, 0, stream>>>(ht, wb3 + W3_OFF[i], db_cb[i], ws + F_FEATS, cin); break;
      case 192: conv3x3_mfma_kernel<192><<<dim3(144, 4), blk, 0, stream>>>(ht, wb3 + W3_OFF[i], db_cb[i], ws + F_FEATS, cin); break;
      default:  conv3x3_mfma_kernel<224><<<dim3(144, 4), blk, 0, stream>>>(ht, wb3 + W3_OFF[i], db_cb[i], ws + F_FEATS, cin); break;
    }
    if (i < 3)
      bn_stats_kernel<<<32, blk, 0, stream>>>(ws + F_FEATS, cin, mean, var);
  }

  // --- spike path ---
  __bf16* feats_t = (__bf16*)(ws + F_R);
  trans_kernel<256, 0><<<dim3(72, 8, 4), blk, 0, stream>>>(ws + F_FEATS, feats_t, nullptr);
  __bf16* z1_t = (__bf16*)(ws + F_XR);
  gemm_mfma_kernel<256, 1, 1, 1><<<dim3(144, 4, 1), dim3(128), 0, stream>>>(
      feats_t, wbase + W_SN1, sn1_b, sn1_b, nullptr, nullptr, z1_t, z1_t, 64, 64, 1.f, 1.f);
  gemm_mfma_kernel<64, 2, 0, 0><<<dim3(144, 4, 2), blk, 0, stream>>>(
      z1_t, wbase + W_SN2, sn2_b, sn2_b, nullptr, nullptr, ws + F_Z2, ws + F_Z2, 256, 256, 1.f, 1.f);
  tau_kernel<<<BB * DCC, blk, 0, stream>>>(ws + F_Z2, tau);
  __bf16* sf_t = (__bf16*)(ws + F_V);
  trans_kernel<256, 2><<<dim3(72, 8, 4), blk, 0, stream>>>(ws + F_FEATS, sf_t, tau);
  __bf16* Bft = (__bf16*)(ws + F_XT);
  __bf16* Dfb = (__bf16*)(ws + F_DFB);
  gemm_mfma_kernel<256, 0, 1, 2><<<dim3(144, 4, 1), dim3(128), 0, stream>>>(
      sf_t, wbase + W_LBLD, lb_b, ld_b, nullptr, nullptr, Bft, Dfb, 32, 64, 1.f, 1.f);
  __bf16* Opart = (__bf16*)(ws + F_FEATS);  // feats f32 dead from here
  attn_part_kernel<32><<<dim3(36, 4, KS), blk, 0, stream>>>(Bft, Bft, Dfb, Opart, lp);
  __bf16* att1_t = (__bf16*)(ws + F_AT1T);
  combine32_kernel<<<dim3(72, 1, 4), blk, 0, stream>>>(Opart, lp, att1_t);
  __bf16* comb_t = (__bf16*)(ws + F_CT);
  gemm_mfma_kernel<32, 0, 1, 1><<<dim3(144, 4, 1), blk, 0, stream>>>(
      att1_t, wbase + W_PS, ps_b, ps_b, ws + F_REC, ws + F_REC, comb_t, comb_t, 128, 128, 1.f, 1.f);

  // --- final attention: fused Q|K2 GEMM, V2 GEMM, flash-LDS attn ---
  __bf16* Qt = (__bf16*)(ws + F_XR);
  __bf16* K2t = (__bf16*)(ws + F_XT);
  __bf16* V2b = (__bf16*)(ws + F_R);
  gemm_mfma_kernel<128, 0, 1, 1><<<dim3(144, 4, 2), blk, 0, stream>>>(
      comb_t, wbase + W_PQK, pq_b, k_b, nullptr, nullptr, Qt, K2t, 128, 256,
      0.08838834764831845f, 1.f);
  gemm_mfma_kernel<128, 0, 2, 2><<<dim3(144, 4, 1), blk, 0, stream>>>(
      comb_t, wbase + W_KV + 16384, v_b, v_b, nullptr, nullptr, V2b, V2b, 128, 128, 1.f, 1.f);
  attn_part_kernel<128><<<dim3(36, 4, KS), blk, 0, stream>>>(Qt, K2t, V2b, Opart, lp);
  float* x1 = ws + F_R;                 // V2b dead after attn
  __bf16* x1_t = (__bf16*)(ws + F_CT);  // comb_t dead after V2 gemm
  combine128_kernel<<<dim3(72, 4, 4), blk, 0, stream>>>(Opart, lp, x, x1, x1_t);

  // --- FFN tail ---
  __bf16* h_t = (__bf16*)(ws + F_FEATS);  // Op partials dead after combine
  gemm_mfma_kernel<128, 3, 1, 1><<<dim3(144, 4, 4), blk, 0, stream>>>(
      x1_t, wbase + W_FC1, fc1_b, fc1_b, nullptr, nullptr, h_t, h_t, 512, 512, 1.f, 1.f);
  gemm_mfma_kernel<512, 0, 0, 0><<<dim3(144, 4, 1), blk, 0, stream>>>(
      h_t, wbase + W_FC2, fc2_b, fc2_b, x1, x1, outp, outp, 128, 128, 1.f, 1.f);
}